// Round 1
// baseline (2641.951 us; speedup 1.0000x reference)
//
#include <hip/hip_runtime.h>
#include <cstddef>

#define EMB 256
#define NN  256
#define BB  32
#define FFD 512
#define LL  5
#define MTOT (BB*NN)          // 8192 rows

static const size_t SLOT = (size_t)BB * NN * EMB;   // 2,097,152 floats = 8 MB

// ---------------------------------------------------------------------------
// Generic 64x64-tile fp32 GEMM with epilogue: C = A@W (+bias) (+resid) (relu)
// Batched over side s = blockIdx.z (pointer strides per side).
// ---------------------------------------------------------------------------
template<int BIAS, int RES, int RELU>
__global__ __launch_bounds__(256)
void gemm_k(const float* __restrict__ Abase, size_t Astr,
            const float* __restrict__ Wbase, size_t Wstr,
            const float* __restrict__ biasBase, size_t bstr,
            const float* __restrict__ Rbase, size_t Rstr,
            float* __restrict__ Cbase, size_t Cstr,
            int Kd, int Nd)
{
    const int s = blockIdx.z;
    const float* A  = Abase + (size_t)s * Astr;
    const float* Wp = Wbase + (size_t)s * Wstr;
    float*       C  = Cbase + (size_t)s * Cstr;

    __shared__ float As[32][68];   // [k][m], pad 68 (16B-aligned rows)
    __shared__ float Bs[32][64];   // [k][n]

    const int m0 = blockIdx.x * 64;
    const int n0 = blockIdx.y * 64;
    const int tid = threadIdx.x;
    const int tx = tid & 15, ty = tid >> 4;

    float acc[4][4] = {};

    for (int k0 = 0; k0 < Kd; k0 += 32) {
        __syncthreads();
        // A tile: 64 rows x 32 k  (512 float4, 2/thread)
        #pragma unroll
        for (int i = 0; i < 2; ++i) {
            int f = tid + 256 * i;
            int row = f >> 3;
            int kc  = (f & 7) * 4;
            float4 v = *(const float4*)(A + (size_t)(m0 + row) * Kd + k0 + kc);
            As[kc+0][row] = v.x; As[kc+1][row] = v.y;
            As[kc+2][row] = v.z; As[kc+3][row] = v.w;
        }
        // W tile: 32 k x 64 n
        #pragma unroll
        for (int i = 0; i < 2; ++i) {
            int f = tid + 256 * i;
            int row = f >> 4;
            int nc  = (f & 15) * 4;
            *(float4*)&Bs[row][nc] =
                *(const float4*)(Wp + (size_t)(k0 + row) * Nd + n0 + nc);
        }
        __syncthreads();
        #pragma unroll
        for (int k = 0; k < 32; ++k) {
            float4 a = *(const float4*)&As[k][ty * 4];
            float4 b = *(const float4*)&Bs[k][tx * 4];
            acc[0][0] += a.x*b.x; acc[0][1] += a.x*b.y; acc[0][2] += a.x*b.z; acc[0][3] += a.x*b.w;
            acc[1][0] += a.y*b.x; acc[1][1] += a.y*b.y; acc[1][2] += a.y*b.z; acc[1][3] += a.y*b.w;
            acc[2][0] += a.z*b.x; acc[2][1] += a.z*b.y; acc[2][2] += a.z*b.z; acc[2][3] += a.z*b.w;
            acc[3][0] += a.w*b.x; acc[3][1] += a.w*b.y; acc[3][2] += a.w*b.z; acc[3][3] += a.w*b.w;
        }
    }

    float4 bvec = make_float4(0.f, 0.f, 0.f, 0.f);
    if constexpr (BIAS)
        bvec = *(const float4*)(biasBase + (size_t)s * bstr + n0 + tx * 4);

    #pragma unroll
    for (int i = 0; i < 4; ++i) {
        const size_t ro = (size_t)(m0 + ty * 4 + i) * Nd + n0 + tx * 4;
        float4 v = make_float4(acc[i][0] + bvec.x, acc[i][1] + bvec.y,
                               acc[i][2] + bvec.z, acc[i][3] + bvec.w);
        if constexpr (RES) {
            float4 r = *(const float4*)(Rbase + (size_t)s * Rstr + ro);
            v.x += r.x; v.y += r.y; v.z += r.z; v.w += r.w;
        }
        if constexpr (RELU) {
            v.x = fmaxf(v.x, 0.f); v.y = fmaxf(v.y, 0.f);
            v.z = fmaxf(v.z, 0.f); v.w = fmaxf(v.w, 0.f);
        }
        *(float4*)(C + ro) = v;
    }
}

// ---------------------------------------------------------------------------
// Fused QKV projections. blockIdx.y: seg = y>>2 (0=Q,1=K,2=V), n0=(y&3)*64.
// Q = x_row@Wq ; K = x_row@Ws + x_col@Wa ; V = x_col@Wv
// x_row = X[s], x_col = X[s^1].
// ---------------------------------------------------------------------------
__global__ __launch_bounds__(256)
void gemm_qkv(const float* __restrict__ X0, const float* __restrict__ X1,
              const float* __restrict__ Wq, const float* __restrict__ Ws,
              const float* __restrict__ Wa, const float* __restrict__ Wv,
              float* __restrict__ Qb, float* __restrict__ Kb, float* __restrict__ Vb,
              int l)
{
    const int s   = blockIdx.z;
    const int seg = blockIdx.y >> 2;
    const int n0  = (blockIdx.y & 3) * 64;
    const int m0  = blockIdx.x * 64;
    const float* Xs = s ? X1 : X0;
    const float* Xo = s ? X0 : X1;
    const size_t woff = (size_t)(l * 2 + s) * EMB * EMB;

    __shared__ float As[32][68];
    __shared__ float Bs[32][64];
    const int tid = threadIdx.x;
    const int tx = tid & 15, ty = tid >> 4;

    float acc[4][4] = {};
    const int np = (seg == 1) ? 2 : 1;

    for (int p = 0; p < np; ++p) {
        const float* A  = (seg == 0) ? Xs : (seg == 2) ? Xo : (p == 0 ? Xs : Xo);
        const float* Wp = ((seg == 0) ? Wq : (seg == 2) ? Wv : (p == 0 ? Ws : Wa)) + woff;
        for (int k0 = 0; k0 < EMB; k0 += 32) {
            __syncthreads();
            #pragma unroll
            for (int i = 0; i < 2; ++i) {
                int f = tid + 256 * i;
                int row = f >> 3;
                int kc  = (f & 7) * 4;
                float4 v = *(const float4*)(A + (size_t)(m0 + row) * EMB + k0 + kc);
                As[kc+0][row] = v.x; As[kc+1][row] = v.y;
                As[kc+2][row] = v.z; As[kc+3][row] = v.w;
            }
            #pragma unroll
            for (int i = 0; i < 2; ++i) {
                int f = tid + 256 * i;
                int row = f >> 4;
                int nc  = (f & 15) * 4;
                *(float4*)&Bs[row][nc] =
                    *(const float4*)(Wp + (size_t)(k0 + row) * EMB + n0 + nc);
            }
            __syncthreads();
            #pragma unroll
            for (int k = 0; k < 32; ++k) {
                float4 a = *(const float4*)&As[k][ty * 4];
                float4 b = *(const float4*)&Bs[k][tx * 4];
                acc[0][0] += a.x*b.x; acc[0][1] += a.x*b.y; acc[0][2] += a.x*b.z; acc[0][3] += a.x*b.w;
                acc[1][0] += a.y*b.x; acc[1][1] += a.y*b.y; acc[1][2] += a.y*b.z; acc[1][3] += a.y*b.w;
                acc[2][0] += a.z*b.x; acc[2][1] += a.z*b.y; acc[2][2] += a.z*b.z; acc[2][3] += a.z*b.w;
                acc[3][0] += a.w*b.x; acc[3][1] += a.w*b.y; acc[3][2] += a.w*b.z; acc[3][3] += a.w*b.w;
            }
        }
    }

    float* Ob = (seg == 0) ? Qb : (seg == 1) ? Kb : Vb;
    float* C = Ob + (size_t)s * SLOT;
    #pragma unroll
    for (int i = 0; i < 4; ++i) {
        const size_t ro = (size_t)(m0 + ty * 4 + i) * EMB + n0 + tx * 4;
        *(float4*)(C + ro) = make_float4(acc[i][0], acc[i][1], acc[i][2], acc[i][3]);
    }
}

// ---------------------------------------------------------------------------
// Attention: one WG per (h, b, s); thread i = query row. Two-pass softmax.
// scores = (Q·K)/4 + cost (side 0) / cost^T (side 1)
// ---------------------------------------------------------------------------
__global__ __launch_bounds__(256)
void attn_k(const float* __restrict__ Qb, const float* __restrict__ Kb,
            const float* __restrict__ Vb, const float* __restrict__ cost,
            float* __restrict__ AOb)
{
    const int h = blockIdx.x, b = blockIdx.y, s = blockIdx.z;
    __shared__ float Ks[NN][16];
    __shared__ float Vs[NN][16];
    const int tid = threadIdx.x;

    {
        const float* Kr = Kb + (size_t)s * SLOT + ((size_t)(b * NN + tid)) * EMB + h * 16;
        const float* Vr = Vb + (size_t)s * SLOT + ((size_t)(b * NN + tid)) * EMB + h * 16;
        #pragma unroll
        for (int d4 = 0; d4 < 4; ++d4) {
            *(float4*)&Ks[tid][d4 * 4] = *(const float4*)(Kr + d4 * 4);
            *(float4*)&Vs[tid][d4 * 4] = *(const float4*)(Vr + d4 * 4);
        }
    }
    __syncthreads();

    float q[16];
    {
        const float* Qr = Qb + (size_t)s * SLOT + ((size_t)(b * NN + tid)) * EMB + h * 16;
        #pragma unroll
        for (int d = 0; d < 16; ++d) q[d] = Qr[d];
    }
    const float* cb = cost + (size_t)b * NN * NN;
    const int i = tid;

    float m = -1e30f;
    for (int j = 0; j < NN; ++j) {
        float dv = 0.f;
        #pragma unroll
        for (int d = 0; d < 16; ++d) dv += q[d] * Ks[j][d];
        float cv = (s == 0) ? cb[(size_t)i * NN + j] : cb[(size_t)j * NN + i];
        float sc = dv * 0.25f + cv;
        m = fmaxf(m, sc);
    }

    float l_ = 0.f;
    float acc[16] = {};
    for (int j = 0; j < NN; ++j) {
        float dv = 0.f;
        #pragma unroll
        for (int d = 0; d < 16; ++d) dv += q[d] * Ks[j][d];
        float cv = (s == 0) ? cb[(size_t)i * NN + j] : cb[(size_t)j * NN + i];
        float p = __expf(dv * 0.25f + cv - m);
        l_ += p;
        #pragma unroll
        for (int d = 0; d < 16; ++d) acc[d] += p * Vs[j][d];
    }

    const float inv = 1.f / l_;
    float* AO = AOb + (size_t)s * SLOT + ((size_t)(b * NN + i)) * EMB + h * 16;
    #pragma unroll
    for (int d4 = 0; d4 < 4; ++d4) {
        *(float4*)(AO + d4 * 4) = make_float4(acc[d4*4+0] * inv, acc[d4*4+1] * inv,
                                              acc[d4*4+2] * inv, acc[d4*4+3] * inv);
    }
}

// ---------------------------------------------------------------------------
// InstanceNorm over node axis. WG = (b, channel-group of 64); 4 n-splits.
// ---------------------------------------------------------------------------
__global__ __launch_bounds__(256)
void inorm_k(const float* __restrict__ Xb, size_t Xstr,
             const float* __restrict__ gb, const float* __restrict__ bb,
             float* __restrict__ Yb, size_t Ystr, int l)
{
    const int bx = blockIdx.x;
    const int b = bx >> 2, cg = bx & 3;
    const int s = blockIdx.y;
    const float* X = Xb + (size_t)s * Xstr + (size_t)b * NN * EMB;
    float*       Y = Yb + (size_t)s * Ystr + (size_t)b * NN * EMB;
    const int tid = threadIdx.x;
    const int cl = tid & 63, q = tid >> 6;
    const int c = cg * 64 + cl;

    float sum = 0.f, ss = 0.f;
    for (int n = q * 64; n < q * 64 + 64; ++n) {
        float x = X[(size_t)n * EMB + c];
        sum += x; ss += x * x;
    }
    __shared__ float Ssum[4][64], Sss[4][64], Sa[64], Sb2[64];
    Ssum[q][cl] = sum; Sss[q][cl] = ss;
    __syncthreads();
    if (q == 0) {
        float s4 = Ssum[0][cl] + Ssum[1][cl] + Ssum[2][cl] + Ssum[3][cl];
        float q4 = Sss[0][cl] + Sss[1][cl] + Sss[2][cl] + Sss[3][cl];
        float mean = s4 * (1.f / NN);
        float var  = q4 * (1.f / NN) - mean * mean;
        float inv  = rsqrtf(var + 1e-5f);
        float gv = gb[(size_t)(l * 2 + s) * EMB + c];
        float bv = bb[(size_t)(l * 2 + s) * EMB + c];
        float a = gv * inv;
        Sa[cl]  = a;
        Sb2[cl] = bv - mean * a;
    }
    __syncthreads();
    const float a = Sa[cl], b2 = Sb2[cl];
    for (int n = q * 64; n < q * 64 + 64; ++n) {
        Y[(size_t)n * EMB + c] = X[(size_t)n * EMB + c] * a + b2;
    }
}

// ---------------------------------------------------------------------------
extern "C" void kernel_launch(void* const* d_in, const int* in_sizes, int n_in,
                              void* d_out, int out_size, void* d_ws, size_t ws_size,
                              hipStream_t stream)
{
    const float* row_emb = (const float*)d_in[0];
    const float* col_emb = (const float*)d_in[1];
    const float* cost    = (const float*)d_in[2];
    const float* Wq  = (const float*)d_in[3];
    const float* Ws  = (const float*)d_in[4];
    const float* Wa  = (const float*)d_in[5];
    const float* Wv  = (const float*)d_in[6];
    const float* Wc  = (const float*)d_in[7];
    const float* bc  = (const float*)d_in[8];
    const float* g1  = (const float*)d_in[9];
    const float* be1 = (const float*)d_in[10];
    const float* W1  = (const float*)d_in[11];
    const float* bf1 = (const float*)d_in[12];
    const float* W2  = (const float*)d_in[13];
    const float* bf2 = (const float*)d_in[14];
    const float* g2  = (const float*)d_in[15];
    const float* be2 = (const float*)d_in[16];

    float* ws = (float*)d_ws;
    // layout: curA(2) newB(2) Q(2) K(2) V(2) AO(2) H(2x2)  -> 16 SLOTs = 128 MB
    float* bufA = ws;                  // 2 slots
    float* bufB = ws + 2 * SLOT;       // 2 slots
    float* Qb   = ws + 4 * SLOT;       // 2 slots
    float* Kb   = ws + 6 * SLOT;       // 2 slots
    float* Vb   = ws + 8 * SLOT;       // 2 slots
    float* AOb  = ws + 10 * SLOT;      // 2 slots
    float* Hb   = ws + 12 * SLOT;      // 4 slots ([2 sides] x 4M floats)

    hipMemcpyAsync(bufA,        row_emb, SLOT * sizeof(float), hipMemcpyDeviceToDevice, stream);
    hipMemcpyAsync(bufA + SLOT, col_emb, SLOT * sizeof(float), hipMemcpyDeviceToDevice, stream);

    float* cur = bufA;
    float* nxt = bufB;

    for (int l = 0; l < LL; ++l) {
        // Q,K,V projections (both sides)
        gemm_qkv<<<dim3(MTOT / 64, 12, 2), 256, 0, stream>>>(
            cur, cur + SLOT, Wq, Ws, Wa, Wv, Qb, Kb, Vb, l);

        // attention
        attn_k<<<dim3(16, BB, 2), 256, 0, stream>>>(Qb, Kb, Vb, cost, AOb);

        // mh = AO@Wc + bc + x  -> y1 (reuse Kb)
        gemm_k<1, 1, 0><<<dim3(MTOT / 64, EMB / 64, 2), 256, 0, stream>>>(
            AOb, SLOT,
            Wc + (size_t)l * 2 * EMB * EMB, (size_t)EMB * EMB,
            bc + (size_t)l * 2 * EMB, EMB,
            cur, SLOT,
            Kb, SLOT, EMB, EMB);

        // o1 = inorm(y1) -> reuse Qb
        inorm_k<<<dim3(BB * 4, 2), 256, 0, stream>>>(Kb, SLOT, g1, be1, Qb, SLOT, l);

        // h = relu(o1@W1 + bf1) -> Hb
        gemm_k<1, 0, 1><<<dim3(MTOT / 64, FFD / 64, 2), 256, 0, stream>>>(
            Qb, SLOT,
            W1 + (size_t)l * 2 * EMB * FFD, (size_t)EMB * FFD,
            bf1 + (size_t)l * 2 * FFD, FFD,
            nullptr, 0,
            Hb, 2 * SLOT, EMB, FFD);

        // y2 = h@W2 + bf2 + o1 -> reuse Vb
        gemm_k<1, 1, 0><<<dim3(MTOT / 64, EMB / 64, 2), 256, 0, stream>>>(
            Hb, 2 * SLOT,
            W2 + (size_t)l * 2 * FFD * EMB, (size_t)FFD * EMB,
            bf2 + (size_t)l * 2 * EMB, EMB,
            Qb, SLOT,
            Vb, SLOT, FFD, EMB);

        // out = inorm(y2)
        float* dst = (l == LL - 1) ? (float*)d_out : nxt;
        inorm_k<<<dim3(BB * 4, 2), 256, 0, stream>>>(Vb, SLOT, g2, be2, dst, SLOT, l);

        float* t = cur; cur = nxt; nxt = t;
    }
    (void)in_sizes; (void)n_in; (void)out_size; (void)ws_size;
}

// Round 2
// 2331.114 us; speedup vs baseline: 1.1333x; 1.1333x over previous
//
#include <hip/hip_runtime.h>
#include <cstddef>

#define EMB 256
#define NN  256
#define BB  32
#define FFD 512
#define LL  5
#define MTOT (BB*NN)          // 8192 rows

static const size_t SLOT = (size_t)BB * NN * EMB;   // 2,097,152 floats = 8 MB

// ---------------------------------------------------------------------------
// 128xBN fp32 GEMM core. 256 threads, per-thread 8 rows x (CI*4) cols.
// Rows: {ty*4+r, 64+ty*4+r}; cols: {ci*64 + tx*4+c}. K-tile 32, reg prefetch.
// ---------------------------------------------------------------------------
template<int CI>
struct GemmCore {
    float acc[2][4][CI][4];
    float4 ar[4], br[2*CI];

    __device__ void init() {
        #pragma unroll
        for (int ri=0;ri<2;++ri)
        #pragma unroll
        for (int r=0;r<4;++r)
        #pragma unroll
        for (int ci=0;ci<CI;++ci)
        #pragma unroll
        for (int c=0;c<4;++c) acc[ri][r][ci][c] = 0.f;
    }

    __device__ void loadA(const float* A, int Kd, int m0, int k0, int tid) {
        #pragma unroll
        for (int u=0;u<4;++u) {
            int f = tid + 256*u; int row = f>>3, kc = (f&7)*4;
            ar[u] = *(const float4*)(A + (size_t)(m0+row)*Kd + k0 + kc);
        }
    }
    __device__ void loadB(const float* W, int Nd, int n0, int k0, int tid) {
        #pragma unroll
        for (int u=0;u<2*CI;++u) {
            int f = tid + 256*u;
            int kr, nc;
            if (CI == 2) { kr = f>>5; nc = (f&31)*4; }
            else         { kr = f>>4; nc = (f&15)*4; }
            br[u] = *(const float4*)(W + (size_t)(k0+kr)*Nd + n0 + nc);
        }
    }
    __device__ void storeLDS(float (*As)[132], float (*Bs)[CI*64], int tid) {
        #pragma unroll
        for (int u=0;u<4;++u) {
            int f = tid + 256*u; int row = f>>3, kc = (f&7)*4;
            As[kc+0][row]=ar[u].x; As[kc+1][row]=ar[u].y;
            As[kc+2][row]=ar[u].z; As[kc+3][row]=ar[u].w;
        }
        #pragma unroll
        for (int u=0;u<2*CI;++u) {
            int f = tid + 256*u;
            int kr, nc;
            if (CI == 2) { kr = f>>5; nc = (f&31)*4; }
            else         { kr = f>>4; nc = (f&15)*4; }
            *(float4*)&Bs[kr][nc] = br[u];
        }
    }
    __device__ void inner(const float (*As)[132], const float (*Bs)[CI*64],
                          int tx, int ty) {
        #pragma unroll
        for (int k=0;k<32;++k) {
            float4 a0 = *(const float4*)&As[k][ty*4];
            float4 a1 = *(const float4*)&As[k][64+ty*4];
            float a[2][4] = {{a0.x,a0.y,a0.z,a0.w},{a1.x,a1.y,a1.z,a1.w}};
            float b[CI][4];
            #pragma unroll
            for (int ci=0;ci<CI;++ci) {
                float4 bv = *(const float4*)&Bs[k][ci*64+tx*4];
                b[ci][0]=bv.x; b[ci][1]=bv.y; b[ci][2]=bv.z; b[ci][3]=bv.w;
            }
            #pragma unroll
            for (int ri=0;ri<2;++ri)
            #pragma unroll
            for (int r=0;r<4;++r)
            #pragma unroll
            for (int ci=0;ci<CI;++ci)
            #pragma unroll
            for (int c=0;c<4;++c)
                acc[ri][r][ci][c] += a[ri][r]*b[ci][c];
        }
    }
};

// run npass GEMM passes accumulating into core.acc
template<int CI>
__device__ void gemm_body(GemmCore<CI>& g, float (*As)[132], float (*Bs)[CI*64],
                          const float* A0, const float* W0,
                          const float* A1, const float* W1,
                          int Kd, int Nd, int m0, int n0, int npass,
                          int tid, int tx, int ty)
{
    for (int p = 0; p < npass; ++p) {
        const float* A = p ? A1 : A0;
        const float* W = p ? W1 : W0;
        g.loadA(A, Kd, m0, 0, tid);
        g.loadB(W, Nd, n0, 0, tid);
        for (int k0 = 0; k0 < Kd; k0 += 32) {
            __syncthreads();
            g.storeLDS(As, Bs, tid);
            __syncthreads();
            int kn = k0 + 32;
            if (kn < Kd) {             // prefetch next tile into regs
                g.loadA(A, Kd, m0, kn, tid);
                g.loadB(W, Nd, n0, kn, tid);
            }
            g.inner(As, Bs, tx, ty);
        }
    }
}

// ---------------------------------------------------------------------------
// Generic epilogue GEMM: C = A@W (+bias)(+resid)(relu). BN = CI*64.
// ---------------------------------------------------------------------------
template<int CI, int BIAS, int RES, int RELU>
__global__ __launch_bounds__(256)
void gemm_k(const float* __restrict__ Abase, size_t Astr,
            const float* __restrict__ Wbase, size_t Wstr,
            const float* __restrict__ biasBase, size_t bstr,
            const float* __restrict__ Rbase, size_t Rstr,
            float* __restrict__ Cbase, size_t Cstr,
            int Kd, int Nd)
{
    const int s = blockIdx.z;
    const float* A  = Abase + (size_t)s * Astr;
    const float* Wp = Wbase + (size_t)s * Wstr;
    float*       C  = Cbase + (size_t)s * Cstr;
    const int m0 = blockIdx.x * 128;
    const int n0 = blockIdx.y * (CI*64);
    const int tid = threadIdx.x;
    const int tx = tid & 15, ty = tid >> 4;

    __shared__ float As[32][132];
    __shared__ float Bs[32][CI*64];

    GemmCore<CI> g; g.init();
    gemm_body<CI>(g, As, Bs, A, Wp, nullptr, nullptr, Kd, Nd, m0, n0, 1, tid, tx, ty);

    #pragma unroll
    for (int ri=0;ri<2;++ri)
    #pragma unroll
    for (int r=0;r<4;++r) {
        const int row = m0 + ri*64 + ty*4 + r;
        #pragma unroll
        for (int ci=0;ci<CI;++ci) {
            const int col = n0 + ci*64 + tx*4;
            const size_t ro = (size_t)row*Nd + col;
            float4 v = make_float4(g.acc[ri][r][ci][0], g.acc[ri][r][ci][1],
                                   g.acc[ri][r][ci][2], g.acc[ri][r][ci][3]);
            if constexpr (BIAS) {
                float4 bv = *(const float4*)(biasBase + (size_t)s*bstr + col);
                v.x+=bv.x; v.y+=bv.y; v.z+=bv.z; v.w+=bv.w;
            }
            if constexpr (RES) {
                float4 rv = *(const float4*)(Rbase + (size_t)s*Rstr + ro);
                v.x+=rv.x; v.y+=rv.y; v.z+=rv.z; v.w+=rv.w;
            }
            if constexpr (RELU) {
                v.x=fmaxf(v.x,0.f); v.y=fmaxf(v.y,0.f);
                v.z=fmaxf(v.z,0.f); v.w=fmaxf(v.w,0.f);
            }
            *(float4*)(C + ro) = v;
        }
    }
}

// ---------------------------------------------------------------------------
// Fused QKV. blockIdx.y: seg = y>>1 (0=Q,1=K,2=V), n0=(y&1)*128.
// Q = Xs@Wq ; K = Xs@Ws + Xo@Wa ; V = Xo@Wv
// ---------------------------------------------------------------------------
__global__ __launch_bounds__(256)
void qkv_k(const float* __restrict__ X0, const float* __restrict__ X1,
           const float* __restrict__ Wq, const float* __restrict__ Ws,
           const float* __restrict__ Wa, const float* __restrict__ Wv,
           float* __restrict__ Qb, float* __restrict__ Kb, float* __restrict__ Vb,
           int l)
{
    const int s   = blockIdx.z;
    const int seg = blockIdx.y >> 1;
    const int n0  = (blockIdx.y & 1) * 128;
    const int m0  = blockIdx.x * 128;
    const float* Xs = s ? X1 : X0;
    const float* Xo = s ? X0 : X1;
    const size_t woff = (size_t)(l*2+s)*EMB*EMB;

    const float* A0 = (seg==2) ? Xo : Xs;
    const float* W0 = ((seg==0) ? Wq : (seg==2) ? Wv : Ws) + woff;
    const float* A1 = Xo;
    const float* W1 = Wa + woff;
    const int npass = (seg==1) ? 2 : 1;

    const int tid = threadIdx.x;
    const int tx = tid & 15, ty = tid >> 4;

    __shared__ float As[32][132];
    __shared__ float Bs[32][128];

    GemmCore<2> g; g.init();
    gemm_body<2>(g, As, Bs, A0, W0, A1, W1, EMB, EMB, m0, n0, npass, tid, tx, ty);

    float* C = ((seg==0) ? Qb : (seg==1) ? Kb : Vb) + (size_t)s*SLOT;
    #pragma unroll
    for (int ri=0;ri<2;++ri)
    #pragma unroll
    for (int r=0;r<4;++r) {
        const int row = m0 + ri*64 + ty*4 + r;
        #pragma unroll
        for (int ci=0;ci<2;++ci) {
            const size_t ro = (size_t)row*EMB + n0 + ci*64 + tx*4;
            *(float4*)(C + ro) = make_float4(g.acc[ri][r][ci][0], g.acc[ri][r][ci][1],
                                             g.acc[ri][r][ci][2], g.acc[ri][r][ci][3]);
        }
    }
}

// ---------------------------------------------------------------------------
// Attention: WG = (i-tile of 32, b, s); 512 thr = 16 heads x 32 queries.
// K/V tiles for ALL heads + shared cost tile staged in LDS; online softmax.
// ---------------------------------------------------------------------------
__global__ __launch_bounds__(512)
void attn_k(const float* __restrict__ Qb, const float* __restrict__ Kb,
            const float* __restrict__ Vb, const float* __restrict__ cost,
            float* __restrict__ AOb)
{
    const int i0 = blockIdx.x * 32;
    const int b  = blockIdx.y;
    const int s  = blockIdx.z;

    __shared__ float Ks[32][256];   // [j][emb]  32 KB
    __shared__ float Vs[32][256];   // 32 KB
    __shared__ float Cs[32][33];    // [i][j], pad 33 -> conflict-free reads

    const int tid = threadIdx.x;
    const int i = tid & 31, h = tid >> 5;

    float q[16];
    {
        const float* Qr = Qb + (size_t)s*SLOT + (size_t)(b*NN + i0 + i)*EMB + h*16;
        #pragma unroll
        for (int d4=0; d4<4; ++d4) {
            float4 v = *(const float4*)(Qr + d4*4);
            q[d4*4+0]=v.x; q[d4*4+1]=v.y; q[d4*4+2]=v.z; q[d4*4+3]=v.w;
        }
    }
    const float* cb = cost + (size_t)b*NN*NN;

    float m = -1e30f, l = 0.f;
    float acc[16] = {};

    for (int jt = 0; jt < 8; ++jt) {
        const int j0 = jt * 32;
        __syncthreads();
        {   // stage K/V tiles (all heads)
            const float* Kr = Kb + (size_t)s*SLOT + (size_t)(b*NN + j0)*EMB;
            const float* Vr = Vb + (size_t)s*SLOT + (size_t)(b*NN + j0)*EMB;
            #pragma unroll
            for (int u = 0; u < 4; ++u) {
                int f = tid + 512*u;             // 0..2047
                int row = f >> 6, col = (f & 63) * 4;
                *(float4*)&Ks[row][col] = *(const float4*)(Kr + (size_t)row*EMB + col);
                *(float4*)&Vs[row][col] = *(const float4*)(Vr + (size_t)row*EMB + col);
            }
            // cost tile: Cs[i][j] = cost[b][i0+i][j0+j] (s=0) / cost[b][j0+j][i0+i] (s=1)
            if (tid < 256) {
                int r = tid >> 3, c4 = (tid & 7) * 4;
                if (s == 0) {
                    float4 v = *(const float4*)(cb + (size_t)(i0 + r)*NN + j0 + c4);
                    Cs[r][c4+0]=v.x; Cs[r][c4+1]=v.y; Cs[r][c4+2]=v.z; Cs[r][c4+3]=v.w;
                } else {
                    float4 v = *(const float4*)(cb + (size_t)(j0 + r)*NN + i0 + c4);
                    Cs[c4+0][r]=v.x; Cs[c4+1][r]=v.y; Cs[c4+2][r]=v.z; Cs[c4+3][r]=v.w;
                }
            }
        }
        __syncthreads();

        float sc[32];
        float tmax = -1e30f;
        #pragma unroll
        for (int j = 0; j < 32; ++j) {
            const float* kr = &Ks[j][h*16];
            float dv = 0.f;
            #pragma unroll
            for (int d = 0; d < 16; ++d) dv += q[d]*kr[d];
            float v = dv*0.25f + Cs[i][j];
            sc[j] = v;
            tmax = fmaxf(tmax, v);
        }
        float mnew = fmaxf(m, tmax);
        float scale = __expf(m - mnew);
        l *= scale;
        #pragma unroll
        for (int d = 0; d < 16; ++d) acc[d] *= scale;
        m = mnew;
        #pragma unroll
        for (int j = 0; j < 32; ++j) {
            float p = __expf(sc[j] - m);
            l += p;
            const float* vr = &Vs[j][h*16];
            #pragma unroll
            for (int d = 0; d < 16; ++d) acc[d] += p*vr[d];
        }
    }

    const float inv = 1.f / l;
    float* AO = AOb + (size_t)s*SLOT + (size_t)(b*NN + i0 + i)*EMB + h*16;
    #pragma unroll
    for (int d4 = 0; d4 < 4; ++d4)
        *(float4*)(AO + d4*4) = make_float4(acc[d4*4]*inv, acc[d4*4+1]*inv,
                                            acc[d4*4+2]*inv, acc[d4*4+3]*inv);
}

// ---------------------------------------------------------------------------
// InstanceNorm over node axis. WG = (b, channel-group of 64); 4 n-splits.
// ---------------------------------------------------------------------------
__global__ __launch_bounds__(256)
void inorm_k(const float* __restrict__ Xb, size_t Xstr,
             const float* __restrict__ gb, const float* __restrict__ bb,
             float* __restrict__ Yb, size_t Ystr, int l)
{
    const int bx = blockIdx.x;
    const int b = bx >> 2, cg = bx & 3;
    const int s = blockIdx.y;
    const float* X = Xb + (size_t)s * Xstr + (size_t)b * NN * EMB;
    float*       Y = Yb + (size_t)s * Ystr + (size_t)b * NN * EMB;
    const int tid = threadIdx.x;
    const int cl = tid & 63, q = tid >> 6;
    const int c = cg * 64 + cl;

    float sum = 0.f, ss = 0.f;
    for (int n = q * 64; n < q * 64 + 64; ++n) {
        float x = X[(size_t)n * EMB + c];
        sum += x; ss += x * x;
    }
    __shared__ float Ssum[4][64], Sss[4][64], Sa[64], Sb2[64];
    Ssum[q][cl] = sum; Sss[q][cl] = ss;
    __syncthreads();
    if (q == 0) {
        float s4 = Ssum[0][cl] + Ssum[1][cl] + Ssum[2][cl] + Ssum[3][cl];
        float q4 = Sss[0][cl] + Sss[1][cl] + Sss[2][cl] + Sss[3][cl];
        float mean = s4 * (1.f / NN);
        float var  = q4 * (1.f / NN) - mean * mean;
        float inv  = rsqrtf(var + 1e-5f);
        float gv = gb[(size_t)(l * 2 + s) * EMB + c];
        float bv = bb[(size_t)(l * 2 + s) * EMB + c];
        float a = gv * inv;
        Sa[cl]  = a;
        Sb2[cl] = bv - mean * a;
    }
    __syncthreads();
    const float a = Sa[cl], b2 = Sb2[cl];
    for (int n = q * 64; n < q * 64 + 64; ++n) {
        Y[(size_t)n * EMB + c] = X[(size_t)n * EMB + c] * a + b2;
    }
}

// ---------------------------------------------------------------------------
extern "C" void kernel_launch(void* const* d_in, const int* in_sizes, int n_in,
                              void* d_out, int out_size, void* d_ws, size_t ws_size,
                              hipStream_t stream)
{
    const float* row_emb = (const float*)d_in[0];
    const float* col_emb = (const float*)d_in[1];
    const float* cost    = (const float*)d_in[2];
    const float* Wq  = (const float*)d_in[3];
    const float* Ws  = (const float*)d_in[4];
    const float* Wa  = (const float*)d_in[5];
    const float* Wv  = (const float*)d_in[6];
    const float* Wc  = (const float*)d_in[7];
    const float* bc  = (const float*)d_in[8];
    const float* g1  = (const float*)d_in[9];
    const float* be1 = (const float*)d_in[10];
    const float* W1  = (const float*)d_in[11];
    const float* bf1 = (const float*)d_in[12];
    const float* W2  = (const float*)d_in[13];
    const float* bf2 = (const float*)d_in[14];
    const float* g2  = (const float*)d_in[15];
    const float* be2 = (const float*)d_in[16];

    float* ws = (float*)d_ws;
    float* bufA = ws;                  // 2 slots (row/col current)
    float* bufB = ws + 2 * SLOT;       // 2 slots (next)
    float* Qb   = ws + 4 * SLOT;       // 2 slots
    float* Kb   = ws + 6 * SLOT;       // 2 slots
    float* Vb   = ws + 8 * SLOT;       // 2 slots
    float* AOb  = ws + 10 * SLOT;      // 2 slots
    float* Hb   = ws + 12 * SLOT;      // 4 slots (FF hidden, both sides)

    hipMemcpyAsync(bufA,        row_emb, SLOT * sizeof(float), hipMemcpyDeviceToDevice, stream);
    hipMemcpyAsync(bufA + SLOT, col_emb, SLOT * sizeof(float), hipMemcpyDeviceToDevice, stream);

    float* cur = bufA;
    float* nxt = bufB;

    for (int l = 0; l < LL; ++l) {
        // Q,K,V projections (both sides)
        qkv_k<<<dim3(MTOT/128, 6, 2), 256, 0, stream>>>(
            cur, cur + SLOT, Wq, Ws, Wa, Wv, Qb, Kb, Vb, l);

        // attention
        attn_k<<<dim3(NN/32, BB, 2), 512, 0, stream>>>(Qb, Kb, Vb, cost, AOb);

        // mh = AO@Wc + bc + x  -> Kb (reuse)
        gemm_k<1,1,1,0><<<dim3(MTOT/128, EMB/64, 2), 256, 0, stream>>>(
            AOb, SLOT,
            Wc + (size_t)l*2*EMB*EMB, (size_t)EMB*EMB,
            bc + (size_t)l*2*EMB, EMB,
            cur, SLOT,
            Kb, SLOT, EMB, EMB);

        // o1 = inorm(mh) -> Qb (reuse)
        inorm_k<<<dim3(BB*4, 2), 256, 0, stream>>>(Kb, SLOT, g1, be1, Qb, SLOT, l);

        // h = relu(o1@W1 + bf1) -> Hb
        gemm_k<2,1,0,1><<<dim3(MTOT/128, FFD/128, 2), 256, 0, stream>>>(
            Qb, SLOT,
            W1 + (size_t)l*2*EMB*FFD, (size_t)EMB*FFD,
            bf1 + (size_t)l*2*FFD, FFD,
            nullptr, 0,
            Hb, 2*SLOT, EMB, FFD);

        // y2 = h@W2 + bf2 + o1 -> Vb (reuse)
        gemm_k<1,1,1,0><<<dim3(MTOT/128, EMB/64, 2), 256, 0, stream>>>(
            Hb, 2*SLOT,
            W2 + (size_t)l*2*FFD*EMB, (size_t)FFD*EMB,
            bf2 + (size_t)l*2*EMB, EMB,
            Qb, SLOT,
            Vb, SLOT, FFD, EMB);

        // out = inorm(y2)
        float* dst = (l == LL-1) ? (float*)d_out : nxt;
        inorm_k<<<dim3(BB*4, 2), 256, 0, stream>>>(Vb, SLOT, g2, be2, dst, SLOT, l);

        float* t = cur; cur = nxt; nxt = t;
    }
    (void)in_sizes; (void)n_in; (void)out_size; (void)ws_size;
}

// Round 5
// 1529.491 us; speedup vs baseline: 1.7273x; 1.5241x over previous
//
#include <hip/hip_runtime.h>
#include <cstddef>
#include <cstdint>

#define EMB 256
#define NN  256
#define BB  32
#define FFD 512
#define LL  5
#define MTOT (BB*NN)          // 8192 rows

typedef unsigned short u16;
typedef short bf16x8 __attribute__((ext_vector_type(8)));
typedef float f32x4  __attribute__((ext_vector_type(4)));

static const size_t MB = 1048576ull;
// plane sizes (elements)
static const size_t PLX = 2097152;     // 8192x256 activation plane
static const size_t PLH = 4194304;     // 8192x512 hidden plane
// weight-plane region: per side = [hi|lo] planes of 589824 u16 each
static const size_t WSEG = 589824;     // Wq..Wv(4x65536)+Wc(65536)+W1t(131072)+W2t(131072)
#define OQ 0
#define OS 65536
#define OA 131072
#define OV 196608
#define OC 262144
#define O1 327680
#define O2 458752

// ---------------------------------------------------------------------------
// bf16 split helpers
// ---------------------------------------------------------------------------
__device__ __forceinline__ u16 bf16_rne(float x) {
    unsigned u = __float_as_uint(x);
    unsigned r = u + 0x7FFF + ((u >> 16) & 1);
    return (u16)(r >> 16);
}
__device__ __forceinline__ float bf16_f(u16 h) {
    return __uint_as_float(((unsigned)h) << 16);
}
__device__ __forceinline__ void split2(float x, u16& hi, u16& lo) {
    hi = bf16_rne(x);
    lo = bf16_rne(x - bf16_f(hi));
}

// async global->LDS, 16B per lane, dest = wave-uniform base + lane*16
__device__ __forceinline__ void gll16(const void* g, void* l) {
    __builtin_amdgcn_global_load_lds(
        (const __attribute__((address_space(1))) unsigned int*)g,
        (__attribute__((address_space(3))) unsigned int*)l,
        16, 0, 0);
}

// ---------------------------------------------------------------------------
// MFMA GEMM core: 128x128 tile, BK=64, 4 waves (2x2), 3..6 accumulation passes.
// A-tile LDS: [row 128][64 k] bf16, 16B-chunk XOR-swizzled (chunk^=(row&7)),
// applied on the global SOURCE address (linear LDS dest) and again on the
// LDS READ (both-sides-or-neither, rule 21).
// B-tile identical with row = n (weights pre-transposed to [N][K]).
// Fragment: m/n = lane&15, k-chunk = lane>>4 (consistent A/B k-ordering).
// ---------------------------------------------------------------------------
template<typename PF>
__device__ __forceinline__ void mfma_core(f32x4 (&acc)[4][4], int np, int K,
                                          int m0, int n0,
                                          u16* As, u16* Bs, PF pf)
{
    const int tid  = threadIdx.x;
    const int lane = tid & 63;
    const int w    = tid >> 6;
    const int wr   = w >> 1, wc = w & 1;
    const int l15  = lane & 15, lg = lane >> 4;

    for (int p = 0; p < np; ++p) {
        const u16 *Ap, *Bp;
        pf(p, Ap, Bp);
        const int nkt = K >> 6;
        for (int kt = 0; kt < nkt; ++kt) {
            __syncthreads();
            #pragma unroll
            for (int c = 0; c < 4; ++c) {
                int slot = w * 256 + c * 64 + lane;       // 1024 16B-slots
                int row  = slot >> 3;
                int cc   = slot & 7;
                int kc   = cc ^ (row & 7);                // inverse-swizzled source
                const u16* sa = Ap + (size_t)(m0 + row) * K + (kt << 6) + kc * 8;
                gll16(sa, As + (size_t)(w * 256 + c * 64) * 8);
                const u16* sb = Bp + (size_t)(n0 + row) * K + (kt << 6) + kc * 8;
                gll16(sb, Bs + (size_t)(w * 256 + c * 64) * 8);
            }
            __syncthreads();   // compiler emits vmcnt(0) drain before barrier
            #pragma unroll
            for (int ks = 0; ks < 2; ++ks) {
                bf16x8 a[4], b[4];
                #pragma unroll
                for (int i = 0; i < 4; ++i) {
                    int arow = wr * 64 + i * 16 + l15;
                    int achk = (ks * 4 + lg) ^ (arow & 7);
                    a[i] = *(const bf16x8*)(As + ((arow << 3) + achk) * 8);
                    int brow = wc * 64 + i * 16 + l15;
                    int bchk = (ks * 4 + lg) ^ (brow & 7);
                    b[i] = *(const bf16x8*)(Bs + ((brow << 3) + bchk) * 8);
                }
                #pragma unroll
                for (int mi = 0; mi < 4; ++mi)
                    #pragma unroll
                    for (int ni = 0; ni < 4; ++ni)
                        acc[mi][ni] = __builtin_amdgcn_mfma_f32_16x16x32_bf16(
                            a[mi], b[ni], acc[mi][ni], 0, 0, 0);
            }
        }
    }
}

// ---------------------------------------------------------------------------
// Fused QKV (split-bf16). seg = blockIdx.y>>1 (0=Q,1=K,2=V).
// Q = Xs@Wq ; K = Xs@Ws + Xo@Wa ; V = Xo@Wv   (each as 3-term split product)
// ---------------------------------------------------------------------------
__global__ __launch_bounds__(256)
void qkv_k(const u16* __restrict__ Ssp, const u16* __restrict__ wt,
           float* __restrict__ Qf, float* __restrict__ Kf, float* __restrict__ Vf)
{
    const int s   = blockIdx.z;
    const int seg = blockIdx.y >> 1;
    const int n0  = (blockIdx.y & 1) * 128;
    const int m0  = blockIdx.x * 128;

    const u16* Xsh = Ssp + (size_t)s * (2 * PLX);
    const u16* Xsl = Xsh + PLX;
    const u16* Xoh = Ssp + (size_t)(1 - s) * (2 * PLX);
    const u16* Xol = Xoh + PLX;
    const u16* Wh  = wt + (size_t)s * (2 * WSEG);
    const u16* Wl  = Wh + WSEG;
    const int  np  = (seg == 1) ? 6 : 3;

    __shared__ u16 As[8192];
    __shared__ u16 Bs[8192];

    f32x4 acc[4][4];
    #pragma unroll
    for (int i = 0; i < 4; ++i)
        #pragma unroll
        for (int j = 0; j < 4; ++j) acc[i][j] = (f32x4){0.f, 0.f, 0.f, 0.f};

    auto pf = [&](int p, const u16*& Ap, const u16*& Bp) {
        int half = (p >= 3) ? 1 : 0;
        int pp = p - half * 3;
        const u16 *ah, *al; size_t wo;
        if (seg == 0)      { ah = Xsh; al = Xsl; wo = OQ; }
        else if (seg == 2) { ah = Xoh; al = Xol; wo = OV; }
        else if (!half)    { ah = Xsh; al = Xsl; wo = OS; }
        else               { ah = Xoh; al = Xol; wo = OA; }
        Ap = (pp == 1) ? al : ah;
        Bp = ((pp == 2) ? Wl : Wh) + wo;
    };
    mfma_core(acc, np, 256, m0, n0, As, Bs, pf);

    float* O = ((seg == 0) ? Qf : (seg == 1) ? Kf : Vf) + (size_t)s * PLX;
    const int lane = threadIdx.x & 63, w = threadIdx.x >> 6;
    const int wr = w >> 1, wc = w & 1, l15 = lane & 15, lg = lane >> 4;
    #pragma unroll
    for (int mi = 0; mi < 4; ++mi)
        #pragma unroll
        for (int ni = 0; ni < 4; ++ni) {
            const int col = n0 + wc * 64 + ni * 16 + l15;
            #pragma unroll
            for (int r = 0; r < 4; ++r) {
                const int row = m0 + wr * 64 + mi * 16 + lg * 4 + r;
                O[(size_t)row * 256 + col] = acc[mi][ni][r];
            }
        }
}

// ---------------------------------------------------------------------------
// Generic 3-pass split GEMM with epilogue.
// RESID: 0 none, 1 fp32, 2 split(hi+lo). OUTF32 / OUTBF16 select outputs.
// ---------------------------------------------------------------------------
template<int RESID, int RELU, int OUTF32, int OUTBF16>
__global__ __launch_bounds__(256)
void gemm3(const u16* __restrict__ Asp, size_t AMK, int K,
           const u16* __restrict__ wt, int boff,
           const float* __restrict__ bias, int Nd,
           const u16* __restrict__ Rsp, const float* __restrict__ Rf,
           float* __restrict__ Of, u16* __restrict__ Ob, size_t OMN, int l)
{
    const int s  = blockIdx.z;
    const int n0 = blockIdx.y * 128;
    const int m0 = blockIdx.x * 128;

    const u16* Ah = Asp + (size_t)s * (2 * AMK);
    const u16* Al = Ah + AMK;
    const u16* Bh = wt + (size_t)s * (2 * WSEG) + boff;
    const u16* Bl = Bh + WSEG;

    __shared__ u16 As[8192];
    __shared__ u16 Bs[8192];

    f32x4 acc[4][4];
    #pragma unroll
    for (int i = 0; i < 4; ++i)
        #pragma unroll
        for (int j = 0; j < 4; ++j) acc[i][j] = (f32x4){0.f, 0.f, 0.f, 0.f};

    auto pf = [&](int p, const u16*& Ap, const u16*& Bp) {
        Ap = (p == 1) ? Al : Ah;
        Bp = (p == 2) ? Bl : Bh;
    };
    mfma_core(acc, 3, K, m0, n0, As, Bs, pf);

    const float* bs = bias + (size_t)(l * 2 + s) * Nd;
    const int lane = threadIdx.x & 63, w = threadIdx.x >> 6;
    const int wr = w >> 1, wc = w & 1, l15 = lane & 15, lg = lane >> 4;

    #pragma unroll
    for (int mi = 0; mi < 4; ++mi)
        #pragma unroll
        for (int ni = 0; ni < 4; ++ni) {
            const int col = n0 + wc * 64 + ni * 16 + l15;
            const float bv = bs[col];
            #pragma unroll
            for (int r = 0; r < 4; ++r) {
                const int row = m0 + wr * 64 + mi * 16 + lg * 4 + r;
                const size_t idx = (size_t)row * Nd + col;
                float v = acc[mi][ni][r] + bv;
                if constexpr (RESID == 1) {
                    v += Rf[(size_t)s * PLX + idx];
                } else if constexpr (RESID == 2) {
                    const u16* Rh = Rsp + (size_t)s * (2 * PLX);
                    v += bf16_f(Rh[idx]) + bf16_f(Rh[PLX + idx]);
                }
                if constexpr (RELU) v = fmaxf(v, 0.f);
                if constexpr (OUTF32) Of[(size_t)s * PLX + idx] = v;
                if constexpr (OUTBF16) {
                    u16 hi, lo; split2(v, hi, lo);
                    u16* Oh = Ob + (size_t)s * (2 * OMN);
                    Oh[idx] = hi;
                    Oh[OMN + idx] = lo;
                }
            }
        }
}

// ---------------------------------------------------------------------------
// Attention (fp32): WG = (i-tile 32, b, s); 512 thr = 16 heads x 32 queries.
// Writes AO as split bf16 planes.
// ---------------------------------------------------------------------------
__global__ __launch_bounds__(512)
void attn_k(const float* __restrict__ Qb, const float* __restrict__ Kb,
            const float* __restrict__ Vb, const float* __restrict__ cost,
            u16* __restrict__ AOs)
{
    const int i0 = blockIdx.x * 32;
    const int b  = blockIdx.y;
    const int s  = blockIdx.z;

    __shared__ float Ks[32][256];
    __shared__ float Vs[32][256];
    __shared__ float Cs[32][33];

    const int tid = threadIdx.x;
    const int i = tid & 31, h = tid >> 5;

    float q[16];
    {
        const float* Qr = Qb + (size_t)s * PLX + (size_t)(b * NN + i0 + i) * EMB + h * 16;
        #pragma unroll
        for (int d4 = 0; d4 < 4; ++d4) {
            float4 v = *(const float4*)(Qr + d4 * 4);
            q[d4*4+0]=v.x; q[d4*4+1]=v.y; q[d4*4+2]=v.z; q[d4*4+3]=v.w;
        }
    }
    const float* cb = cost + (size_t)b * NN * NN;

    float m = -1e30f, l = 0.f;
    float acc[16] = {};

    for (int jt = 0; jt < 8; ++jt) {
        const int j0 = jt * 32;
        __syncthreads();
        {
            const float* Kr = Kb + (size_t)s * PLX + (size_t)(b * NN + j0) * EMB;
            const float* Vr = Vb + (size_t)s * PLX + (size_t)(b * NN + j0) * EMB;
            #pragma unroll
            for (int u = 0; u < 4; ++u) {
                int f = tid + 512 * u;
                int row = f >> 6, col = (f & 63) * 4;
                *(float4*)&Ks[row][col] = *(const float4*)(Kr + (size_t)row * EMB + col);
                *(float4*)&Vs[row][col] = *(const float4*)(Vr + (size_t)row * EMB + col);
            }
            if (tid < 256) {
                int r = tid >> 3, c4 = (tid & 7) * 4;
                if (s == 0) {
                    float4 v = *(const float4*)(cb + (size_t)(i0 + r) * NN + j0 + c4);
                    Cs[r][c4+0]=v.x; Cs[r][c4+1]=v.y; Cs[r][c4+2]=v.z; Cs[r][c4+3]=v.w;
                } else {
                    float4 v = *(const float4*)(cb + (size_t)(j0 + r) * NN + i0 + c4);
                    Cs[c4+0][r]=v.x; Cs[c4+1][r]=v.y; Cs[c4+2][r]=v.z; Cs[c4+3][r]=v.w;
                }
            }
        }
        __syncthreads();

        float sc[32];
        float tmax = -1e30f;
        #pragma unroll
        for (int j = 0; j < 32; ++j) {
            const float* kr = &Ks[j][h * 16];
            float dv = 0.f;
            #pragma unroll
            for (int d = 0; d < 16; ++d) dv += q[d] * kr[d];
            float v = dv * 0.25f + Cs[i][j];
            sc[j] = v;
            tmax = fmaxf(tmax, v);
        }
        float mnew = fmaxf(m, tmax);
        float scale = __expf(m - mnew);
        l *= scale;
        #pragma unroll
        for (int d = 0; d < 16; ++d) acc[d] *= scale;
        m = mnew;
        #pragma unroll
        for (int j = 0; j < 32; ++j) {
            float p = __expf(sc[j] - m);
            l += p;
            const float* vr = &Vs[j][h * 16];
            #pragma unroll
            for (int d = 0; d < 16; ++d) acc[d] += p * vr[d];
        }
    }

    const float inv = 1.f / l;
    u16* AOh = AOs + (size_t)s * (2 * PLX);
    u16* AOl = AOh + PLX;
    const size_t base = (size_t)(b * NN + i0 + i) * EMB + h * 16;
    #pragma unroll
    for (int d4 = 0; d4 < 4; ++d4) {
        u16 h0,l0,h1,l1,h2,l2,h3,l3;
        split2(acc[d4*4+0]*inv, h0, l0);
        split2(acc[d4*4+1]*inv, h1, l1);
        split2(acc[d4*4+2]*inv, h2, l2);
        split2(acc[d4*4+3]*inv, h3, l3);
        ushort4 vh; vh.x=h0; vh.y=h1; vh.z=h2; vh.w=h3;
        ushort4 vl; vl.x=l0; vl.y=l1; vl.z=l2; vl.w=l3;
        *(ushort4*)(AOh + base + d4 * 4) = vh;
        *(ushort4*)(AOl + base + d4 * 4) = vl;
    }
}

// ---------------------------------------------------------------------------
// InstanceNorm over node axis; writes split planes (+ optional fp32).
// ---------------------------------------------------------------------------
template<int WF32>
__global__ __launch_bounds__(256)
void inorm_k(const float* __restrict__ Xb,
             const float* __restrict__ gb, const float* __restrict__ bb,
             float* __restrict__ Yf, u16* __restrict__ Ysp, int l)
{
    const int bx = blockIdx.x;
    const int b = bx >> 2, cg = bx & 3;
    const int s = blockIdx.y;
    const float* X = Xb + (size_t)s * PLX + (size_t)b * NN * EMB;
    const int tid = threadIdx.x;
    const int cl = tid & 63, q = tid >> 6;
    const int c = cg * 64 + cl;

    float sum = 0.f, ss = 0.f;
    for (int n = q * 64; n < q * 64 + 64; ++n) {
        float x = X[(size_t)n * EMB + c];
        sum += x; ss += x * x;
    }
    __shared__ float Ssum[4][64], Sss[4][64], Sa[64], Sb2[64];
    Ssum[q][cl] = sum; Sss[q][cl] = ss;
    __syncthreads();
    if (q == 0) {
        float s4 = Ssum[0][cl] + Ssum[1][cl] + Ssum[2][cl] + Ssum[3][cl];
        float q4 = Sss[0][cl] + Sss[1][cl] + Sss[2][cl] + Sss[3][cl];
        float mean = s4 * (1.f / NN);
        float var  = q4 * (1.f / NN) - mean * mean;
        float inv  = rsqrtf(var + 1e-5f);
        float gv = gb[(size_t)(l * 2 + s) * EMB + c];
        float bv = bb[(size_t)(l * 2 + s) * EMB + c];
        float a = gv * inv;
        Sa[cl]  = a;
        Sb2[cl] = bv - mean * a;
    }
    __syncthreads();
    const float a = Sa[cl], b2 = Sb2[cl];
    u16* Yh = Ysp + (size_t)s * (2 * PLX) + (size_t)b * NN * EMB;
    u16* Yl = Yh + PLX;
    float* Yo = WF32 ? (Yf + (size_t)s * PLX + (size_t)b * NN * EMB) : nullptr;
    for (int n = q * 64; n < q * 64 + 64; ++n) {
        const size_t idx = (size_t)n * EMB + c;
        float y = X[idx] * a + b2;
        if constexpr (WF32) Yo[idx] = y;
        u16 hi, lo; split2(y, hi, lo);
        Yh[idx] = hi; Yl[idx] = lo;
    }
}

// ---------------------------------------------------------------------------
// Embedding -> split planes
// ---------------------------------------------------------------------------
__global__ __launch_bounds__(256)
void conv0_k(const float* __restrict__ rowe, const float* __restrict__ cole,
             u16* __restrict__ S0)
{
    const int side = blockIdx.y;
    const float* src = side ? cole : rowe;
    const size_t o = ((size_t)blockIdx.x * 256 + threadIdx.x) * 4;
    float4 v = *(const float4*)(src + o);
    u16 h0,l0,h1,l1,h2,l2,h3,l3;
    split2(v.x, h0, l0); split2(v.y, h1, l1);
    split2(v.z, h2, l2); split2(v.w, h3, l3);
    u16* Sh = S0 + (size_t)side * (2 * PLX);
    u16* Sl = Sh + PLX;
    ushort4 vh; vh.x=h0; vh.y=h1; vh.z=h2; vh.w=h3;
    ushort4 vl; vl.x=l0; vl.y=l1; vl.z=l2; vl.w=l3;
    *(ushort4*)(Sh + o) = vh;
    *(ushort4*)(Sl + o) = vl;
}

// ---------------------------------------------------------------------------
// Per-layer weight transpose + split:  W[k][n] -> Wt_hi/lo[n][k]
// 144 tiles x 2 sides; 64x64 tiles via LDS.
// ---------------------------------------------------------------------------
__global__ __launch_bounds__(256)
void wconv_k(const float* __restrict__ Wq, const float* __restrict__ Ws,
             const float* __restrict__ Wa, const float* __restrict__ Wv,
             const float* __restrict__ Wc, const float* __restrict__ W1,
             const float* __restrict__ W2, u16* __restrict__ wt, int l)
{
    const int t = blockIdx.x;
    const int s = blockIdx.y;
    const float* src; int Kd, Nd, tr, tc; size_t dsto;
    if (t < 80) {
        int m = t >> 4, tt = t & 15; tr = tt >> 2; tc = tt & 3; Kd = 256; Nd = 256;
        const float* w0;
        switch (m) {
            case 0: w0 = Wq; dsto = OQ; break;
            case 1: w0 = Ws; dsto = OS; break;
            case 2: w0 = Wa; dsto = OA; break;
            case 3: w0 = Wv; dsto = OV; break;
            default: w0 = Wc; dsto = OC; break;
        }
        src = w0 + (size_t)(l * 2 + s) * 65536;
    } else if (t < 112) {
        int tt = t - 80; tr = tt >> 3; tc = tt & 7; Kd = 256; Nd = 512;
        src = W1 + (size_t)(l * 2 + s) * 131072; dsto = O1;
    } else {
        int tt = t - 112; tr = tt >> 2; tc = tt & 3; Kd = 512; Nd = 256;
        src = W2 + (size_t)(l * 2 + s) * 131072; dsto = O2;
    }
    const int k0 = tr * 64, n0 = tc * 64;
    __shared__ float T[64][65];
    const int tid = threadIdx.x;
    {
        const int j4 = tid & 15, i0 = tid >> 4;
        #pragma unroll
        for (int ii = 0; ii < 4; ++ii) {
            int i = ii * 16 + i0;
            float4 v = *(const float4*)(src + (size_t)(k0 + i) * Nd + n0 + j4 * 4);
            T[i][j4*4+0] = v.x; T[i][j4*4+1] = v.y;
            T[i][j4*4+2] = v.z; T[i][j4*4+3] = v.w;
        }
    }
    __syncthreads();
    u16* Whi = wt + (size_t)s * (2 * WSEG) + dsto;
    u16* Wlo = Whi + WSEG;
    {
        const int k4 = tid & 15, j0 = tid >> 4;
        #pragma unroll
        for (int jj = 0; jj < 4; ++jj) {
            int j = jj * 16 + j0;
            int n = n0 + j;
            u16 h[4], lo[4];
            #pragma unroll
            for (int r = 0; r < 4; ++r) split2(T[k4*4+r][j], h[r], lo[r]);
            ushort4 vh; vh.x=h[0]; vh.y=h[1]; vh.z=h[2]; vh.w=h[3];
            ushort4 vl; vl.x=lo[0]; vl.y=lo[1]; vl.z=lo[2]; vl.w=lo[3];
            *(ushort4*)(Whi + (size_t)n * Kd + k0 + k4 * 4) = vh;
            *(ushort4*)(Wlo + (size_t)n * Kd + k0 + k4 * 4) = vl;
        }
    }
}

// ---------------------------------------------------------------------------
extern "C" void kernel_launch(void* const* d_in, const int* in_sizes, int n_in,
                              void* d_out, int out_size, void* d_ws, size_t ws_size,
                              hipStream_t stream)
{
    const float* row_emb = (const float*)d_in[0];
    const float* col_emb = (const float*)d_in[1];
    const float* cost    = (const float*)d_in[2];
    const float* Wq  = (const float*)d_in[3];
    const float* Ws  = (const float*)d_in[4];
    const float* Wa  = (const float*)d_in[5];
    const float* Wv  = (const float*)d_in[6];
    const float* Wc  = (const float*)d_in[7];
    const float* bc  = (const float*)d_in[8];
    const float* g1  = (const float*)d_in[9];
    const float* be1 = (const float*)d_in[10];
    const float* W1  = (const float*)d_in[11];
    const float* bf1 = (const float*)d_in[12];
    const float* W2  = (const float*)d_in[13];
    const float* bf2 = (const float*)d_in[14];
    const float* g2  = (const float*)d_in[15];
    const float* be2 = (const float*)d_in[16];

    char* W = (char*)d_ws;
    // arena: Sb0 0-16MB, Sb1 16-32, Qf 32-48, Kf 48-64, Vf 64-80, J 80-112, wt 112-116.5
    u16*   Sb[2] = { (u16*)(W + 0 * MB), (u16*)(W + 16 * MB) };
    float* Qf = (float*)(W + 32 * MB);
    float* Kf = (float*)(W + 48 * MB);
    float* Vf = (float*)(W + 64 * MB);
    u16*   Jb = (u16*)(W + 80 * MB);     // AO planes (16MB) then hS planes (32MB)
    u16*   wt = (u16*)(W + 112 * MB);

    conv0_k<<<dim3(2048, 2), 256, 0, stream>>>(row_emb, col_emb, Sb[0]);

    for (int l = 0; l < LL; ++l) {
        const int cur = l & 1;

        wconv_k<<<dim3(144, 2), 256, 0, stream>>>(Wq, Ws, Wa, Wv, Wc, W1, W2, wt, l);

        qkv_k<<<dim3(MTOT / 128, 6, 2), 256, 0, stream>>>(Sb[cur], wt, Qf, Kf, Vf);

        attn_k<<<dim3(NN / 32, BB, 2), 512, 0, stream>>>(Qf, Kf, Vf, cost, Jb);

        // y1 = AO@Wc + bc + x(split)  -> Kf
        gemm3<2, 0, 1, 0><<<dim3(MTOT / 128, 2, 2), 256, 0, stream>>>(
            Jb, PLX, 256, wt, OC, bc, 256, Sb[cur], nullptr, Kf, nullptr, 0, l);

        // o1 = inorm(y1) -> Qf (fp32) + Sb[cur] (planes)
        inorm_k<1><<<dim3(BB * 4, 2), 256, 0, stream>>>(Kf, g1, be1, Qf, Sb[cur], l);

        // h = relu(o1@W1 + bf1) -> Jb planes (8192x512)
        gemm3<0, 1, 0, 1><<<dim3(MTOT / 128, 4, 2), 256, 0, stream>>>(
            Sb[cur], PLX, 256, wt, O1, bf1, 512, nullptr, nullptr, nullptr, Jb, PLH, l);

        // y2 = h@W2 + bf2 + o1 -> Vf
        gemm3<1, 0, 1, 0><<<dim3(MTOT / 128, 2, 2), 256, 0, stream>>>(
            Jb, PLH, 512, wt, O2, bf2, 256, nullptr, Qf, Vf, nullptr, 0, l);

        // out = inorm(y2) -> Sb[1-cur] planes (+ d_out fp32 on last layer)
        if (l == LL - 1)
            inorm_k<1><<<dim3(BB * 4, 2), 256, 0, stream>>>(Vf, g2, be2,
                (float*)d_out, Sb[1 - cur], l);
        else
            inorm_k<0><<<dim3(BB * 4, 2), 256, 0, stream>>>(Vf, g2, be2,
                nullptr, Sb[1 - cur], l);
    }
    (void)in_sizes; (void)n_in; (void)out_size; (void)ws_size;
}

// Round 7
// 1402.656 us; speedup vs baseline: 1.8835x; 1.0904x over previous
//
#include <hip/hip_runtime.h>
#include <cstddef>
#include <cstdint>

#define EMB 256
#define NN  256
#define BB  32
#define FFD 512
#define LL  5
#define MTOT (BB*NN)          // 8192 rows

typedef unsigned short u16;
typedef short bf16x8 __attribute__((ext_vector_type(8)));
typedef float f32x4  __attribute__((ext_vector_type(4)));

static const size_t MB = 1048576ull;
static const size_t PLX = 2097152;     // 8192x256 plane (elements)
static const size_t PLH = 4194304;     // 8192x512 plane
static const size_t WSEG = 589824;
#define OQ 0
#define OS 65536
#define OA 131072
#define OV 196608
#define OC 262144
#define O1 327680
#define O2 458752

__device__ __forceinline__ u16 bf16_rne(float x) {
    unsigned u = __float_as_uint(x);
    unsigned r = u + 0x7FFF + ((u >> 16) & 1);
    return (u16)(r >> 16);
}
__device__ __forceinline__ float bf16_f(u16 h) {
    return __uint_as_float(((unsigned)h) << 16);
}
__device__ __forceinline__ void split2(float x, u16& hi, u16& lo) {
    hi = bf16_rne(x);
    lo = bf16_rne(x - bf16_f(hi));
}

__device__ __forceinline__ void gll16(const void* g, void* l) {
    __builtin_amdgcn_global_load_lds(
        (const __attribute__((address_space(1))) unsigned int*)g,
        (__attribute__((address_space(3))) unsigned int*)l,
        16, 0, 0);
}

// ---------------------------------------------------------------------------
// MFMA GEMM core (hardware-verified in round 5).
// ---------------------------------------------------------------------------
template<typename PF>
__device__ __forceinline__ void mfma_core(f32x4 (&acc)[4][4], int np, int K,
                                          int m0, int n0,
                                          u16* As, u16* Bs, PF pf)
{
    const int tid  = threadIdx.x;
    const int lane = tid & 63;
    const int w    = tid >> 6;
    const int wr   = w >> 1, wc = w & 1;
    const int l15  = lane & 15, lg = lane >> 4;

    for (int p = 0; p < np; ++p) {
        const u16 *Ap, *Bp;
        pf(p, Ap, Bp);
        const int nkt = K >> 6;
        for (int kt = 0; kt < nkt; ++kt) {
            __syncthreads();
            #pragma unroll
            for (int c = 0; c < 4; ++c) {
                int slot = w * 256 + c * 64 + lane;
                int row  = slot >> 3;
                int cc   = slot & 7;
                int kc   = cc ^ (row & 7);
                const u16* sa = Ap + (size_t)(m0 + row) * K + (kt << 6) + kc * 8;
                gll16(sa, As + (size_t)(w * 256 + c * 64) * 8);
                const u16* sb = Bp + (size_t)(n0 + row) * K + (kt << 6) + kc * 8;
                gll16(sb, Bs + (size_t)(w * 256 + c * 64) * 8);
            }
            __syncthreads();
            #pragma unroll
            for (int ks = 0; ks < 2; ++ks) {
                bf16x8 a[4], b[4];
                #pragma unroll
                for (int i = 0; i < 4; ++i) {
                    int arow = wr * 64 + i * 16 + l15;
                    int achk = (ks * 4 + lg) ^ (arow & 7);
                    a[i] = *(const bf16x8*)(As + ((arow << 3) + achk) * 8);
                    int brow = wc * 64 + i * 16 + l15;
                    int bchk = (ks * 4 + lg) ^ (brow & 7);
                    b[i] = *(const bf16x8*)(Bs + ((brow << 3) + bchk) * 8);
                }
                #pragma unroll
                for (int mi = 0; mi < 4; ++mi)
                    #pragma unroll
                    for (int ni = 0; ni < 4; ++ni)
                        acc[mi][ni] = __builtin_amdgcn_mfma_f32_16x16x32_bf16(
                            a[mi], b[ni], acc[mi][ni], 0, 0, 0);
            }
        }
    }
}

// ---------------------------------------------------------------------------
// Fused QKV. Outputs: Q,K as split bf16 row-major planes; V TRANSPOSED
// split planes Vt[s][plane][b][d][j].
// ---------------------------------------------------------------------------
__global__ __launch_bounds__(256)
void qkv_k(const u16* __restrict__ Ssp, const u16* __restrict__ wt,
           u16* __restrict__ Qsp, u16* __restrict__ Ksp, u16* __restrict__ Vtsp)
{
    const int s   = blockIdx.z;
    const int seg = blockIdx.y >> 1;
    const int n0  = (blockIdx.y & 1) * 128;
    const int m0  = blockIdx.x * 128;

    const u16* Xsh = Ssp + (size_t)s * (2 * PLX);
    const u16* Xsl = Xsh + PLX;
    const u16* Xoh = Ssp + (size_t)(1 - s) * (2 * PLX);
    const u16* Xol = Xoh + PLX;
    const u16* Wh  = wt + (size_t)s * (2 * WSEG);
    const u16* Wl  = Wh + WSEG;
    const int  np  = (seg == 1) ? 6 : 3;

    __shared__ u16 As[8192];
    __shared__ u16 Bs[8192];

    f32x4 acc[4][4];
    #pragma unroll
    for (int i = 0; i < 4; ++i)
        #pragma unroll
        for (int j = 0; j < 4; ++j) acc[i][j] = (f32x4){0.f, 0.f, 0.f, 0.f};

    auto pf = [&](int p, const u16*& Ap, const u16*& Bp) {
        int half = (p >= 3) ? 1 : 0;
        int pp = p - half * 3;
        const u16 *ah, *al; size_t wo;
        if (seg == 0)      { ah = Xsh; al = Xsl; wo = OQ; }
        else if (seg == 2) { ah = Xoh; al = Xol; wo = OV; }
        else if (!half)    { ah = Xsh; al = Xsl; wo = OS; }
        else               { ah = Xoh; al = Xol; wo = OA; }
        Ap = (pp == 1) ? al : ah;
        Bp = ((pp == 2) ? Wl : Wh) + wo;
    };
    mfma_core(acc, np, 256, m0, n0, As, Bs, pf);

    const int lane = threadIdx.x & 63, w = threadIdx.x >> 6;
    const int wr = w >> 1, wc = w & 1, l15 = lane & 15, lg = lane >> 4;

    if (seg <= 1) {
        u16* Oh = ((seg == 0) ? Qsp : Ksp) + (size_t)s * (2 * PLX);
        u16* Ol = Oh + PLX;
        #pragma unroll
        for (int mi = 0; mi < 4; ++mi)
            #pragma unroll
            for (int ni = 0; ni < 4; ++ni) {
                const int col = n0 + wc * 64 + ni * 16 + l15;
                #pragma unroll
                for (int r = 0; r < 4; ++r) {
                    const int row = m0 + wr * 64 + mi * 16 + lg * 4 + r;
                    const size_t idx = (size_t)row * 256 + col;
                    u16 hi, lo; split2(acc[mi][ni][r], hi, lo);
                    Oh[idx] = hi; Ol[idx] = lo;
                }
            }
    } else {
        const int bb = m0 >> 8;                // tile is within one batch row-block
        u16* Th = Vtsp + (size_t)s * (2 * PLX) + (size_t)bb * 65536;
        u16* Tl = Th + PLX;
        #pragma unroll
        for (int mi = 0; mi < 4; ++mi)
            #pragma unroll
            for (int ni = 0; ni < 4; ++ni) {
                const int col = n0 + wc * 64 + ni * 16 + l15;
                #pragma unroll
                for (int r = 0; r < 4; ++r) {
                    const int row = m0 + wr * 64 + mi * 16 + lg * 4 + r;
                    const size_t idx = (size_t)col * 256 + (row & 255);
                    u16 hi, lo; split2(acc[mi][ni][r], hi, lo);
                    Th[idx] = hi; Tl[idx] = lo;
                }
            }
    }
}

// ---------------------------------------------------------------------------
// Generic 3-pass split GEMM with epilogue.
// ---------------------------------------------------------------------------
template<int RESID, int RELU, int OUTF32, int OUTBF16>
__global__ __launch_bounds__(256)
void gemm3(const u16* __restrict__ Asp, size_t AMK, int K,
           const u16* __restrict__ wt, int boff,
           const float* __restrict__ bias, int Nd,
           const u16* __restrict__ Rsp, const float* __restrict__ Rf,
           float* __restrict__ Of, u16* __restrict__ Ob, size_t OMN, int l)
{
    const int s  = blockIdx.z;
    const int n0 = blockIdx.y * 128;
    const int m0 = blockIdx.x * 128;

    const u16* Ah = Asp + (size_t)s * (2 * AMK);
    const u16* Al = Ah + AMK;
    const u16* Bh = wt + (size_t)s * (2 * WSEG) + boff;
    const u16* Bl = Bh + WSEG;

    __shared__ u16 As[8192];
    __shared__ u16 Bs[8192];

    f32x4 acc[4][4];
    #pragma unroll
    for (int i = 0; i < 4; ++i)
        #pragma unroll
        for (int j = 0; j < 4; ++j) acc[i][j] = (f32x4){0.f, 0.f, 0.f, 0.f};

    auto pf = [&](int p, const u16*& Ap, const u16*& Bp) {
        Ap = (p == 1) ? Al : Ah;
        Bp = (p == 2) ? Bl : Bh;
    };
    mfma_core(acc, 3, K, m0, n0, As, Bs, pf);

    const float* bs = bias + (size_t)(l * 2 + s) * Nd;
    const int lane = threadIdx.x & 63, w = threadIdx.x >> 6;
    const int wr = w >> 1, wc = w & 1, l15 = lane & 15, lg = lane >> 4;

    #pragma unroll
    for (int mi = 0; mi < 4; ++mi)
        #pragma unroll
        for (int ni = 0; ni < 4; ++ni) {
            const int col = n0 + wc * 64 + ni * 16 + l15;
            const float bv = bs[col];
            #pragma unroll
            for (int r = 0; r < 4; ++r) {
                const int row = m0 + wr * 64 + mi * 16 + lg * 4 + r;
                const size_t idx = (size_t)row * Nd + col;
                float v = acc[mi][ni][r] + bv;
                if constexpr (RESID == 1) {
                    v += Rf[(size_t)s * PLX + idx];
                } else if constexpr (RESID == 2) {
                    const u16* Rh = Rsp + (size_t)s * (2 * PLX);
                    v += bf16_f(Rh[idx]) + bf16_f(Rh[PLX + idx]);
                }
                if constexpr (RELU) v = fmaxf(v, 0.f);
                if constexpr (OUTF32) Of[(size_t)s * PLX + idx] = v;
                if constexpr (OUTBF16) {
                    u16 hi, lo; split2(v, hi, lo);
                    u16* Oh = Ob + (size_t)s * (2 * OMN);
                    Oh[idx] = hi;
                    Oh[OMN + idx] = lo;
                }
            }
        }
}

// ---------------------------------------------------------------------------
// MFMA flash attention. Block = (i-block 32, b, s), 512 thr = 8 waves;
// wave handles 2 heads x 2 i-tiles(16). No LDS.
// ---------------------------------------------------------------------------
__global__ __launch_bounds__(512)
void attn_k(const u16* __restrict__ Qsp, const u16* __restrict__ Ksp,
            const u16* __restrict__ Vtsp, const float* __restrict__ cost,
            u16* __restrict__ AOs)
{
    const int i0 = blockIdx.x * 32;
    const int b  = blockIdx.y;
    const int s  = blockIdx.z;
    const int tid = threadIdx.x;
    const int lane = tid & 63;
    const int wv = tid >> 6;
    const int l15 = lane & 15, lg = lane >> 4;
    const int h0 = wv * 2;

    const u16* Qh = Qsp + (size_t)s * (2 * PLX);
    const u16* Ql = Qh + PLX;
    const u16* Kh = Ksp + (size_t)s * (2 * PLX);
    const u16* Kl = Kh + PLX;
    const u16* Vth = Vtsp + (size_t)s * (2 * PLX) + (size_t)b * 65536;
    const float* cb = cost + (size_t)b * NN * NN;

    // hoisted Q fragments
    bf16x8 qb1[2][2], qb2[2][2];
    #pragma unroll
    for (int hh = 0; hh < 2; ++hh)
        #pragma unroll
        for (int it = 0; it < 2; ++it) {
            const size_t qoff = (size_t)(b * NN + i0 + it * 16 + l15) * EMB
                              + (h0 + hh) * 16 + (lg & 1) * 8;
            qb1[hh][it] = *(const bf16x8*)(Qh + qoff);
            bf16x8 t = *(const bf16x8*)(Ql + qoff);
            if (lg >= 2) {
                #pragma unroll
                for (int e = 0; e < 8; ++e) t[e] = 0;
            }
            qb2[hh][it] = t;
        }

    float m_s[2][2], l_s[2][2];
    f32x4 occ[2][2];
    #pragma unroll
    for (int hh = 0; hh < 2; ++hh)
        #pragma unroll
        for (int it = 0; it < 2; ++it) {
            m_s[hh][it] = -1e30f;
            l_s[hh][it] = 0.f;
            occ[hh][it] = (f32x4){0.f, 0.f, 0.f, 0.f};
        }

    const int jperm = 8 * (l15 >> 2) + (l15 & 3);   // A-row m=l15 -> j offset

    for (int g = 0; g < 8; ++g) {
        const int jj0 = g * 32;

        // cost values for the scores this lane will hold: j = jj0+8*lg+4t+r
        float cst[2][8];
        #pragma unroll
        for (int it = 0; it < 2; ++it) {
            const int ib = i0 + it * 16 + l15;
            #pragma unroll
            for (int t = 0; t < 2; ++t) {
                if (s == 0) {
                    float4 cv = *(const float4*)(cb + (size_t)ib * NN + jj0 + 8 * lg + 4 * t);
                    cst[it][t*4+0] = cv.x; cst[it][t*4+1] = cv.y;
                    cst[it][t*4+2] = cv.z; cst[it][t*4+3] = cv.w;
                } else {
                    #pragma unroll
                    for (int r = 0; r < 4; ++r)
                        cst[it][t*4+r] = cb[(size_t)(jj0 + 8*lg + 4*t + r) * NN + ib];
                }
            }
        }

        #pragma unroll
        for (int hh = 0; hh < 2; ++hh) {
            const int h = h0 + hh;
            const u16* kpl = (lg < 2) ? Kh : Kl;
            const int kcol = h * 16 + (lg & 1) * 8;
            bf16x8 kA[2];
            #pragma unroll
            for (int t = 0; t < 2; ++t) {
                const int jrow = b * NN + jj0 + jperm + 4 * t;
                kA[t] = *(const bf16x8*)(kpl + (size_t)jrow * EMB + kcol);
            }
            const u16* vbase = Vth + (size_t)(h * 16 + l15) * NN + jj0 + lg * 8;
            bf16x8 vh = *(const bf16x8*)(vbase);
            bf16x8 vl = *(const bf16x8*)(vbase + PLX);

            #pragma unroll
            for (int it = 0; it < 2; ++it) {
                f32x4 st0 = (f32x4){0.f,0.f,0.f,0.f};
                f32x4 st1 = (f32x4){0.f,0.f,0.f,0.f};
                st0 = __builtin_amdgcn_mfma_f32_16x16x32_bf16(kA[0], qb1[hh][it], st0, 0,0,0);
                st0 = __builtin_amdgcn_mfma_f32_16x16x32_bf16(kA[0], qb2[hh][it], st0, 0,0,0);
                st1 = __builtin_amdgcn_mfma_f32_16x16x32_bf16(kA[1], qb1[hh][it], st1, 0,0,0);
                st1 = __builtin_amdgcn_mfma_f32_16x16x32_bf16(kA[1], qb2[hh][it], st1, 0,0,0);

                float sv[8];
                #pragma unroll
                for (int r = 0; r < 4; ++r) {
                    sv[r]     = st0[r] * 0.25f + cst[it][r];
                    sv[4 + r] = st1[r] * 0.25f + cst[it][4 + r];
                }
                float tm = sv[0];
                #pragma unroll
                for (int e = 1; e < 8; ++e) tm = fmaxf(tm, sv[e]);
                tm = fmaxf(tm, __shfl_xor(tm, 16));
                tm = fmaxf(tm, __shfl_xor(tm, 32));

                const float mo = m_s[hh][it];
                const float mn = fmaxf(mo, tm);
                const float sc = __expf(mo - mn);
                float p[8], ts = 0.f;
                #pragma unroll
                for (int e = 0; e < 8; ++e) { p[e] = __expf(sv[e] - mn); ts += p[e]; }
                ts += __shfl_xor(ts, 16);
                ts += __shfl_xor(ts, 32);
                l_s[hh][it] = l_s[hh][it] * sc + ts;
                m_s[hh][it] = mn;

                f32x4 o = occ[hh][it];
                o[0] *= sc; o[1] *= sc; o[2] *= sc; o[3] *= sc;
                bf16x8 pb;
                #pragma unroll
                for (int e = 0; e < 8; ++e) pb[e] = (short)bf16_rne(p[e]);
                o = __builtin_amdgcn_mfma_f32_16x16x32_bf16(vh, pb, o, 0,0,0);
                o = __builtin_amdgcn_mfma_f32_16x16x32_bf16(vl, pb, o, 0,0,0);
                occ[hh][it] = o;
            }
        }
    }

    u16* AOh = AOs + (size_t)s * (2 * PLX);
    u16* AOl = AOh + PLX;
    #pragma unroll
    for (int hh = 0; hh < 2; ++hh)
        #pragma unroll
        for (int it = 0; it < 2; ++it) {
            const float inv = 1.f / l_s[hh][it];
            const size_t base = (size_t)(b * NN + i0 + it * 16 + l15) * EMB
                              + (h0 + hh) * 16 + lg * 4;
            ushort4 vh4, vl4;
            u16 h_, l_;
            split2(occ[hh][it][0] * inv, h_, l_); vh4.x = h_; vl4.x = l_;
            split2(occ[hh][it][1] * inv, h_, l_); vh4.y = h_; vl4.y = l_;
            split2(occ[hh][it][2] * inv, h_, l_); vh4.z = h_; vl4.z = l_;
            split2(occ[hh][it][3] * inv, h_, l_); vh4.w = h_; vl4.w = l_;
            *(ushort4*)(AOh + base) = vh4;
            *(ushort4*)(AOl + base) = vl4;
        }
}

// ---------------------------------------------------------------------------
// InstanceNorm over node axis; writes split planes (+ optional fp32).
// ---------------------------------------------------------------------------
template<int WF32>
__global__ __launch_bounds__(256)
void inorm_k(const float* __restrict__ Xb,
             const float* __restrict__ gb, const float* __restrict__ bb,
             float* __restrict__ Yf, u16* __restrict__ Ysp, int l)
{
    const int bx = blockIdx.x;
    const int b = bx >> 2, cg = bx & 3;
    const int s = blockIdx.y;
    const float* X = Xb + (size_t)s * PLX + (size_t)b * NN * EMB;
    const int tid = threadIdx.x;
    const int cl = tid & 63, q = tid >> 6;
    const int c = cg * 64 + cl;

    float sum = 0.f, ss = 0.f;
    for (int n = q * 64; n < q * 64 + 64; ++n) {
        float x = X[(size_t)n * EMB + c];
        sum += x; ss += x * x;
    }
    __shared__ float Ssum[4][64], Sss[4][64], Sa[64], Sb2[64];
    Ssum[q][cl] = sum; Sss[q][cl] = ss;
    __syncthreads();
    if (q == 0) {
        float s4 = Ssum[0][cl] + Ssum[1][cl] + Ssum[2][cl] + Ssum[3][cl];
        float q4 = Sss[0][cl] + Sss[1][cl] + Sss[2][cl] + Sss[3][cl];
        float mean = s4 * (1.f / NN);
        float var  = q4 * (1.f / NN) - mean * mean;
        float inv  = rsqrtf(var + 1e-5f);
        float gv = gb[(size_t)(l * 2 + s) * EMB + c];
        float bv = bb[(size_t)(l * 2 + s) * EMB + c];
        float a = gv * inv;
        Sa[cl]  = a;
        Sb2[cl] = bv - mean * a;
    }
    __syncthreads();
    const float a = Sa[cl], b2 = Sb2[cl];
    u16* Yh = Ysp + (size_t)s * (2 * PLX) + (size_t)b * NN * EMB;
    u16* Yl = Yh + PLX;
    float* Yo = WF32 ? (Yf + (size_t)s * PLX + (size_t)b * NN * EMB) : nullptr;
    for (int n = q * 64; n < q * 64 + 64; ++n) {
        const size_t idx = (size_t)n * EMB + c;
        float y = X[idx] * a + b2;
        if constexpr (WF32) Yo[idx] = y;
        u16 hi, lo; split2(y, hi, lo);
        Yh[idx] = hi; Yl[idx] = lo;
    }
}

// ---------------------------------------------------------------------------
// Embedding -> split planes
// ---------------------------------------------------------------------------
__global__ __launch_bounds__(256)
void conv0_k(const float* __restrict__ rowe, const float* __restrict__ cole,
             u16* __restrict__ S0)
{
    const int side = blockIdx.y;
    const float* src = side ? cole : rowe;
    const size_t o = ((size_t)blockIdx.x * 256 + threadIdx.x) * 4;
    float4 v = *(const float4*)(src + o);
    u16 h0,l0,h1,l1,h2,l2,h3,l3;
    split2(v.x, h0, l0); split2(v.y, h1, l1);
    split2(v.z, h2, l2); split2(v.w, h3, l3);
    u16* Sh = S0 + (size_t)side * (2 * PLX);
    u16* Sl = Sh + PLX;
    ushort4 vh; vh.x=h0; vh.y=h1; vh.z=h2; vh.w=h3;
    ushort4 vl; vl.x=l0; vl.y=l1; vl.z=l2; vl.w=l3;
    *(ushort4*)(Sh + o) = vh;
    *(ushort4*)(Sl + o) = vl;
}

// ---------------------------------------------------------------------------
// Per-layer weight transpose + split.
// ---------------------------------------------------------------------------
__global__ __launch_bounds__(256)
void wconv_k(const float* __restrict__ Wq, const float* __restrict__ Ws,
             const float* __restrict__ Wa, const float* __restrict__ Wv,
             const float* __restrict__ Wc, const float* __restrict__ W1,
             const float* __restrict__ W2, u16* __restrict__ wt, int l)
{
    const int t = blockIdx.x;
    const int s = blockIdx.y;
    const float* src; int Kd, Nd, tr, tc; size_t dsto;
    if (t < 80) {
        int m = t >> 4, tt = t & 15; tr = tt >> 2; tc = tt & 3; Kd = 256; Nd = 256;
        const float* w0;
        switch (m) {
            case 0: w0 = Wq; dsto = OQ; break;
            case 1: w0 = Ws; dsto = OS; break;
            case 2: w0 = Wa; dsto = OA; break;
            case 3: w0 = Wv; dsto = OV; break;
            default: w0 = Wc; dsto = OC; break;
        }
        src = w0 + (size_t)(l * 2 + s) * 65536;
    } else if (t < 112) {
        int tt = t - 80; tr = tt >> 3; tc = tt & 7; Kd = 256; Nd = 512;
        src = W1 + (size_t)(l * 2 + s) * 131072; dsto = O1;
    } else {
        int tt = t - 112; tr = tt >> 2; tc = tt & 3; Kd = 512; Nd = 256;
        src = W2 + (size_t)(l * 2 + s) * 131072; dsto = O2;
    }
    const int k0 = tr * 64, n0 = tc * 64;
    __shared__ float T[64][65];
    const int tid = threadIdx.x;
    {
        const int j4 = tid & 15, i0 = tid >> 4;
        #pragma unroll
        for (int ii = 0; ii < 4; ++ii) {
            int i = ii * 16 + i0;
            float4 v = *(const float4*)(src + (size_t)(k0 + i) * Nd + n0 + j4 * 4);
            T[i][j4*4+0] = v.x; T[i][j4*4+1] = v.y;
            T[i][j4*4+2] = v.z; T[i][j4*4+3] = v.w;
        }
    }
    __syncthreads();
    u16* Whi = wt + (size_t)s * (2 * WSEG) + dsto;
    u16* Wlo = Whi + WSEG;
    {
        const int k4 = tid & 15, j0 = tid >> 4;
        #pragma unroll
        for (int jj = 0; jj < 4; ++jj) {
            int j = jj * 16 + j0;
            int n = n0 + j;
            u16 h[4], lo[4];
            #pragma unroll
            for (int r = 0; r < 4; ++r) split2(T[k4*4+r][j], h[r], lo[r]);
            ushort4 vh; vh.x=h[0]; vh.y=h[1]; vh.z=h[2]; vh.w=h[3];
            ushort4 vl; vl.x=lo[0]; vl.y=lo[1]; vl.z=lo[2]; vl.w=lo[3];
            *(ushort4*)(Whi + (size_t)n * Kd + k0 + k4 * 4) = vh;
            *(ushort4*)(Wlo + (size_t)n * Kd + k0 + k4 * 4) = vl;
        }
    }
}

// ---------------------------------------------------------------------------
// Workspace arena (128 MB, liveness-audited):
//  0-16 Sb0 | 16-32 Sb1 | 32-48 Qsp->o1sp | 48-64 Ksp->y1f->y2f
// 64-80 Vtsp->o1f | 80-84.5 wt | 96-112 AO -> 96-128 h planes
// ---------------------------------------------------------------------------
extern "C" void kernel_launch(void* const* d_in, const int* in_sizes, int n_in,
                              void* d_out, int out_size, void* d_ws, size_t ws_size,
                              hipStream_t stream)
{
    const float* row_emb = (const float*)d_in[0];
    const float* col_emb = (const float*)d_in[1];
    const float* cost    = (const float*)d_in[2];
    const float* Wq  = (const float*)d_in[3];
    const float* Ws  = (const float*)d_in[4];
    const float* Wa  = (const float*)d_in[5];
    const float* Wv  = (const float*)d_in[6];
    const float* Wc  = (const float*)d_in[7];
    const float* bc  = (const float*)d_in[8];
    const float* g1  = (const float*)d_in[9];
    const float* be1 = (const float*)d_in[10];
    const float* W1  = (const float*)d_in[11];
    const float* bf1 = (const float*)d_in[12];
    const float* W2  = (const float*)d_in[13];
    const float* bf2 = (const float*)d_in[14];
    const float* g2  = (const float*)d_in[15];
    const float* be2 = (const float*)d_in[16];

    char* W = (char*)d_ws;
    u16*   Sb[2]  = { (u16*)(W + 0 * MB), (u16*)(W + 16 * MB) };
    u16*   Qsp    = (u16*)(W + 32 * MB);
    u16*   Ksp    = (u16*)(W + 48 * MB);
    u16*   Vtsp   = (u16*)(W + 64 * MB);
    u16*   wt     = (u16*)(W + 80 * MB);
    u16*   AOsp   = (u16*)(W + 96 * MB);
    u16*   o1sp   = (u16*)(W + 32 * MB);     // alias Qsp (dead after attn)
    float* y1f    = (float*)(W + 48 * MB);   // alias Ksp (dead after attn)
    float* o1f    = (float*)(W + 64 * MB);   // alias Vtsp (dead after attn)
    u16*   hsp    = (u16*)(W + 96 * MB);     // alias AO (dead after Wc gemm)
    float* y2f    = (float*)(W + 48 * MB);   // alias y1 (dead after inorm1)

    conv0_k<<<dim3(2048, 2), 256, 0, stream>>>(row_emb, col_emb, Sb[0]);

    for (int l = 0; l < LL; ++l) {
        const int cur = l & 1;

        wconv_k<<<dim3(144, 2), 256, 0, stream>>>(Wq, Ws, Wa, Wv, Wc, W1, W2, wt, l);

        qkv_k<<<dim3(MTOT / 128, 6, 2), 256, 0, stream>>>(Sb[cur], wt, Qsp, Ksp, Vtsp);

        attn_k<<<dim3(8, BB, 2), 512, 0, stream>>>(Qsp, Ksp, Vtsp, cost, AOsp);

        // y1 = AO@Wc + bc + x(split)  -> y1f
        gemm3<2, 0, 1, 0><<<dim3(MTOT / 128, 2, 2), 256, 0, stream>>>(
            AOsp, PLX, 256, wt, OC, bc, 256, Sb[cur], nullptr, y1f, nullptr, 0, l);

        // o1 = inorm(y1) -> o1f (fp32) + o1sp (planes)
        inorm_k<1><<<dim3(BB * 4, 2), 256, 0, stream>>>(y1f, g1, be1, o1f, o1sp, l);

        // h = relu(o1@W1 + bf1) -> hsp planes
        gemm3<0, 1, 0, 1><<<dim3(MTOT / 128, 4, 2), 256, 0, stream>>>(
            o1sp, PLX, 256, wt, O1, bf1, 512, nullptr, nullptr, nullptr, hsp, PLH, l);

        // y2 = h@W2 + bf2 + o1 -> y2f
        gemm3<1, 0, 1, 0><<<dim3(MTOT / 128, 2, 2), 256, 0, stream>>>(
            hsp, PLH, 512, wt, O2, bf2, 256, nullptr, o1f, y2f, nullptr, 0, l);

        // out = inorm(y2) -> Sb[1-cur] planes (+ d_out fp32 on last layer)
        if (l == LL - 1)
            inorm_k<1><<<dim3(BB * 4, 2), 256, 0, stream>>>(y2f, g2, be2,
                (float*)d_out, Sb[1 - cur], l);
        else
            inorm_k<0><<<dim3(BB * 4, 2), 256, 0, stream>>>(y2f, g2, be2,
                nullptr, Sb[1 - cur], l);
    }
    (void)in_sizes; (void)n_in; (void)out_size; (void)ws_size;
}

// Round 8
// 1115.736 us; speedup vs baseline: 2.3679x; 1.2572x over previous
//
#include <hip/hip_runtime.h>
#include <cstddef>
#include <cstdint>

#define EMB 256
#define NN  256
#define BB  32
#define FFD 512
#define LL  5
#define MTOT (BB*NN)          // 8192 rows

typedef unsigned short u16;
typedef short bf16x8 __attribute__((ext_vector_type(8)));
typedef float f32x4  __attribute__((ext_vector_type(4)));

static const size_t MB = 1048576ull;
static const size_t PLX = 2097152;     // 8192x256 plane (elements)
static const size_t PLH = 4194304;     // 8192x512 plane
static const size_t WSEG = 589824;
#define OQ 0
#define OS 65536
#define OA 131072
#define OV 196608
#define OC 262144
#define O1 327680
#define O2 458752

__device__ __forceinline__ u16 bf16_rne(float x) {
    unsigned u = __float_as_uint(x);
    unsigned r = u + 0x7FFF + ((u >> 16) & 1);
    return (u16)(r >> 16);
}
__device__ __forceinline__ float bf16_f(u16 h) {
    return __uint_as_float(((unsigned)h) << 16);
}
__device__ __forceinline__ void split2(float x, u16& hi, u16& lo) {
    hi = bf16_rne(x);
    lo = bf16_rne(x - bf16_f(hi));
}

__device__ __forceinline__ void gll16(const void* g, void* l) {
    __builtin_amdgcn_global_load_lds(
        (const __attribute__((address_space(1))) unsigned int*)g,
        (__attribute__((address_space(3))) unsigned int*)l,
        16, 0, 0);
}

// ---------------------------------------------------------------------------
// MFMA GEMM core, single-staging 3-term split: per K-tile stage
// {Ah,Al,Bh,Bl} once, then acc += Ah*Bh + Al*Bh + Ah*Bl (96 MFMA per
// barrier pair). Swizzle/fragment layout identical to the HW-verified round-5
// core (source-side XOR chunk swizzle + same XOR on LDS read).
// ---------------------------------------------------------------------------
template<typename PF>
__device__ __forceinline__ void mfma_core3(f32x4 (&acc)[4][4], int nsp, int K,
                                           int m0, int n0,
                                           u16* AsH, u16* AsL,
                                           u16* BsH, u16* BsL, PF pf)
{
    const int tid  = threadIdx.x;
    const int lane = tid & 63;
    const int w    = tid >> 6;
    const int wr   = w >> 1, wc = w & 1;
    const int l15  = lane & 15, lg = lane >> 4;

    for (int p = 0; p < nsp; ++p) {
        const u16 *Ah, *Al, *Bh, *Bl;
        pf(p, Ah, Al, Bh, Bl);
        const int nkt = K >> 6;
        for (int kt = 0; kt < nkt; ++kt) {
            __syncthreads();
            #pragma unroll
            for (int c = 0; c < 4; ++c) {
                int slot = w * 256 + c * 64 + lane;
                int row  = slot >> 3;
                int cc   = slot & 7;
                int kc   = cc ^ (row & 7);
                const size_t ga = (size_t)(m0 + row) * K + (kt << 6) + kc * 8;
                const size_t gb = (size_t)(n0 + row) * K + (kt << 6) + kc * 8;
                const int lo = (w * 256 + c * 64) * 8;
                gll16(Ah + ga, AsH + lo);
                gll16(Al + ga, AsL + lo);
                gll16(Bh + gb, BsH + lo);
                gll16(Bl + gb, BsL + lo);
            }
            __syncthreads();
            #pragma unroll
            for (int ks = 0; ks < 2; ++ks) {
                bf16x8 ah[4], al[4], bh[4], bl[4];
                #pragma unroll
                for (int i = 0; i < 4; ++i) {
                    int arow = wr * 64 + i * 16 + l15;
                    int aoff = ((arow << 3) + ((ks * 4 + lg) ^ (arow & 7))) * 8;
                    ah[i] = *(const bf16x8*)(AsH + aoff);
                    al[i] = *(const bf16x8*)(AsL + aoff);
                    int brow = wc * 64 + i * 16 + l15;
                    int boff = ((brow << 3) + ((ks * 4 + lg) ^ (brow & 7))) * 8;
                    bh[i] = *(const bf16x8*)(BsH + boff);
                    bl[i] = *(const bf16x8*)(BsL + boff);
                }
                #pragma unroll
                for (int mi = 0; mi < 4; ++mi)
                    #pragma unroll
                    for (int ni = 0; ni < 4; ++ni) {
                        acc[mi][ni] = __builtin_amdgcn_mfma_f32_16x16x32_bf16(
                            ah[mi], bh[ni], acc[mi][ni], 0, 0, 0);
                        acc[mi][ni] = __builtin_amdgcn_mfma_f32_16x16x32_bf16(
                            al[mi], bh[ni], acc[mi][ni], 0, 0, 0);
                        acc[mi][ni] = __builtin_amdgcn_mfma_f32_16x16x32_bf16(
                            ah[mi], bl[ni], acc[mi][ni], 0, 0, 0);
                    }
            }
        }
    }
}

// ---------------------------------------------------------------------------
// Fused QKV. Outputs: Q,K split bf16 row-major planes; V transposed split
// planes Vt[s][plane][b][d][j].
// ---------------------------------------------------------------------------
__global__ __launch_bounds__(256)
void qkv_k(const u16* __restrict__ Ssp, const u16* __restrict__ wt,
           u16* __restrict__ Qsp, u16* __restrict__ Ksp, u16* __restrict__ Vtsp)
{
    const int s   = blockIdx.z;
    const int seg = blockIdx.y >> 1;
    const int n0  = (blockIdx.y & 1) * 128;
    const int m0  = blockIdx.x * 128;

    const u16* Xsh = Ssp + (size_t)s * (2 * PLX);
    const u16* Xsl = Xsh + PLX;
    const u16* Xoh = Ssp + (size_t)(1 - s) * (2 * PLX);
    const u16* Xol = Xoh + PLX;
    const u16* Wh  = wt + (size_t)s * (2 * WSEG);
    const u16* Wl  = Wh + WSEG;
    const int  nsp = (seg == 1) ? 2 : 1;

    __shared__ u16 AsH[8192], AsL[8192], BsH[8192], BsL[8192];

    f32x4 acc[4][4];
    #pragma unroll
    for (int i = 0; i < 4; ++i)
        #pragma unroll
        for (int j = 0; j < 4; ++j) acc[i][j] = (f32x4){0.f, 0.f, 0.f, 0.f};

    auto pf = [&](int p, const u16*& Ah, const u16*& Al,
                  const u16*& Bh, const u16*& Bl) {
        if (seg == 0)      { Ah = Xsh; Al = Xsl; Bh = Wh + OQ; Bl = Wl + OQ; }
        else if (seg == 2) { Ah = Xoh; Al = Xol; Bh = Wh + OV; Bl = Wl + OV; }
        else if (p == 0)   { Ah = Xsh; Al = Xsl; Bh = Wh + OS; Bl = Wl + OS; }
        else               { Ah = Xoh; Al = Xol; Bh = Wh + OA; Bl = Wl + OA; }
    };
    mfma_core3(acc, nsp, 256, m0, n0, AsH, AsL, BsH, BsL, pf);

    const int lane = threadIdx.x & 63, w = threadIdx.x >> 6;
    const int wr = w >> 1, wc = w & 1, l15 = lane & 15, lg = lane >> 4;

    if (seg <= 1) {
        u16* Oh = ((seg == 0) ? Qsp : Ksp) + (size_t)s * (2 * PLX);
        u16* Ol = Oh + PLX;
        #pragma unroll
        for (int mi = 0; mi < 4; ++mi)
            #pragma unroll
            for (int ni = 0; ni < 4; ++ni) {
                const int col = n0 + wc * 64 + ni * 16 + l15;
                #pragma unroll
                for (int r = 0; r < 4; ++r) {
                    const int row = m0 + wr * 64 + mi * 16 + lg * 4 + r;
                    const size_t idx = (size_t)row * 256 + col;
                    u16 hi, lo; split2(acc[mi][ni][r], hi, lo);
                    Oh[idx] = hi; Ol[idx] = lo;
                }
            }
    } else {
        const int bb = m0 >> 8;
        u16* Th = Vtsp + (size_t)s * (2 * PLX) + (size_t)bb * 65536;
        u16* Tl = Th + PLX;
        #pragma unroll
        for (int mi = 0; mi < 4; ++mi)
            #pragma unroll
            for (int ni = 0; ni < 4; ++ni) {
                const int col = n0 + wc * 64 + ni * 16 + l15;
                #pragma unroll
                for (int r = 0; r < 4; ++r) {
                    const int row = m0 + wr * 64 + mi * 16 + lg * 4 + r;
                    const size_t idx = (size_t)col * 256 + (row & 255);
                    u16 hi, lo; split2(acc[mi][ni][r], hi, lo);
                    Th[idx] = hi; Tl[idx] = lo;
                }
            }
    }
}

// ---------------------------------------------------------------------------
// Generic single-staging 3-term GEMM with epilogue.
// ---------------------------------------------------------------------------
template<int RESID, int RELU, int OUTF32, int OUTBF16>
__global__ __launch_bounds__(256)
void gemm3(const u16* __restrict__ Asp, size_t AMK, int K,
           const u16* __restrict__ wt, int boff,
           const float* __restrict__ bias, int Nd,
           const u16* __restrict__ Rsp, const float* __restrict__ Rf,
           float* __restrict__ Of, u16* __restrict__ Ob, size_t OMN, int l)
{
    const int s  = blockIdx.z;
    const int n0 = blockIdx.y * 128;
    const int m0 = blockIdx.x * 128;

    const u16* Ah0 = Asp + (size_t)s * (2 * AMK);
    const u16* Al0 = Ah0 + AMK;
    const u16* Bh0 = wt + (size_t)s * (2 * WSEG) + boff;
    const u16* Bl0 = Bh0 + WSEG;

    __shared__ u16 AsH[8192], AsL[8192], BsH[8192], BsL[8192];

    f32x4 acc[4][4];
    #pragma unroll
    for (int i = 0; i < 4; ++i)
        #pragma unroll
        for (int j = 0; j < 4; ++j) acc[i][j] = (f32x4){0.f, 0.f, 0.f, 0.f};

    auto pf = [&](int p, const u16*& Ah, const u16*& Al,
                  const u16*& Bh, const u16*& Bl) {
        Ah = Ah0; Al = Al0; Bh = Bh0; Bl = Bl0;
    };
    mfma_core3(acc, 1, K, m0, n0, AsH, AsL, BsH, BsL, pf);

    const float* bs = bias + (size_t)(l * 2 + s) * Nd;
    const int lane = threadIdx.x & 63, w = threadIdx.x >> 6;
    const int wr = w >> 1, wc = w & 1, l15 = lane & 15, lg = lane >> 4;

    #pragma unroll
    for (int mi = 0; mi < 4; ++mi)
        #pragma unroll
        for (int ni = 0; ni < 4; ++ni) {
            const int col = n0 + wc * 64 + ni * 16 + l15;
            const float bv = bs[col];
            #pragma unroll
            for (int r = 0; r < 4; ++r) {
                const int row = m0 + wr * 64 + mi * 16 + lg * 4 + r;
                const size_t idx = (size_t)row * Nd + col;
                float v = acc[mi][ni][r] + bv;
                if constexpr (RESID == 1) {
                    v += Rf[(size_t)s * PLX + idx];
                } else if constexpr (RESID == 2) {
                    const u16* Rh = Rsp + (size_t)s * (2 * PLX);
                    v += bf16_f(Rh[idx]) + bf16_f(Rh[PLX + idx]);
                }
                if constexpr (RELU) v = fmaxf(v, 0.f);
                if constexpr (OUTF32) Of[(size_t)s * PLX + idx] = v;
                if constexpr (OUTBF16) {
                    u16 hi, lo; split2(v, hi, lo);
                    u16* Oh = Ob + (size_t)s * (2 * OMN);
                    Oh[idx] = hi;
                    Oh[OMN + idx] = lo;
                }
            }
        }
}

// ---------------------------------------------------------------------------
// MFMA flash attention v3. Block = (i-block 32, b, s), 512 thr = 8 waves.
// Cost tile through double-buffered LDS (staged once per block, coalesced,
// shared by all 8 waves); K/V fragments prefetched one g ahead in registers.
// ---------------------------------------------------------------------------
__global__ __launch_bounds__(512)
void attn_k(const u16* __restrict__ Qsp, const u16* __restrict__ Ksp,
            const u16* __restrict__ Vtsp, const float* __restrict__ cost,
            u16* __restrict__ AOs)
{
    const int i0 = blockIdx.x * 32;
    const int b  = blockIdx.y;
    const int s  = blockIdx.z;
    const int tid = threadIdx.x;
    const int lane = tid & 63;
    const int wv = tid >> 6;
    const int l15 = lane & 15, lg = lane >> 4;
    const int h0 = wv * 2;

    const u16* Qh = Qsp + (size_t)s * (2 * PLX);
    const u16* Ql = Qh + PLX;
    const u16* Kh = Ksp + (size_t)s * (2 * PLX);
    const u16* Kl = Kh + PLX;
    const u16* Vth = Vtsp + (size_t)s * (2 * PLX) + (size_t)b * 65536;
    const float* cb = cost + (size_t)b * NN * NN;

    __shared__ float Cs[2][32][36];   // [buf][i][j], pad 36

    // hoisted Q fragments
    bf16x8 qb1[2][2], qb2[2][2];
    #pragma unroll
    for (int hh = 0; hh < 2; ++hh)
        #pragma unroll
        for (int it = 0; it < 2; ++it) {
            const size_t qoff = (size_t)(b * NN + i0 + it * 16 + l15) * EMB
                              + (h0 + hh) * 16 + (lg & 1) * 8;
            qb1[hh][it] = *(const bf16x8*)(Qh + qoff);
            bf16x8 t = *(const bf16x8*)(Ql + qoff);
            if (lg >= 2) {
                #pragma unroll
                for (int e = 0; e < 8; ++e) t[e] = 0;
            }
            qb2[hh][it] = t;
        }

    float m_s[2][2], l_s[2][2];
    f32x4 occ[2][2];
    #pragma unroll
    for (int hh = 0; hh < 2; ++hh)
        #pragma unroll
        for (int it = 0; it < 2; ++it) {
            m_s[hh][it] = -1e30f;
            l_s[hh][it] = 0.f;
            occ[hh][it] = (f32x4){0.f, 0.f, 0.f, 0.f};
        }

    const int jperm = 8 * (l15 >> 2) + (l15 & 3);

    auto stageCost = [&](int g, int buf) {
        if (tid < 256) {
            if (s == 0) {
                const int i = tid >> 3, j4 = (tid & 7) * 4;
                float4 cv = *(const float4*)(cb + (size_t)(i0 + i) * NN + g * 32 + j4);
                Cs[buf][i][j4+0] = cv.x; Cs[buf][i][j4+1] = cv.y;
                Cs[buf][i][j4+2] = cv.z; Cs[buf][i][j4+3] = cv.w;
            } else {
                const int j = tid >> 3, i4 = (tid & 7) * 4;
                float4 cv = *(const float4*)(cb + (size_t)(g * 32 + j) * NN + i0 + i4);
                Cs[buf][i4+0][j] = cv.x; Cs[buf][i4+1][j] = cv.y;
                Cs[buf][i4+2][j] = cv.z; Cs[buf][i4+3][j] = cv.w;
            }
        }
    };

    auto loadKV = [&](int g, bf16x8 (&kA)[2][2], bf16x8 (&vv)[2][2]) {
        const int jj0 = g * 32;
        #pragma unroll
        for (int hh = 0; hh < 2; ++hh) {
            const int h = h0 + hh;
            const u16* kpl = (lg < 2) ? Kh : Kl;
            const int kcol = h * 16 + (lg & 1) * 8;
            #pragma unroll
            for (int t = 0; t < 2; ++t)
                kA[hh][t] = *(const bf16x8*)(kpl
                    + (size_t)(b * NN + jj0 + jperm + 4 * t) * EMB + kcol);
            const u16* vbase = Vth + (size_t)(h * 16 + l15) * NN + jj0 + lg * 8;
            vv[hh][0] = *(const bf16x8*)(vbase);
            vv[hh][1] = *(const bf16x8*)(vbase + PLX);
        }
    };

    bf16x8 kA0[2][2], vv0[2][2], kA1[2][2], vv1[2][2];
    stageCost(0, 0);
    loadKV(0, kA0, vv0);
    __syncthreads();

    auto iter = [&](int g, int cur,
                    bf16x8 (&kAc)[2][2], bf16x8 (&vvc)[2][2],
                    bf16x8 (&kAn)[2][2], bf16x8 (&vvn)[2][2]) {
        if (g < 7) {
            stageCost(g + 1, cur ^ 1);
            loadKV(g + 1, kAn, vvn);
        }
        float cst[2][8];
        #pragma unroll
        for (int it = 0; it < 2; ++it)
            #pragma unroll
            for (int t = 0; t < 2; ++t) {
                float4 cv = *(const float4*)&Cs[cur][it * 16 + l15][8 * lg + 4 * t];
                cst[it][t*4+0] = cv.x; cst[it][t*4+1] = cv.y;
                cst[it][t*4+2] = cv.z; cst[it][t*4+3] = cv.w;
            }
        #pragma unroll
        for (int hh = 0; hh < 2; ++hh) {
            #pragma unroll
            for (int it = 0; it < 2; ++it) {
                f32x4 st0 = (f32x4){0.f,0.f,0.f,0.f};
                f32x4 st1 = (f32x4){0.f,0.f,0.f,0.f};
                st0 = __builtin_amdgcn_mfma_f32_16x16x32_bf16(kAc[hh][0], qb1[hh][it], st0, 0,0,0);
                st0 = __builtin_amdgcn_mfma_f32_16x16x32_bf16(kAc[hh][0], qb2[hh][it], st0, 0,0,0);
                st1 = __builtin_amdgcn_mfma_f32_16x16x32_bf16(kAc[hh][1], qb1[hh][it], st1, 0,0,0);
                st1 = __builtin_amdgcn_mfma_f32_16x16x32_bf16(kAc[hh][1], qb2[hh][it], st1, 0,0,0);

                float sv[8];
                #pragma unroll
                for (int r = 0; r < 4; ++r) {
                    sv[r]     = st0[r] * 0.25f + cst[it][r];
                    sv[4 + r] = st1[r] * 0.25f + cst[it][4 + r];
                }
                float tm = sv[0];
                #pragma unroll
                for (int e = 1; e < 8; ++e) tm = fmaxf(tm, sv[e]);
                tm = fmaxf(tm, __shfl_xor(tm, 16));
                tm = fmaxf(tm, __shfl_xor(tm, 32));

                const float mo = m_s[hh][it];
                const float mn = fmaxf(mo, tm);
                const float sc = __expf(mo - mn);
                float p[8], ts = 0.f;
                #pragma unroll
                for (int e = 0; e < 8; ++e) { p[e] = __expf(sv[e] - mn); ts += p[e]; }
                ts += __shfl_xor(ts, 16);
                ts += __shfl_xor(ts, 32);
                l_s[hh][it] = l_s[hh][it] * sc + ts;
                m_s[hh][it] = mn;

                f32x4 o = occ[hh][it];
                o[0] *= sc; o[1] *= sc; o[2] *= sc; o[3] *= sc;
                bf16x8 pb;
                #pragma unroll
                for (int e = 0; e < 8; ++e) pb[e] = (short)bf16_rne(p[e]);
                o = __builtin_amdgcn_mfma_f32_16x16x32_bf16(vvc[hh][0], pb, o, 0,0,0);
                o = __builtin_amdgcn_mfma_f32_16x16x32_bf16(vvc[hh][1], pb, o, 0,0,0);
                occ[hh][it] = o;
            }
        }
        __syncthreads();
    };

    for (int gp = 0; gp < 8; gp += 2) {
        iter(gp,     0, kA0, vv0, kA1, vv1);
        iter(gp + 1, 1, kA1, vv1, kA0, vv0);
    }

    u16* AOh = AOs + (size_t)s * (2 * PLX);
    u16* AOl = AOh + PLX;
    #pragma unroll
    for (int hh = 0; hh < 2; ++hh)
        #pragma unroll
        for (int it = 0; it < 2; ++it) {
            const float inv = 1.f / l_s[hh][it];
            const size_t base = (size_t)(b * NN + i0 + it * 16 + l15) * EMB
                              + (h0 + hh) * 16 + lg * 4;
            ushort4 vh4, vl4;
            u16 h_, l_;
            split2(occ[hh][it][0] * inv, h_, l_); vh4.x = h_; vl4.x = l_;
            split2(occ[hh][it][1] * inv, h_, l_); vh4.y = h_; vl4.y = l_;
            split2(occ[hh][it][2] * inv, h_, l_); vh4.z = h_; vl4.z = l_;
            split2(occ[hh][it][3] * inv, h_, l_); vh4.w = h_; vl4.w = l_;
            *(ushort4*)(AOh + base) = vh4;
            *(ushort4*)(AOl + base) = vl4;
        }
}

// ---------------------------------------------------------------------------
// InstanceNorm over node axis; writes split planes (+ optional fp32).
// ---------------------------------------------------------------------------
template<int WF32>
__global__ __launch_bounds__(256)
void inorm_k(const float* __restrict__ Xb,
             const float* __restrict__ gb, const float* __restrict__ bb,
             float* __restrict__ Yf, u16* __restrict__ Ysp, int l)
{
    const int bx = blockIdx.x;
    const int b = bx >> 2, cg = bx & 3;
    const int s = blockIdx.y;
    const float* X = Xb + (size_t)s * PLX + (size_t)b * NN * EMB;
    const int tid = threadIdx.x;
    const int cl = tid & 63, q = tid >> 6;
    const int c = cg * 64 + cl;

    float sum = 0.f, ss = 0.f;
    for (int n = q * 64; n < q * 64 + 64; ++n) {
        float x = X[(size_t)n * EMB + c];
        sum += x; ss += x * x;
    }
    __shared__ float Ssum[4][64], Sss[4][64], Sa[64], Sb2[64];
    Ssum[q][cl] = sum; Sss[q][cl] = ss;
    __syncthreads();
    if (q == 0) {
        float s4 = Ssum[0][cl] + Ssum[1][cl] + Ssum[2][cl] + Ssum[3][cl];
        float q4 = Sss[0][cl] + Sss[1][cl] + Sss[2][cl] + Sss[3][cl];
        float mean = s4 * (1.f / NN);
        float var  = q4 * (1.f / NN) - mean * mean;
        float inv  = rsqrtf(var + 1e-5f);
        float gv = gb[(size_t)(l * 2 + s) * EMB + c];
        float bv = bb[(size_t)(l * 2 + s) * EMB + c];
        float a = gv * inv;
        Sa[cl]  = a;
        Sb2[cl] = bv - mean * a;
    }
    __syncthreads();
    const float a = Sa[cl], b2 = Sb2[cl];
    u16* Yh = Ysp + (size_t)s * (2 * PLX) + (size_t)b * NN * EMB;
    u16* Yl = Yh + PLX;
    float* Yo = WF32 ? (Yf + (size_t)s * PLX + (size_t)b * NN * EMB) : nullptr;
    for (int n = q * 64; n < q * 64 + 64; ++n) {
        const size_t idx = (size_t)n * EMB + c;
        float y = X[idx] * a + b2;
        if constexpr (WF32) Yo[idx] = y;
        u16 hi, lo; split2(y, hi, lo);
        Yh[idx] = hi; Yl[idx] = lo;
    }
}

// ---------------------------------------------------------------------------
// Embedding -> split planes
// ---------------------------------------------------------------------------
__global__ __launch_bounds__(256)
void conv0_k(const float* __restrict__ rowe, const float* __restrict__ cole,
             u16* __restrict__ S0)
{
    const int side = blockIdx.y;
    const float* src = side ? cole : rowe;
    const size_t o = ((size_t)blockIdx.x * 256 + threadIdx.x) * 4;
    float4 v = *(const float4*)(src + o);
    u16 h0,l0,h1,l1,h2,l2,h3,l3;
    split2(v.x, h0, l0); split2(v.y, h1, l1);
    split2(v.z, h2, l2); split2(v.w, h3, l3);
    u16* Sh = S0 + (size_t)side * (2 * PLX);
    u16* Sl = Sh + PLX;
    ushort4 vh; vh.x=h0; vh.y=h1; vh.z=h2; vh.w=h3;
    ushort4 vl; vl.x=l0; vl.y=l1; vl.z=l2; vl.w=l3;
    *(ushort4*)(Sh + o) = vh;
    *(ushort4*)(Sl + o) = vl;
}

// ---------------------------------------------------------------------------
// Per-layer weight transpose + split.
// ---------------------------------------------------------------------------
__global__ __launch_bounds__(256)
void wconv_k(const float* __restrict__ Wq, const float* __restrict__ Ws,
             const float* __restrict__ Wa, const float* __restrict__ Wv,
             const float* __restrict__ Wc, const float* __restrict__ W1,
             const float* __restrict__ W2, u16* __restrict__ wt, int l)
{
    const int t = blockIdx.x;
    const int s = blockIdx.y;
    const float* src; int Kd, Nd, tr, tc; size_t dsto;
    if (t < 80) {
        int m = t >> 4, tt = t & 15; tr = tt >> 2; tc = tt & 3; Kd = 256; Nd = 256;
        const float* w0;
        switch (m) {
            case 0: w0 = Wq; dsto = OQ; break;
            case 1: w0 = Ws; dsto = OS; break;
            case 2: w0 = Wa; dsto = OA; break;
            case 3: w0 = Wv; dsto = OV; break;
            default: w0 = Wc; dsto = OC; break;
        }
        src = w0 + (size_t)(l * 2 + s) * 65536;
    } else if (t < 112) {
        int tt = t - 80; tr = tt >> 3; tc = tt & 7; Kd = 256; Nd = 512;
        src = W1 + (size_t)(l * 2 + s) * 131072; dsto = O1;
    } else {
        int tt = t - 112; tr = tt >> 2; tc = tt & 3; Kd = 512; Nd = 256;
        src = W2 + (size_t)(l * 2 + s) * 131072; dsto = O2;
    }
    const int k0 = tr * 64, n0 = tc * 64;
    __shared__ float T[64][65];
    const int tid = threadIdx.x;
    {
        const int j4 = tid & 15, i0 = tid >> 4;
        #pragma unroll
        for (int ii = 0; ii < 4; ++ii) {
            int i = ii * 16 + i0;
            float4 v = *(const float4*)(src + (size_t)(k0 + i) * Nd + n0 + j4 * 4);
            T[i][j4*4+0] = v.x; T[i][j4*4+1] = v.y;
            T[i][j4*4+2] = v.z; T[i][j4*4+3] = v.w;
        }
    }
    __syncthreads();
    u16* Whi = wt + (size_t)s * (2 * WSEG) + dsto;
    u16* Wlo = Whi + WSEG;
    {
        const int k4 = tid & 15, j0 = tid >> 4;
        #pragma unroll
        for (int jj = 0; jj < 4; ++jj) {
            int j = jj * 16 + j0;
            int n = n0 + j;
            u16 h[4], lo[4];
            #pragma unroll
            for (int r = 0; r < 4; ++r) split2(T[k4*4+r][j], h[r], lo[r]);
            ushort4 vh; vh.x=h[0]; vh.y=h[1]; vh.z=h[2]; vh.w=h[3];
            ushort4 vl; vl.x=lo[0]; vl.y=lo[1]; vl.z=lo[2]; vl.w=lo[3];
            *(ushort4*)(Whi + (size_t)n * Kd + k0 + k4 * 4) = vh;
            *(ushort4*)(Wlo + (size_t)n * Kd + k0 + k4 * 4) = vl;
        }
    }
}

// ---------------------------------------------------------------------------
// Workspace arena (128 MB, liveness-audited):
//  0-16 Sb0 | 16-32 Sb1 | 32-48 Qsp->o1sp | 48-64 Ksp->y1f->y2f
// 64-80 Vtsp->o1f | 80-84.5 wt | 96-112 AO -> 96-128 h planes
// ---------------------------------------------------------------------------
extern "C" void kernel_launch(void* const* d_in, const int* in_sizes, int n_in,
                              void* d_out, int out_size, void* d_ws, size_t ws_size,
                              hipStream_t stream)
{
    const float* row_emb = (const float*)d_in[0];
    const float* col_emb = (const float*)d_in[1];
    const float* cost    = (const float*)d_in[2];
    const float* Wq  = (const float*)d_in[3];
    const float* Ws  = (const float*)d_in[4];
    const float* Wa  = (const float*)d_in[5];
    const float* Wv  = (const float*)d_in[6];
    const float* Wc  = (const float*)d_in[7];
    const float* bc  = (const float*)d_in[8];
    const float* g1  = (const float*)d_in[9];
    const float* be1 = (const float*)d_in[10];
    const float* W1  = (const float*)d_in[11];
    const float* bf1 = (const float*)d_in[12];
    const float* W2  = (const float*)d_in[13];
    const float* bf2 = (const float*)d_in[14];
    const float* g2  = (const float*)d_in[15];
    const float* be2 = (const float*)d_in[16];

    char* W = (char*)d_ws;
    u16*   Sb[2]  = { (u16*)(W + 0 * MB), (u16*)(W + 16 * MB) };
    u16*   Qsp    = (u16*)(W + 32 * MB);
    u16*   Ksp    = (u16*)(W + 48 * MB);
    u16*   Vtsp   = (u16*)(W + 64 * MB);
    u16*   wt     = (u16*)(W + 80 * MB);
    u16*   AOsp   = (u16*)(W + 96 * MB);
    u16*   o1sp   = (u16*)(W + 32 * MB);     // alias Qsp (dead after attn)
    float* y1f    = (float*)(W + 48 * MB);   // alias Ksp (dead after attn)
    float* o1f    = (float*)(W + 64 * MB);   // alias Vtsp (dead after attn)
    u16*   hsp    = (u16*)(W + 96 * MB);     // alias AO (dead after Wc gemm)
    float* y2f    = (float*)(W + 48 * MB);   // alias y1 (dead after inorm1)

    conv0_k<<<dim3(2048, 2), 256, 0, stream>>>(row_emb, col_emb, Sb[0]);

    for (int l = 0; l < LL; ++l) {
        const int cur = l & 1;

        wconv_k<<<dim3(144, 2), 256, 0, stream>>>(Wq, Ws, Wa, Wv, Wc, W1, W2, wt, l);

        qkv_k<<<dim3(MTOT / 128, 6, 2), 256, 0, stream>>>(Sb[cur], wt, Qsp, Ksp, Vtsp);

        attn_k<<<dim3(8, BB, 2), 512, 0, stream>>>(Qsp, Ksp, Vtsp, cost, AOsp);

        // y1 = AO@Wc + bc + x(split)  -> y1f
        gemm3<2, 0, 1, 0><<<dim3(MTOT / 128, 2, 2), 256, 0, stream>>>(
            AOsp, PLX, 256, wt, OC, bc, 256, Sb[cur], nullptr, y1f, nullptr, 0, l);

        // o1 = inorm(y1) -> o1f (fp32) + o1sp (planes)
        inorm_k<1><<<dim3(BB * 4, 2), 256, 0, stream>>>(y1f, g1, be1, o1f, o1sp, l);

        // h = relu(o1@W1 + bf1) -> hsp planes
        gemm3<0, 1, 0, 1><<<dim3(MTOT / 128, 4, 2), 256, 0, stream>>>(
            o1sp, PLX, 256, wt, O1, bf1, 512, nullptr, nullptr, nullptr, hsp, PLH, l);

        // y2 = h@W2 + bf2 + o1 -> y2f
        gemm3<1, 0, 1, 0><<<dim3(MTOT / 128, 2, 2), 256, 0, stream>>>(
            hsp, PLH, 512, wt, O2, bf2, 256, nullptr, o1f, y2f, nullptr, 0, l);

        // out = inorm(y2) -> Sb[1-cur] planes (+ d_out fp32 on last layer)
        if (l == LL - 1)
            inorm_k<1><<<dim3(BB * 4, 2), 256, 0, stream>>>(y2f, g2, be2,
                (float*)d_out, Sb[1 - cur], l);
        else
            inorm_k<0><<<dim3(BB * 4, 2), 256, 0, stream>>>(y2f, g2, be2,
                nullptr, Sb[1 - cur], l);
    }
    (void)in_sizes; (void)n_in; (void)out_size; (void)ws_size;
}

// Round 9
// 1109.470 us; speedup vs baseline: 2.3813x; 1.0056x over previous
//
#include <hip/hip_runtime.h>
#include <cstddef>
#include <cstdint>

#define EMB 256
#define NN  256
#define BB  32
#define FFD 512
#define LL  5
#define MTOT (BB*NN)          // 8192 rows

typedef unsigned short u16;
typedef short bf16x8 __attribute__((ext_vector_type(8)));
typedef float f32x4  __attribute__((ext_vector_type(4)));

static const size_t MB = 1048576ull;
static const size_t PLX = 2097152;     // 8192x256 plane (elements)
static const size_t PLH = 4194304;     // 8192x512 plane
static const size_t FRAG = 4194304;    // 8 MB fragment buffer per side (u16)
static const size_t WSEG = 589824;
#define OQ 0
#define OS 65536
#define OA 131072
#define OV 196608
#define OC 262144
#define O1 327680
#define O2 458752

__device__ __forceinline__ u16 bf16_rne(float x) {
    unsigned u = __float_as_uint(x);
    unsigned r = u + 0x7FFF + ((u >> 16) & 1);
    return (u16)(r >> 16);
}
__device__ __forceinline__ float bf16_f(u16 h) {
    return __uint_as_float(((unsigned)h) << 16);
}
__device__ __forceinline__ void split2(float x, u16& hi, u16& lo) {
    hi = bf16_rne(x);
    lo = bf16_rne(x - bf16_f(hi));
}

__device__ __forceinline__ void gll16(const void* g, void* l) {
    __builtin_amdgcn_global_load_lds(
        (const __attribute__((address_space(1))) unsigned int*)g,
        (__attribute__((address_space(3))) unsigned int*)l,
        16, 0, 0);
}

// ---------------------------------------------------------------------------
// MFMA GEMM core, single-staging 3-term split (HW-verified round 8).
// ---------------------------------------------------------------------------
template<typename PF>
__device__ __forceinline__ void mfma_core3(f32x4 (&acc)[4][4], int nsp, int K,
                                           int m0, int n0,
                                           u16* AsH, u16* AsL,
                                           u16* BsH, u16* BsL, PF pf)
{
    const int tid  = threadIdx.x;
    const int lane = tid & 63;
    const int w    = tid >> 6;
    const int wr   = w >> 1, wc = w & 1;
    const int l15  = lane & 15, lg = lane >> 4;

    for (int p = 0; p < nsp; ++p) {
        const u16 *Ah, *Al, *Bh, *Bl;
        pf(p, Ah, Al, Bh, Bl);
        const int nkt = K >> 6;
        for (int kt = 0; kt < nkt; ++kt) {
            __syncthreads();
            #pragma unroll
            for (int c = 0; c < 4; ++c) {
                int slot = w * 256 + c * 64 + lane;
                int row  = slot >> 3;
                int cc   = slot & 7;
                int kc   = cc ^ (row & 7);
                const size_t ga = (size_t)(m0 + row) * K + (kt << 6) + kc * 8;
                const size_t gb = (size_t)(n0 + row) * K + (kt << 6) + kc * 8;
                const int lo = (w * 256 + c * 64) * 8;
                gll16(Ah + ga, AsH + lo);
                gll16(Al + ga, AsL + lo);
                gll16(Bh + gb, BsH + lo);
                gll16(Bl + gb, BsL + lo);
            }
            __syncthreads();
            #pragma unroll
            for (int ks = 0; ks < 2; ++ks) {
                bf16x8 ah[4], al[4], bh[4], bl[4];
                #pragma unroll
                for (int i = 0; i < 4; ++i) {
                    int arow = wr * 64 + i * 16 + l15;
                    int aoff = ((arow << 3) + ((ks * 4 + lg) ^ (arow & 7))) * 8;
                    ah[i] = *(const bf16x8*)(AsH + aoff);
                    al[i] = *(const bf16x8*)(AsL + aoff);
                    int brow = wc * 64 + i * 16 + l15;
                    int boff = ((brow << 3) + ((ks * 4 + lg) ^ (brow & 7))) * 8;
                    bh[i] = *(const bf16x8*)(BsH + boff);
                    bl[i] = *(const bf16x8*)(BsL + boff);
                }
                #pragma unroll
                for (int mi = 0; mi < 4; ++mi)
                    #pragma unroll
                    for (int ni = 0; ni < 4; ++ni) {
                        acc[mi][ni] = __builtin_amdgcn_mfma_f32_16x16x32_bf16(
                            ah[mi], bh[ni], acc[mi][ni], 0, 0, 0);
                        acc[mi][ni] = __builtin_amdgcn_mfma_f32_16x16x32_bf16(
                            al[mi], bh[ni], acc[mi][ni], 0, 0, 0);
                        acc[mi][ni] = __builtin_amdgcn_mfma_f32_16x16x32_bf16(
                            ah[mi], bl[ni], acc[mi][ni], 0, 0, 0);
                    }
            }
        }
    }
}

// ---------------------------------------------------------------------------
// Fused QKV -> fragment-packed outputs for attention:
//  Qf[b][T(16)][h][p][half][l15]x8   (512 u16 per (b,T,h))
//  Kf[b][g(8)][h][t][lane(64)]x8     (1024 u16 per (b,g,h); lane=(p*2+half)*16+lk)
//  Vf[b][g(8)][h][p][lane(64)]x8     (1024 u16 per (b,g,h); lane=lg*16+l15)
// j-permutation baked in: lk = ((jj>>3)<<2)|(jj&3), t=(jj>>2)&1.
// ---------------------------------------------------------------------------
__global__ __launch_bounds__(256)
void qkv_k(const u16* __restrict__ Ssp, const u16* __restrict__ wt,
           u16* __restrict__ Qf, u16* __restrict__ Kf, u16* __restrict__ Vf)
{
    const int s   = blockIdx.z;
    const int seg = blockIdx.y >> 1;
    const int n0  = (blockIdx.y & 1) * 128;
    const int m0  = blockIdx.x * 128;

    const u16* Xsh = Ssp + (size_t)s * (2 * PLX);
    const u16* Xsl = Xsh + PLX;
    const u16* Xoh = Ssp + (size_t)(1 - s) * (2 * PLX);
    const u16* Xol = Xoh + PLX;
    const u16* Wh  = wt + (size_t)s * (2 * WSEG);
    const u16* Wl  = Wh + WSEG;
    const int  nsp = (seg == 1) ? 2 : 1;

    __shared__ u16 AsH[8192], AsL[8192], BsH[8192], BsL[8192];

    f32x4 acc[4][4];
    #pragma unroll
    for (int i = 0; i < 4; ++i)
        #pragma unroll
        for (int j = 0; j < 4; ++j) acc[i][j] = (f32x4){0.f, 0.f, 0.f, 0.f};

    auto pf = [&](int p, const u16*& Ah, const u16*& Al,
                  const u16*& Bh, const u16*& Bl) {
        if (seg == 0)      { Ah = Xsh; Al = Xsl; Bh = Wh + OQ; Bl = Wl + OQ; }
        else if (seg == 2) { Ah = Xoh; Al = Xol; Bh = Wh + OV; Bl = Wl + OV; }
        else if (p == 0)   { Ah = Xsh; Al = Xsl; Bh = Wh + OS; Bl = Wl + OS; }
        else               { Ah = Xoh; Al = Xol; Bh = Wh + OA; Bl = Wl + OA; }
    };
    mfma_core3(acc, nsp, 256, m0, n0, AsH, AsL, BsH, BsL, pf);

    const int lane = threadIdx.x & 63, w = threadIdx.x >> 6;
    const int wr = w >> 1, wc = w & 1, l15 = lane & 15, lg = lane >> 4;

    u16* Of = ((seg == 0) ? Qf : (seg == 1) ? Kf : Vf) + (size_t)s * FRAG;

    #pragma unroll
    for (int mi = 0; mi < 4; ++mi)
        #pragma unroll
        for (int ni = 0; ni < 4; ++ni) {
            const int col = n0 + wc * 64 + ni * 16 + l15;
            #pragma unroll
            for (int r = 0; r < 4; ++r) {
                const int row = m0 + wr * 64 + mi * 16 + lg * 4 + r;
                u16 hi, lo; split2(acc[mi][ni][r], hi, lo);
                const int bloc = row >> 8;
                const int h = col >> 4;
                if (seg == 0) {
                    const int T = (row >> 4) & 15, rq = row & 15;
                    const int half = (col >> 3) & 1, e = col & 7;
                    const size_t base = (((size_t)bloc * 16 + T) * 16 + h) * 512
                                      + half * 128 + rq * 8 + e;
                    Of[base] = hi;
                    Of[base + 256] = lo;
                } else if (seg == 1) {
                    const int g = (row >> 5) & 7, jj = row & 31;
                    const int t = (jj >> 2) & 1;
                    const int lk = ((jj >> 3) << 2) | (jj & 3);
                    const int half = (col >> 3) & 1, e = col & 7;
                    const size_t base = (((size_t)bloc * 8 + g) * 16 + h) * 1024
                                      + t * 512 + half * 128 + lk * 8 + e;
                    Of[base] = hi;
                    Of[base + 256] = lo;
                } else {
                    const int g = (row >> 5) & 7, jj = row & 31;
                    const int lgv = jj >> 3, e = jj & 7;
                    const int lv = col & 15;
                    const size_t base = (((size_t)bloc * 8 + g) * 16 + h) * 1024
                                      + (lgv * 16 + lv) * 8 + e;
                    Of[base] = hi;
                    Of[base + 512] = lo;
                }
            }
        }
}

// ---------------------------------------------------------------------------
// Generic single-staging 3-term GEMM with epilogue.
// ---------------------------------------------------------------------------
template<int RESID, int RELU, int OUTF32, int OUTBF16>
__global__ __launch_bounds__(256)
void gemm3(const u16* __restrict__ Asp, size_t AMK, int K,
           const u16* __restrict__ wt, int boff,
           const float* __restrict__ bias, int Nd,
           const u16* __restrict__ Rsp, const float* __restrict__ Rf,
           float* __restrict__ Of, u16* __restrict__ Ob, size_t OMN, int l)
{
    const int s  = blockIdx.z;
    const int n0 = blockIdx.y * 128;
    const int m0 = blockIdx.x * 128;

    const u16* Ah0 = Asp + (size_t)s * (2 * AMK);
    const u16* Al0 = Ah0 + AMK;
    const u16* Bh0 = wt + (size_t)s * (2 * WSEG) + boff;
    const u16* Bl0 = Bh0 + WSEG;

    __shared__ u16 AsH[8192], AsL[8192], BsH[8192], BsL[8192];

    f32x4 acc[4][4];
    #pragma unroll
    for (int i = 0; i < 4; ++i)
        #pragma unroll
        for (int j = 0; j < 4; ++j) acc[i][j] = (f32x4){0.f, 0.f, 0.f, 0.f};

    auto pf = [&](int p, const u16*& Ah, const u16*& Al,
                  const u16*& Bh, const u16*& Bl) {
        Ah = Ah0; Al = Al0; Bh = Bh0; Bl = Bl0;
    };
    mfma_core3(acc, 1, K, m0, n0, AsH, AsL, BsH, BsL, pf);

    const float* bs = bias + (size_t)(l * 2 + s) * Nd;
    const int lane = threadIdx.x & 63, w = threadIdx.x >> 6;
    const int wr = w >> 1, wc = w & 1, l15 = lane & 15, lg = lane >> 4;

    #pragma unroll
    for (int mi = 0; mi < 4; ++mi)
        #pragma unroll
        for (int ni = 0; ni < 4; ++ni) {
            const int col = n0 + wc * 64 + ni * 16 + l15;
            const float bv = bs[col];
            #pragma unroll
            for (int r = 0; r < 4; ++r) {
                const int row = m0 + wr * 64 + mi * 16 + lg * 4 + r;
                const size_t idx = (size_t)row * Nd + col;
                float v = acc[mi][ni][r] + bv;
                if constexpr (RESID == 1) {
                    v += Rf[(size_t)s * PLX + idx];
                } else if constexpr (RESID == 2) {
                    const u16* Rh = Rsp + (size_t)s * (2 * PLX);
                    v += bf16_f(Rh[idx]) + bf16_f(Rh[PLX + idx]);
                }
                if constexpr (RELU) v = fmaxf(v, 0.f);
                if constexpr (OUTF32) Of[(size_t)s * PLX + idx] = v;
                if constexpr (OUTBF16) {
                    u16 hi, lo; split2(v, hi, lo);
                    u16* Oh = Ob + (size_t)s * (2 * OMN);
                    Oh[idx] = hi;
                    Oh[OMN + idx] = lo;
                }
            }
        }
}

// ---------------------------------------------------------------------------
// MFMA flash attention v4. 1-D grid: id = ib*64 + (b*2+s); 64 % 8 == 0 so
// all 8 i-blocks of one (b,s) share id%8 -> same XCD -> K/V/cost L2 reuse.
// All global loads are fragment-packed, fully coalesced (1KB/wave).
// ---------------------------------------------------------------------------
__global__ __launch_bounds__(512)
void attn_k(const u16* __restrict__ Qf, const u16* __restrict__ Kf,
            const u16* __restrict__ Vf, const float* __restrict__ cost,
            u16* __restrict__ AOs)
{
    const int id = blockIdx.x;
    const int bs = id & 63;
    const int ib = id >> 6;
    const int b = bs >> 1, s = bs & 1;
    const int i0 = ib * 32;

    const int tid = threadIdx.x;
    const int lane = tid & 63;
    const int wv = tid >> 6;
    const int l15 = lane & 15, lg = lane >> 4;
    const int h0 = wv * 2;

    const u16* Qfs = Qf + (size_t)s * FRAG;
    const u16* Kfs = Kf + (size_t)s * FRAG;
    const u16* Vfs = Vf + (size_t)s * FRAG;
    const float* cb = cost + (size_t)b * NN * NN;

    __shared__ float Cs[2][32][36];

    // hoisted Q fragments (coalesced packed loads)
    bf16x8 qb1[2][2], qb2[2][2];
    #pragma unroll
    for (int hh = 0; hh < 2; ++hh)
        #pragma unroll
        for (int it = 0; it < 2; ++it) {
            const int T = (i0 >> 4) + it;
            const size_t base = (((size_t)b * 16 + T) * 16 + (h0 + hh)) * 512
                              + (lg & 1) * 128 + l15 * 8;
            qb1[hh][it] = *(const bf16x8*)(Qfs + base);
            bf16x8 t = *(const bf16x8*)(Qfs + base + 256);
            if (lg >= 2) {
                #pragma unroll
                for (int e = 0; e < 8; ++e) t[e] = 0;
            }
            qb2[hh][it] = t;
        }

    float m_s[2][2], l_s[2][2];
    f32x4 occ[2][2];
    #pragma unroll
    for (int hh = 0; hh < 2; ++hh)
        #pragma unroll
        for (int it = 0; it < 2; ++it) {
            m_s[hh][it] = -1e30f;
            l_s[hh][it] = 0.f;
            occ[hh][it] = (f32x4){0.f, 0.f, 0.f, 0.f};
        }

    auto stageCost = [&](int g, int buf) {
        if (tid < 256) {
            if (s == 0) {
                const int i = tid >> 3, j4 = (tid & 7) * 4;
                float4 cv = *(const float4*)(cb + (size_t)(i0 + i) * NN + g * 32 + j4);
                Cs[buf][i][j4+0] = cv.x; Cs[buf][i][j4+1] = cv.y;
                Cs[buf][i][j4+2] = cv.z; Cs[buf][i][j4+3] = cv.w;
            } else {
                const int j = tid >> 3, i4 = (tid & 7) * 4;
                float4 cv = *(const float4*)(cb + (size_t)(g * 32 + j) * NN + i0 + i4);
                Cs[buf][i4+0][j] = cv.x; Cs[buf][i4+1][j] = cv.y;
                Cs[buf][i4+2][j] = cv.z; Cs[buf][i4+3][j] = cv.w;
            }
        }
    };

    auto loadKV = [&](int g, bf16x8 (&kA)[2][2], bf16x8 (&vv)[2][2]) {
        #pragma unroll
        for (int hh = 0; hh < 2; ++hh) {
            const size_t kb = (((size_t)b * 8 + g) * 16 + (h0 + hh)) * 1024;
            kA[hh][0] = *(const bf16x8*)(Kfs + kb + lane * 8);
            kA[hh][1] = *(const bf16x8*)(Kfs + kb + 512 + lane * 8);
            const size_t vb = (((size_t)b * 8 + g) * 16 + (h0 + hh)) * 1024;
            vv[hh][0] = *(const bf16x8*)(Vfs + vb + lane * 8);
            vv[hh][1] = *(const bf16x8*)(Vfs + vb + 512 + lane * 8);
        }
    };

    bf16x8 kA0[2][2], vv0[2][2], kA1[2][2], vv1[2][2];
    stageCost(0, 0);
    loadKV(0, kA0, vv0);
    __syncthreads();

    auto iter = [&](int g, int cur,
                    bf16x8 (&kAc)[2][2], bf16x8 (&vvc)[2][2],
                    bf16x8 (&kAn)[2][2], bf16x8 (&vvn)[2][2]) {
        if (g < 7) {
            stageCost(g + 1, cur ^ 1);
            loadKV(g + 1, kAn, vvn);
        }
        float cst[2][8];
        #pragma unroll
        for (int it = 0; it < 2; ++it)
            #pragma unroll
            for (int t = 0; t < 2; ++t) {
                float4 cv = *(const float4*)&Cs[cur][it * 16 + l15][8 * lg + 4 * t];
                cst[it][t*4+0] = cv.x; cst[it][t*4+1] = cv.y;
                cst[it][t*4+2] = cv.z; cst[it][t*4+3] = cv.w;
            }
        #pragma unroll
        for (int hh = 0; hh < 2; ++hh) {
            #pragma unroll
            for (int it = 0; it < 2; ++it) {
                f32x4 st0 = (f32x4){0.f,0.f,0.f,0.f};
                f32x4 st1 = (f32x4){0.f,0.f,0.f,0.f};
                st0 = __builtin_amdgcn_mfma_f32_16x16x32_bf16(kAc[hh][0], qb1[hh][it], st0, 0,0,0);
                st0 = __builtin_amdgcn_mfma_f32_16x16x32_bf16(kAc[hh][0], qb2[hh][it], st0, 0,0,0);
                st1 = __builtin_amdgcn_mfma_f32_16x16x32_bf16(kAc[hh][1], qb1[hh][it], st1, 0,0,0);
                st1 = __builtin_amdgcn_mfma_f32_16x16x32_bf16(kAc[hh][1], qb2[hh][it], st1, 0,0,0);

                float sv[8];
                #pragma unroll
                for (int r = 0; r < 4; ++r) {
                    sv[r]     = st0[r] * 0.25f + cst[it][r];
                    sv[4 + r] = st1[r] * 0.25f + cst[it][4 + r];
                }
                float tm = sv[0];
                #pragma unroll
                for (int e = 1; e < 8; ++e) tm = fmaxf(tm, sv[e]);
                tm = fmaxf(tm, __shfl_xor(tm, 16));
                tm = fmaxf(tm, __shfl_xor(tm, 32));

                const float mo = m_s[hh][it];
                const float mn = fmaxf(mo, tm);
                const float sc = __expf(mo - mn);
                float p[8], ts = 0.f;
                #pragma unroll
                for (int e = 0; e < 8; ++e) { p[e] = __expf(sv[e] - mn); ts += p[e]; }
                ts += __shfl_xor(ts, 16);
                ts += __shfl_xor(ts, 32);
                l_s[hh][it] = l_s[hh][it] * sc + ts;
                m_s[hh][it] = mn;

                f32x4 o = occ[hh][it];
                o[0] *= sc; o[1] *= sc; o[2] *= sc; o[3] *= sc;
                bf16x8 pb;
                #pragma unroll
                for (int e = 0; e < 8; ++e) pb[e] = (short)bf16_rne(p[e]);
                o = __builtin_amdgcn_mfma_f32_16x16x32_bf16(vvc[hh][0], pb, o, 0,0,0);
                o = __builtin_amdgcn_mfma_f32_16x16x32_bf16(vvc[hh][1], pb, o, 0,0,0);
                occ[hh][it] = o;
            }
        }
        __syncthreads();
    };

    for (int gp = 0; gp < 8; gp += 2) {
        iter(gp,     0, kA0, vv0, kA1, vv1);
        iter(gp + 1, 1, kA1, vv1, kA0, vv0);
    }

    u16* AOh = AOs + (size_t)s * (2 * PLX);
    u16* AOl = AOh + PLX;
    #pragma unroll
    for (int hh = 0; hh < 2; ++hh)
        #pragma unroll
        for (int it = 0; it < 2; ++it) {
            const float inv = 1.f / l_s[hh][it];
            const size_t base = (size_t)(b * NN + i0 + it * 16 + l15) * EMB
                              + (h0 + hh) * 16 + lg * 4;
            ushort4 vh4, vl4;
            u16 h_, l_;
            split2(occ[hh][it][0] * inv, h_, l_); vh4.x = h_; vl4.x = l_;
            split2(occ[hh][it][1] * inv, h_, l_); vh4.y = h_; vl4.y = l_;
            split2(occ[hh][it][2] * inv, h_, l_); vh4.z = h_; vl4.z = l_;
            split2(occ[hh][it][3] * inv, h_, l_); vh4.w = h_; vl4.w = l_;
            *(ushort4*)(AOh + base) = vh4;
            *(ushort4*)(AOl + base) = vl4;
        }
}

// ---------------------------------------------------------------------------
// InstanceNorm over node axis; writes split planes (+ optional fp32).
// ---------------------------------------------------------------------------
template<int WF32>
__global__ __launch_bounds__(256)
void inorm_k(const float* __restrict__ Xb,
             const float* __restrict__ gb, const float* __restrict__ bb,
             float* __restrict__ Yf, u16* __restrict__ Ysp, int l)
{
    const int bx = blockIdx.x;
    const int b = bx >> 2, cg = bx & 3;
    const int s = blockIdx.y;
    const float* X = Xb + (size_t)s * PLX + (size_t)b * NN * EMB;
    const int tid = threadIdx.x;
    const int cl = tid & 63, q = tid >> 6;
    const int c = cg * 64 + cl;

    float sum = 0.f, ss = 0.f;
    for (int n = q * 64; n < q * 64 + 64; ++n) {
        float x = X[(size_t)n * EMB + c];
        sum += x; ss += x * x;
    }
    __shared__ float Ssum[4][64], Sss[4][64], Sa[64], Sb2[64];
    Ssum[q][cl] = sum; Sss[q][cl] = ss;
    __syncthreads();
    if (q == 0) {
        float s4 = Ssum[0][cl] + Ssum[1][cl] + Ssum[2][cl] + Ssum[3][cl];
        float q4 = Sss[0][cl] + Sss[1][cl] + Sss[2][cl] + Sss[3][cl];
        float mean = s4 * (1.f / NN);
        float var  = q4 * (1.f / NN) - mean * mean;
        float inv  = rsqrtf(var + 1e-5f);
        float gv = gb[(size_t)(l * 2 + s) * EMB + c];
        float bv = bb[(size_t)(l * 2 + s) * EMB + c];
        float a = gv * inv;
        Sa[cl]  = a;
        Sb2[cl] = bv - mean * a;
    }
    __syncthreads();
    const float a = Sa[cl], b2 = Sb2[cl];
    u16* Yh = Ysp + (size_t)s * (2 * PLX) + (size_t)b * NN * EMB;
    u16* Yl = Yh + PLX;
    float* Yo = WF32 ? (Yf + (size_t)s * PLX + (size_t)b * NN * EMB) : nullptr;
    for (int n = q * 64; n < q * 64 + 64; ++n) {
        const size_t idx = (size_t)n * EMB + c;
        float y = X[idx] * a + b2;
        if constexpr (WF32) Yo[idx] = y;
        u16 hi, lo; split2(y, hi, lo);
        Yh[idx] = hi; Yl[idx] = lo;
    }
}

// ---------------------------------------------------------------------------
// Embedding -> split planes
// ---------------------------------------------------------------------------
__global__ __launch_bounds__(256)
void conv0_k(const float* __restrict__ rowe, const float* __restrict__ cole,
             u16* __restrict__ S0)
{
    const int side = blockIdx.y;
    const float* src = side ? cole : rowe;
    const size_t o = ((size_t)blockIdx.x * 256 + threadIdx.x) * 4;
    float4 v = *(const float4*)(src + o);
    u16 h0,l0,h1,l1,h2,l2,h3,l3;
    split2(v.x, h0, l0); split2(v.y, h1, l1);
    split2(v.z, h2, l2); split2(v.w, h3, l3);
    u16* Sh = S0 + (size_t)side * (2 * PLX);
    u16* Sl = Sh + PLX;
    ushort4 vh; vh.x=h0; vh.y=h1; vh.z=h2; vh.w=h3;
    ushort4 vl; vl.x=l0; vl.y=l1; vl.z=l2; vl.w=l3;
    *(ushort4*)(Sh + o) = vh;
    *(ushort4*)(Sl + o) = vl;
}

// ---------------------------------------------------------------------------
// Per-layer weight transpose + split.
// ---------------------------------------------------------------------------
__global__ __launch_bounds__(256)
void wconv_k(const float* __restrict__ Wq, const float* __restrict__ Ws,
             const float* __restrict__ Wa, const float* __restrict__ Wv,
             const float* __restrict__ Wc, const float* __restrict__ W1,
             const float* __restrict__ W2, u16* __restrict__ wt, int l)
{
    const int t = blockIdx.x;
    const int s = blockIdx.y;
    const float* src; int Kd, Nd, tr, tc; size_t dsto;
    if (t < 80) {
        int m = t >> 4, tt = t & 15; tr = tt >> 2; tc = tt & 3; Kd = 256; Nd = 256;
        const float* w0;
        switch (m) {
            case 0: w0 = Wq; dsto = OQ; break;
            case 1: w0 = Ws; dsto = OS; break;
            case 2: w0 = Wa; dsto = OA; break;
            case 3: w0 = Wv; dsto = OV; break;
            default: w0 = Wc; dsto = OC; break;
        }
        src = w0 + (size_t)(l * 2 + s) * 65536;
    } else if (t < 112) {
        int tt = t - 80; tr = tt >> 3; tc = tt & 7; Kd = 256; Nd = 512;
        src = W1 + (size_t)(l * 2 + s) * 131072; dsto = O1;
    } else {
        int tt = t - 112; tr = tt >> 2; tc = tt & 3; Kd = 512; Nd = 256;
        src = W2 + (size_t)(l * 2 + s) * 131072; dsto = O2;
    }
    const int k0 = tr * 64, n0 = tc * 64;
    __shared__ float T[64][65];
    const int tid = threadIdx.x;
    {
        const int j4 = tid & 15, i0 = tid >> 4;
        #pragma unroll
        for (int ii = 0; ii < 4; ++ii) {
            int i = ii * 16 + i0;
            float4 v = *(const float4*)(src + (size_t)(k0 + i) * Nd + n0 + j4 * 4);
            T[i][j4*4+0] = v.x; T[i][j4*4+1] = v.y;
            T[i][j4*4+2] = v.z; T[i][j4*4+3] = v.w;
        }
    }
    __syncthreads();
    u16* Whi = wt + (size_t)s * (2 * WSEG) + dsto;
    u16* Wlo = Whi + WSEG;
    {
        const int k4 = tid & 15, j0 = tid >> 4;
        #pragma unroll
        for (int jj = 0; jj < 4; ++jj) {
            int j = jj * 16 + j0;
            int n = n0 + j;
            u16 h[4], lo[4];
            #pragma unroll
            for (int r = 0; r < 4; ++r) split2(T[k4*4+r][j], h[r], lo[r]);
            ushort4 vh; vh.x=h[0]; vh.y=h[1]; vh.z=h[2]; vh.w=h[3];
            ushort4 vl; vl.x=lo[0]; vl.y=lo[1]; vl.z=lo[2]; vl.w=lo[3];
            *(ushort4*)(Whi + (size_t)n * Kd + k0 + k4 * 4) = vh;
            *(ushort4*)(Wlo + (size_t)n * Kd + k0 + k4 * 4) = vl;
        }
    }
}

// ---------------------------------------------------------------------------
// Workspace arena (128 MB, liveness-audited):
//  0-16 Sb0 | 16-32 Sb1 | 32-48 Qf->o1sp | 48-64 Kf->y1f->y2f
// 64-80 Vf->o1f | 80-84.5 wt | 96-112 AO -> 96-128 h planes
// ---------------------------------------------------------------------------
extern "C" void kernel_launch(void* const* d_in, const int* in_sizes, int n_in,
                              void* d_out, int out_size, void* d_ws, size_t ws_size,
                              hipStream_t stream)
{
    const float* row_emb = (const float*)d_in[0];
    const float* col_emb = (const float*)d_in[1];
    const float* cost    = (const float*)d_in[2];
    const float* Wq  = (const float*)d_in[3];
    const float* Ws  = (const float*)d_in[4];
    const float* Wa  = (const float*)d_in[5];
    const float* Wv  = (const float*)d_in[6];
    const float* Wc  = (const float*)d_in[7];
    const float* bc  = (const float*)d_in[8];
    const float* g1  = (const float*)d_in[9];
    const float* be1 = (const float*)d_in[10];
    const float* W1  = (const float*)d_in[11];
    const float* bf1 = (const float*)d_in[12];
    const float* W2  = (const float*)d_in[13];
    const float* bf2 = (const float*)d_in[14];
    const float* g2  = (const float*)d_in[15];
    const float* be2 = (const float*)d_in[16];

    char* W = (char*)d_ws;
    u16*   Sb[2]  = { (u16*)(W + 0 * MB), (u16*)(W + 16 * MB) };
    u16*   Qf     = (u16*)(W + 32 * MB);
    u16*   Kf     = (u16*)(W + 48 * MB);
    u16*   Vf     = (u16*)(W + 64 * MB);
    u16*   wt     = (u16*)(W + 80 * MB);
    u16*   AOsp   = (u16*)(W + 96 * MB);
    u16*   o1sp   = (u16*)(W + 32 * MB);     // alias Qf (dead after attn)
    float* y1f    = (float*)(W + 48 * MB);   // alias Kf (dead after attn)
    float* o1f    = (float*)(W + 64 * MB);   // alias Vf (dead after attn)
    u16*   hsp    = (u16*)(W + 96 * MB);     // alias AO (dead after Wc gemm)
    float* y2f    = (float*)(W + 48 * MB);   // alias y1 (dead after inorm1)

    conv0_k<<<dim3(2048, 2), 256, 0, stream>>>(row_emb, col_emb, Sb[0]);

    for (int l = 0; l < LL; ++l) {
        const int cur = l & 1;

        wconv_k<<<dim3(144, 2), 256, 0, stream>>>(Wq, Ws, Wa, Wv, Wc, W1, W2, wt, l);

        qkv_k<<<dim3(MTOT / 128, 6, 2), 256, 0, stream>>>(Sb[cur], wt, Qf, Kf, Vf);

        attn_k<<<dim3(512), 512, 0, stream>>>(Qf, Kf, Vf, cost, AOsp);

        // y1 = AO@Wc + bc + x(split)  -> y1f
        gemm3<2, 0, 1, 0><<<dim3(MTOT / 128, 2, 2), 256, 0, stream>>>(
            AOsp, PLX, 256, wt, OC, bc, 256, Sb[cur], nullptr, y1f, nullptr, 0, l);

        // o1 = inorm(y1) -> o1f (fp32) + o1sp (planes)
        inorm_k<1><<<dim3(BB * 4, 2), 256, 0, stream>>>(y1f, g1, be1, o1f, o1sp, l);

        // h = relu(o1@W1 + bf1) -> hsp planes
        gemm3<0, 1, 0, 1><<<dim3(MTOT / 128, 4, 2), 256, 0, stream>>>(
            o1sp, PLX, 256, wt, O1, bf1, 512, nullptr, nullptr, nullptr, hsp, PLH, l);

        // y2 = h@W2 + bf2 + o1 -> y2f
        gemm3<1, 0, 1, 0><<<dim3(MTOT / 128, 2, 2), 256, 0, stream>>>(
            hsp, PLH, 512, wt, O2, bf2, 256, nullptr, o1f, y2f, nullptr, 0, l);

        // out = inorm(y2) -> Sb[1-cur] planes (+ d_out fp32 on last layer)
        if (l == LL - 1)
            inorm_k<1><<<dim3(BB * 4, 2), 256, 0, stream>>>(y2f, g2, be2,
                (float*)d_out, Sb[1 - cur], l);
        else
            inorm_k<0><<<dim3(BB * 4, 2), 256, 0, stream>>>(y2f, g2, be2,
                nullptr, Sb[1 - cur], l);
    }
    (void)in_sizes; (void)n_in; (void)out_size; (void)ws_size;
}

// Round 10
// 897.796 us; speedup vs baseline: 2.9427x; 1.2358x over previous
//
#include <hip/hip_runtime.h>
#include <cstddef>
#include <cstdint>

#define EMB 256
#define NN  256
#define BB  32
#define FFD 512
#define LL  5
#define MTOT (BB*NN)          // 8192 rows

typedef unsigned short u16;
typedef _Float16 f16;
typedef f16   f16x8 __attribute__((ext_vector_type(8)));
typedef float f32x4 __attribute__((ext_vector_type(4)));

static const size_t MB = 1048576ull;
static const size_t PLX = 2097152;     // 8192x256 plane (elements)
static const size_t PLH = 4194304;     // 8192x512 plane
static const size_t FRAG = 4194304;    // 8 MB fragment buffer per side (u16)
static const size_t WSEG = 589824;
#define OQ 0
#define OS 65536
#define OA 131072
#define OV 196608
#define OC 262144
#define O1 327680
#define O2 458752

__device__ __forceinline__ float f16_f(u16 u) {
    union { u16 u; f16 f; } c; c.u = u;
    return (float)c.f;
}
__device__ __forceinline__ u16 f16_u(f16 h) {
    union { f16 f; u16 u; } c; c.f = h;
    return c.u;
}
// fp16 hi/lo split: hi = RNE(x), lo = RNE(x - hi). |err| ~ 2^-22 of x.
__device__ __forceinline__ void split2h(float x, u16& hi, u16& lo) {
    f16 h = (f16)x;
    f16 l = (f16)(x - (float)h);
    hi = f16_u(h); lo = f16_u(l);
}

__device__ __forceinline__ void gll16(const void* g, void* l) {
    __builtin_amdgcn_global_load_lds(
        (const __attribute__((address_space(1))) unsigned int*)g,
        (__attribute__((address_space(3))) unsigned int*)l,
        16, 0, 0);
}

// ---------------------------------------------------------------------------
// MFMA GEMM core, fp16 2-term split: per K-tile stage {Ah, Al, Bh} (48 KB),
// acc += Ah*Bh + Al*Bh (= A*Bh, err ~2^-12). Swizzle identical to the
// HW-verified bf16 core (source-side XOR chunk swizzle + same XOR on read).
// ---------------------------------------------------------------------------
template<typename PF>
__device__ __forceinline__ void mfma_core2(f32x4 (&acc)[4][4], int nsp, int K,
                                           int m0, int n0,
                                           u16* AsH, u16* AsL, u16* BsH, PF pf)
{
    const int tid  = threadIdx.x;
    const int lane = tid & 63;
    const int w    = tid >> 6;
    const int wr   = w >> 1, wc = w & 1;
    const int l15  = lane & 15, lg = lane >> 4;

    for (int p = 0; p < nsp; ++p) {
        const u16 *Ah, *Al, *Bh;
        pf(p, Ah, Al, Bh);
        const int nkt = K >> 6;
        for (int kt = 0; kt < nkt; ++kt) {
            __syncthreads();
            #pragma unroll
            for (int c = 0; c < 4; ++c) {
                int slot = w * 256 + c * 64 + lane;
                int row  = slot >> 3;
                int cc   = slot & 7;
                int kc   = cc ^ (row & 7);
                const size_t ga = (size_t)(m0 + row) * K + (kt << 6) + kc * 8;
                const size_t gb = (size_t)(n0 + row) * K + (kt << 6) + kc * 8;
                const int lo = (w * 256 + c * 64) * 8;
                gll16(Ah + ga, AsH + lo);
                gll16(Al + ga, AsL + lo);
                gll16(Bh + gb, BsH + lo);
            }
            __syncthreads();
            #pragma unroll
            for (int ks = 0; ks < 2; ++ks) {
                f16x8 ah[4], al[4], bh[4];
                #pragma unroll
                for (int i = 0; i < 4; ++i) {
                    int arow = wr * 64 + i * 16 + l15;
                    int aoff = ((arow << 3) + ((ks * 4 + lg) ^ (arow & 7))) * 8;
                    ah[i] = *(const f16x8*)(AsH + aoff);
                    al[i] = *(const f16x8*)(AsL + aoff);
                    int brow = wc * 64 + i * 16 + l15;
                    int boff = ((brow << 3) + ((ks * 4 + lg) ^ (brow & 7))) * 8;
                    bh[i] = *(const f16x8*)(BsH + boff);
                }
                #pragma unroll
                for (int mi = 0; mi < 4; ++mi)
                    #pragma unroll
                    for (int ni = 0; ni < 4; ++ni) {
                        acc[mi][ni] = __builtin_amdgcn_mfma_f32_16x16x32_f16(
                            ah[mi], bh[ni], acc[mi][ni], 0, 0, 0);
                        acc[mi][ni] = __builtin_amdgcn_mfma_f32_16x16x32_f16(
                            al[mi], bh[ni], acc[mi][ni], 0, 0, 0);
                    }
            }
        }
    }
}

// ---------------------------------------------------------------------------
// Fused QKV -> fragment-packed outputs (layout as round 9, fp16):
//  Qf[b][T][h]: 512-stride, hi only (256 u16 used)
//  Kf[b][g][h]: 1024 u16 = [t][plane(hi/lo)][half][lk]x8  (both planes)
//  Vf[b][g][h]: 1024-stride, hi only (512 u16 used)
// ---------------------------------------------------------------------------
__global__ __launch_bounds__(256)
void qkv_k(const u16* __restrict__ Ssp, const u16* __restrict__ wt,
           u16* __restrict__ Qf, u16* __restrict__ Kf, u16* __restrict__ Vf)
{
    const int s   = blockIdx.z;
    const int seg = blockIdx.y >> 1;
    const int n0  = (blockIdx.y & 1) * 128;
    const int m0  = blockIdx.x * 128;

    const u16* Xsh = Ssp + (size_t)s * (2 * PLX);
    const u16* Xsl = Xsh + PLX;
    const u16* Xoh = Ssp + (size_t)(1 - s) * (2 * PLX);
    const u16* Xol = Xoh + PLX;
    const u16* Wh  = wt + (size_t)s * (2 * WSEG);
    const int  nsp = (seg == 1) ? 2 : 1;

    __shared__ u16 AsH[8192], AsL[8192], BsH[8192];

    f32x4 acc[4][4];
    #pragma unroll
    for (int i = 0; i < 4; ++i)
        #pragma unroll
        for (int j = 0; j < 4; ++j) acc[i][j] = (f32x4){0.f, 0.f, 0.f, 0.f};

    auto pf = [&](int p, const u16*& Ah, const u16*& Al, const u16*& Bh) {
        if (seg == 0)      { Ah = Xsh; Al = Xsl; Bh = Wh + OQ; }
        else if (seg == 2) { Ah = Xoh; Al = Xol; Bh = Wh + OV; }
        else if (p == 0)   { Ah = Xsh; Al = Xsl; Bh = Wh + OS; }
        else               { Ah = Xoh; Al = Xol; Bh = Wh + OA; }
    };
    mfma_core2(acc, nsp, 256, m0, n0, AsH, AsL, BsH, pf);

    const int lane = threadIdx.x & 63, w = threadIdx.x >> 6;
    const int wr = w >> 1, wc = w & 1, l15 = lane & 15, lg = lane >> 4;

    u16* Of = ((seg == 0) ? Qf : (seg == 1) ? Kf : Vf) + (size_t)s * FRAG;

    #pragma unroll
    for (int mi = 0; mi < 4; ++mi)
        #pragma unroll
        for (int ni = 0; ni < 4; ++ni) {
            const int col = n0 + wc * 64 + ni * 16 + l15;
            #pragma unroll
            for (int r = 0; r < 4; ++r) {
                const int row = m0 + wr * 64 + mi * 16 + lg * 4 + r;
                const int bloc = row >> 8;
                const int h = col >> 4;
                if (seg == 0) {
                    const int T = (row >> 4) & 15, rq = row & 15;
                    const int half = (col >> 3) & 1, e = col & 7;
                    const size_t base = (((size_t)bloc * 16 + T) * 16 + h) * 512
                                      + half * 128 + rq * 8 + e;
                    Of[base] = f16_u((f16)acc[mi][ni][r]);     // hi only
                } else if (seg == 1) {
                    const int g = (row >> 5) & 7, jj = row & 31;
                    const int t = (jj >> 2) & 1;
                    const int lk = ((jj >> 3) << 2) | (jj & 3);
                    const int half = (col >> 3) & 1, e = col & 7;
                    const size_t base = (((size_t)bloc * 8 + g) * 16 + h) * 1024
                                      + t * 512 + half * 128 + lk * 8 + e;
                    u16 hi, lo; split2h(acc[mi][ni][r], hi, lo);
                    Of[base] = hi;
                    Of[base + 256] = lo;
                } else {
                    const int g = (row >> 5) & 7, jj = row & 31;
                    const int lgv = jj >> 3, e = jj & 7;
                    const int lv = col & 15;
                    const size_t base = (((size_t)bloc * 8 + g) * 16 + h) * 1024
                                      + (lgv * 16 + lv) * 8 + e;
                    Of[base] = f16_u((f16)acc[mi][ni][r]);     // hi only
                }
            }
        }
}

// ---------------------------------------------------------------------------
// Generic 2-term GEMM with epilogue. RESID: 0 none, 1 fp32, 2 split fp16.
// ---------------------------------------------------------------------------
template<int RESID, int RELU, int OUTF32, int OUTF16>
__global__ __launch_bounds__(256)
void gemm3(const u16* __restrict__ Asp, size_t AMK, int K,
           const u16* __restrict__ wt, int boff,
           const float* __restrict__ bias, int Nd,
           const u16* __restrict__ Rsp, const float* __restrict__ Rf,
           float* __restrict__ Of, u16* __restrict__ Ob, size_t OMN, int l)
{
    const int s  = blockIdx.z;
    const int n0 = blockIdx.y * 128;
    const int m0 = blockIdx.x * 128;

    const u16* Ah0 = Asp + (size_t)s * (2 * AMK);
    const u16* Al0 = Ah0 + AMK;
    const u16* Bh0 = wt + (size_t)s * (2 * WSEG) + boff;

    __shared__ u16 AsH[8192], AsL[8192], BsH[8192];

    f32x4 acc[4][4];
    #pragma unroll
    for (int i = 0; i < 4; ++i)
        #pragma unroll
        for (int j = 0; j < 4; ++j) acc[i][j] = (f32x4){0.f, 0.f, 0.f, 0.f};

    auto pf = [&](int p, const u16*& Ah, const u16*& Al, const u16*& Bh) {
        Ah = Ah0; Al = Al0; Bh = Bh0;
    };
    mfma_core2(acc, 1, K, m0, n0, AsH, AsL, BsH, pf);

    const float* bs = bias + (size_t)(l * 2 + s) * Nd;
    const int lane = threadIdx.x & 63, w = threadIdx.x >> 6;
    const int wr = w >> 1, wc = w & 1, l15 = lane & 15, lg = lane >> 4;

    #pragma unroll
    for (int mi = 0; mi < 4; ++mi)
        #pragma unroll
        for (int ni = 0; ni < 4; ++ni) {
            const int col = n0 + wc * 64 + ni * 16 + l15;
            const float bv = bs[col];
            #pragma unroll
            for (int r = 0; r < 4; ++r) {
                const int row = m0 + wr * 64 + mi * 16 + lg * 4 + r;
                const size_t idx = (size_t)row * Nd + col;
                float v = acc[mi][ni][r] + bv;
                if constexpr (RESID == 1) {
                    v += Rf[(size_t)s * PLX + idx];
                } else if constexpr (RESID == 2) {
                    const u16* Rh = Rsp + (size_t)s * (2 * PLX);
                    v += f16_f(Rh[idx]) + f16_f(Rh[PLX + idx]);
                }
                if constexpr (RELU) v = fmaxf(v, 0.f);
                if constexpr (OUTF32) Of[(size_t)s * PLX + idx] = v;
                if constexpr (OUTF16) {
                    u16 hi, lo; split2h(v, hi, lo);
                    u16* Oh = Ob + (size_t)s * (2 * OMN);
                    Oh[idx] = hi;
                    Oh[OMN + idx] = lo;
                }
            }
        }
}

// ---------------------------------------------------------------------------
// MFMA flash attention v5 (fp16). 1-D grid: id = ib*64 + (b*2+s) (XCD-group).
// QK^T: ONE mfma ([Kh|Kl] x [Qh|Qh] = K*Qh). PV: ONE mfma (fp16 P x Vh).
// ---------------------------------------------------------------------------
__global__ __launch_bounds__(512)
void attn_k(const u16* __restrict__ Qf, const u16* __restrict__ Kf,
            const u16* __restrict__ Vf, const float* __restrict__ cost,
            u16* __restrict__ AOs)
{
    const int id = blockIdx.x;
    const int bs = id & 63;
    const int ib = id >> 6;
    const int b = bs >> 1, s = bs & 1;
    const int i0 = ib * 32;

    const int tid = threadIdx.x;
    const int lane = tid & 63;
    const int wv = tid >> 6;
    const int l15 = lane & 15, lg = lane >> 4;
    const int h0 = wv * 2;

    const u16* Qfs = Qf + (size_t)s * FRAG;
    const u16* Kfs = Kf + (size_t)s * FRAG;
    const u16* Vfs = Vf + (size_t)s * FRAG;
    const float* cb = cost + (size_t)b * NN * NN;

    __shared__ float Cs[2][32][36];

    f16x8 qb1[2][2];
    #pragma unroll
    for (int hh = 0; hh < 2; ++hh)
        #pragma unroll
        for (int it = 0; it < 2; ++it) {
            const int T = (i0 >> 4) + it;
            const size_t base = (((size_t)b * 16 + T) * 16 + (h0 + hh)) * 512
                              + (lg & 1) * 128 + l15 * 8;
            qb1[hh][it] = *(const f16x8*)(Qfs + base);
        }

    float m_s[2][2], l_s[2][2];
    f32x4 occ[2][2];
    #pragma unroll
    for (int hh = 0; hh < 2; ++hh)
        #pragma unroll
        for (int it = 0; it < 2; ++it) {
            m_s[hh][it] = -1e30f;
            l_s[hh][it] = 0.f;
            occ[hh][it] = (f32x4){0.f, 0.f, 0.f, 0.f};
        }

    auto stageCost = [&](int g, int buf) {
        if (tid < 256) {
            if (s == 0) {
                const int i = tid >> 3, j4 = (tid & 7) * 4;
                float4 cv = *(const float4*)(cb + (size_t)(i0 + i) * NN + g * 32 + j4);
                Cs[buf][i][j4+0] = cv.x; Cs[buf][i][j4+1] = cv.y;
                Cs[buf][i][j4+2] = cv.z; Cs[buf][i][j4+3] = cv.w;
            } else {
                const int j = tid >> 3, i4 = (tid & 7) * 4;
                float4 cv = *(const float4*)(cb + (size_t)(g * 32 + j) * NN + i0 + i4);
                Cs[buf][i4+0][j] = cv.x; Cs[buf][i4+1][j] = cv.y;
                Cs[buf][i4+2][j] = cv.z; Cs[buf][i4+3][j] = cv.w;
            }
        }
    };

    auto loadKV = [&](int g, f16x8 (&kA)[2][2], f16x8 (&vv)[2]) {
        #pragma unroll
        for (int hh = 0; hh < 2; ++hh) {
            const size_t kb = (((size_t)b * 8 + g) * 16 + (h0 + hh)) * 1024;
            kA[hh][0] = *(const f16x8*)(Kfs + kb + lane * 8);
            kA[hh][1] = *(const f16x8*)(Kfs + kb + 512 + lane * 8);
            vv[hh]    = *(const f16x8*)(Vfs + kb + lane * 8);
        }
    };

    f16x8 kA0[2][2], vv0[2], kA1[2][2], vv1[2];
    stageCost(0, 0);
    loadKV(0, kA0, vv0);
    __syncthreads();

    auto iter = [&](int g, int cur,
                    f16x8 (&kAc)[2][2], f16x8 (&vvc)[2],
                    f16x8 (&kAn)[2][2], f16x8 (&vvn)[2]) {
        if (g < 7) {
            stageCost(g + 1, cur ^ 1);
            loadKV(g + 1, kAn, vvn);
        }
        float cst[2][8];
        #pragma unroll
        for (int it = 0; it < 2; ++it)
            #pragma unroll
            for (int t = 0; t < 2; ++t) {
                float4 cv = *(const float4*)&Cs[cur][it * 16 + l15][8 * lg + 4 * t];
                cst[it][t*4+0] = cv.x; cst[it][t*4+1] = cv.y;
                cst[it][t*4+2] = cv.z; cst[it][t*4+3] = cv.w;
            }
        #pragma unroll
        for (int hh = 0; hh < 2; ++hh) {
            #pragma unroll
            for (int it = 0; it < 2; ++it) {
                f32x4 st0 = (f32x4){0.f,0.f,0.f,0.f};
                f32x4 st1 = (f32x4){0.f,0.f,0.f,0.f};
                st0 = __builtin_amdgcn_mfma_f32_16x16x32_f16(kAc[hh][0], qb1[hh][it], st0, 0,0,0);
                st1 = __builtin_amdgcn_mfma_f32_16x16x32_f16(kAc[hh][1], qb1[hh][it], st1, 0,0,0);

                float sv[8];
                #pragma unroll
                for (int r = 0; r < 4; ++r) {
                    sv[r]     = st0[r] * 0.25f + cst[it][r];
                    sv[4 + r] = st1[r] * 0.25f + cst[it][4 + r];
                }
                float tm = sv[0];
                #pragma unroll
                for (int e = 1; e < 8; ++e) tm = fmaxf(tm, sv[e]);
                tm = fmaxf(tm, __shfl_xor(tm, 16));
                tm = fmaxf(tm, __shfl_xor(tm, 32));

                const float mo = m_s[hh][it];
                const float mn = fmaxf(mo, tm);
                const float sc = __expf(mo - mn);
                float p[8], ts = 0.f;
                #pragma unroll
                for (int e = 0; e < 8; ++e) { p[e] = __expf(sv[e] - mn); ts += p[e]; }
                ts += __shfl_xor(ts, 16);
                ts += __shfl_xor(ts, 32);
                l_s[hh][it] = l_s[hh][it] * sc + ts;
                m_s[hh][it] = mn;

                f32x4 o = occ[hh][it];
                o[0] *= sc; o[1] *= sc; o[2] *= sc; o[3] *= sc;
                f16x8 pb;
                #pragma unroll
                for (int e = 0; e < 8; ++e) pb[e] = (f16)p[e];
                o = __builtin_amdgcn_mfma_f32_16x16x32_f16(vvc[hh], pb, o, 0,0,0);
                occ[hh][it] = o;
            }
        }
        __syncthreads();
    };

    for (int gp = 0; gp < 8; gp += 2) {
        iter(gp,     0, kA0, vv0, kA1, vv1);
        iter(gp + 1, 1, kA1, vv1, kA0, vv0);
    }

    u16* AOh = AOs + (size_t)s * (2 * PLX);
    u16* AOl = AOh + PLX;
    #pragma unroll
    for (int hh = 0; hh < 2; ++hh)
        #pragma unroll
        for (int it = 0; it < 2; ++it) {
            const float inv = 1.f / l_s[hh][it];
            const size_t base = (size_t)(b * NN + i0 + it * 16 + l15) * EMB
                              + (h0 + hh) * 16 + lg * 4;
            ushort4 vh4, vl4;
            u16 h_, l_;
            split2h(occ[hh][it][0] * inv, h_, l_); vh4.x = h_; vl4.x = l_;
            split2h(occ[hh][it][1] * inv, h_, l_); vh4.y = h_; vl4.y = l_;
            split2h(occ[hh][it][2] * inv, h_, l_); vh4.z = h_; vl4.z = l_;
            split2h(occ[hh][it][3] * inv, h_, l_); vh4.w = h_; vl4.w = l_;
            *(ushort4*)(AOh + base) = vh4;
            *(ushort4*)(AOl + base) = vl4;
        }
}

// ---------------------------------------------------------------------------
// InstanceNorm over node axis; writes split fp16 planes (+ optional fp32).
// ---------------------------------------------------------------------------
template<int WF32>
__global__ __launch_bounds__(256)
void inorm_k(const float* __restrict__ Xb,
             const float* __restrict__ gb, const float* __restrict__ bb,
             float* __restrict__ Yf, u16* __restrict__ Ysp, int l)
{
    const int bx = blockIdx.x;
    const int b = bx >> 2, cg = bx & 3;
    const int s = blockIdx.y;
    const float* X = Xb + (size_t)s * PLX + (size_t)b * NN * EMB;
    const int tid = threadIdx.x;
    const int cl = tid & 63, q = tid >> 6;
    const int c = cg * 64 + cl;

    float sum = 0.f, ss = 0.f;
    for (int n = q * 64; n < q * 64 + 64; ++n) {
        float x = X[(size_t)n * EMB + c];
        sum += x; ss += x * x;
    }
    __shared__ float Ssum[4][64], Sss[4][64], Sa[64], Sb2[64];
    Ssum[q][cl] = sum; Sss[q][cl] = ss;
    __syncthreads();
    if (q == 0) {
        float s4 = Ssum[0][cl] + Ssum[1][cl] + Ssum[2][cl] + Ssum[3][cl];
        float q4 = Sss[0][cl] + Sss[1][cl] + Sss[2][cl] + Sss[3][cl];
        float mean = s4 * (1.f / NN);
        float var  = q4 * (1.f / NN) - mean * mean;
        float inv  = rsqrtf(var + 1e-5f);
        float gv = gb[(size_t)(l * 2 + s) * EMB + c];
        float bv = bb[(size_t)(l * 2 + s) * EMB + c];
        float a = gv * inv;
        Sa[cl]  = a;
        Sb2[cl] = bv - mean * a;
    }
    __syncthreads();
    const float a = Sa[cl], b2 = Sb2[cl];
    u16* Yh = Ysp + (size_t)s * (2 * PLX) + (size_t)b * NN * EMB;
    u16* Yl = Yh + PLX;
    float* Yo = WF32 ? (Yf + (size_t)s * PLX + (size_t)b * NN * EMB) : nullptr;
    for (int n = q * 64; n < q * 64 + 64; ++n) {
        const size_t idx = (size_t)n * EMB + c;
        float y = X[idx] * a + b2;
        if constexpr (WF32) Yo[idx] = y;
        u16 hi, lo; split2h(y, hi, lo);
        Yh[idx] = hi; Yl[idx] = lo;
    }
}

// ---------------------------------------------------------------------------
// Embedding -> split fp16 planes
// ---------------------------------------------------------------------------
__global__ __launch_bounds__(256)
void conv0_k(const float* __restrict__ rowe, const float* __restrict__ cole,
             u16* __restrict__ S0)
{
    const int side = blockIdx.y;
    const float* src = side ? cole : rowe;
    const size_t o = ((size_t)blockIdx.x * 256 + threadIdx.x) * 4;
    float4 v = *(const float4*)(src + o);
    u16 h0,l0,h1,l1,h2,l2,h3,l3;
    split2h(v.x, h0, l0); split2h(v.y, h1, l1);
    split2h(v.z, h2, l2); split2h(v.w, h3, l3);
    u16* Sh = S0 + (size_t)side * (2 * PLX);
    u16* Sl = Sh + PLX;
    ushort4 vh; vh.x=h0; vh.y=h1; vh.z=h2; vh.w=h3;
    ushort4 vl; vl.x=l0; vl.y=l1; vl.z=l2; vl.w=l3;
    *(ushort4*)(Sh + o) = vh;
    *(ushort4*)(Sl + o) = vl;
}

// ---------------------------------------------------------------------------
// Per-layer weight transpose: W[k][n] -> Wt_hi[n][k]  (fp16 hi only).
// ---------------------------------------------------------------------------
__global__ __launch_bounds__(256)
void wconv_k(const float* __restrict__ Wq, const float* __restrict__ Ws,
             const float* __restrict__ Wa, const float* __restrict__ Wv,
             const float* __restrict__ Wc, const float* __restrict__ W1,
             const float* __restrict__ W2, u16* __restrict__ wt, int l)
{
    const int t = blockIdx.x;
    const int s = blockIdx.y;
    const float* src; int Kd, Nd, tr, tc; size_t dsto;
    if (t < 80) {
        int m = t >> 4, tt = t & 15; tr = tt >> 2; tc = tt & 3; Kd = 256; Nd = 256;
        const float* w0;
        switch (m) {
            case 0: w0 = Wq; dsto = OQ; break;
            case 1: w0 = Ws; dsto = OS; break;
            case 2: w0 = Wa; dsto = OA; break;
            case 3: w0 = Wv; dsto = OV; break;
            default: w0 = Wc; dsto = OC; break;
        }
        src = w0 + (size_t)(l * 2 + s) * 65536;
    } else if (t < 112) {
        int tt = t - 80; tr = tt >> 3; tc = tt & 7; Kd = 256; Nd = 512;
        src = W1 + (size_t)(l * 2 + s) * 131072; dsto = O1;
    } else {
        int tt = t - 112; tr = tt >> 2; tc = tt & 3; Kd = 512; Nd = 256;
        src = W2 + (size_t)(l * 2 + s) * 131072; dsto = O2;
    }
    const int k0 = tr * 64, n0 = tc * 64;
    __shared__ float T[64][65];
    const int tid = threadIdx.x;
    {
        const int j4 = tid & 15, i0 = tid >> 4;
        #pragma unroll
        for (int ii = 0; ii < 4; ++ii) {
            int i = ii * 16 + i0;
            float4 v = *(const float4*)(src + (size_t)(k0 + i) * Nd + n0 + j4 * 4);
            T[i][j4*4+0] = v.x; T[i][j4*4+1] = v.y;
            T[i][j4*4+2] = v.z; T[i][j4*4+3] = v.w;
        }
    }
    __syncthreads();
    u16* Whi = wt + (size_t)s * (2 * WSEG) + dsto;
    {
        const int k4 = tid & 15, j0 = tid >> 4;
        #pragma unroll
        for (int jj = 0; jj < 4; ++jj) {
            int j = jj * 16 + j0;
            int n = n0 + j;
            ushort4 vh;
            vh.x = f16_u((f16)T[k4*4+0][j]);
            vh.y = f16_u((f16)T[k4*4+1][j]);
            vh.z = f16_u((f16)T[k4*4+2][j]);
            vh.w = f16_u((f16)T[k4*4+3][j]);
            *(ushort4*)(Whi + (size_t)n * Kd + k0 + k4 * 4) = vh;
        }
    }
}

// ---------------------------------------------------------------------------
// Workspace arena (128 MB, liveness-audited):
//  0-16 Sb0 | 16-32 Sb1 | 32-48 Qf->o1sp | 48-64 Kf->y1f->y2f
// 64-80 Vf->o1f | 80-84.5 wt (hi planes only used) | 96-112 AO -> 96-128 h
// ---------------------------------------------------------------------------
extern "C" void kernel_launch(void* const* d_in, const int* in_sizes, int n_in,
                              void* d_out, int out_size, void* d_ws, size_t ws_size,
                              hipStream_t stream)
{
    const float* row_emb = (const float*)d_in[0];
    const float* col_emb = (const float*)d_in[1];
    const float* cost    = (const float*)d_in[2];
    const float* Wq  = (const float*)d_in[3];
    const float* Ws  = (const float*)d_in[4];
    const float* Wa  = (const float*)d_in[5];
    const float* Wv  = (const float*)d_in[6];
    const float* Wc  = (const float*)d_in[7];
    const float* bc  = (const float*)d_in[8];
    const float* g1  = (const float*)d_in[9];
    const float* be1 = (const float*)d_in[10];
    const float* W1  = (const float*)d_in[11];
    const float* bf1 = (const float*)d_in[12];
    const float* W2  = (const float*)d_in[13];
    const float* bf2 = (const float*)d_in[14];
    const float* g2  = (const float*)d_in[15];
    const float* be2 = (const float*)d_in[16];

    char* W = (char*)d_ws;
    u16*   Sb[2]  = { (u16*)(W + 0 * MB), (u16*)(W + 16 * MB) };
    u16*   Qf     = (u16*)(W + 32 * MB);
    u16*   Kf     = (u16*)(W + 48 * MB);
    u16*   Vf     = (u16*)(W + 64 * MB);
    u16*   wt     = (u16*)(W + 80 * MB);
    u16*   AOsp   = (u16*)(W + 96 * MB);
    u16*   o1sp   = (u16*)(W + 32 * MB);     // alias Qf (dead after attn)
    float* y1f    = (float*)(W + 48 * MB);   // alias Kf (dead after attn)
    float* o1f    = (float*)(W + 64 * MB);   // alias Vf (dead after attn)
    u16*   hsp    = (u16*)(W + 96 * MB);     // alias AO (dead after Wc gemm)
    float* y2f    = (float*)(W + 48 * MB);   // alias y1 (dead after inorm1)

    conv0_k<<<dim3(2048, 2), 256, 0, stream>>>(row_emb, col_emb, Sb[0]);

    for (int l = 0; l < LL; ++l) {
        const int cur = l & 1;

        wconv_k<<<dim3(144, 2), 256, 0, stream>>>(Wq, Ws, Wa, Wv, Wc, W1, W2, wt, l);

        qkv_k<<<dim3(MTOT / 128, 6, 2), 256, 0, stream>>>(Sb[cur], wt, Qf, Kf, Vf);

        attn_k<<<dim3(512), 512, 0, stream>>>(Qf, Kf, Vf, cost, AOsp);

        // y1 = AO@Wc + bc + x(split)  -> y1f
        gemm3<2, 0, 1, 0><<<dim3(MTOT / 128, 2, 2), 256, 0, stream>>>(
            AOsp, PLX, 256, wt, OC, bc, 256, Sb[cur], nullptr, y1f, nullptr, 0, l);

        // o1 = inorm(y1) -> o1f (fp32) + o1sp (planes)
        inorm_k<1><<<dim3(BB * 4, 2), 256, 0, stream>>>(y1f, g1, be1, o1f, o1sp, l);

        // h = relu(o1@W1 + bf1) -> hsp planes
        gemm3<0, 1, 0, 1><<<dim3(MTOT / 128, 4, 2), 256, 0, stream>>>(
            o1sp, PLX, 256, wt, O1, bf1, 512, nullptr, nullptr, nullptr, hsp, PLH, l);

        // y2 = h@W2 + bf2 + o1 -> y2f
        gemm3<1, 0, 1, 0><<<dim3(MTOT / 128, 2, 2), 256, 0, stream>>>(
            hsp, PLH, 512, wt, O2, bf2, 256, nullptr, o1f, y2f, nullptr, 0, l);

        // out = inorm(y2) -> Sb[1-cur] planes (+ d_out fp32 on last layer)
        if (l == LL - 1)
            inorm_k<1><<<dim3(BB * 4, 2), 256, 0, stream>>>(y2f, g2, be2,
                (float*)d_out, Sb[1 - cur], l);
        else
            inorm_k<0><<<dim3(BB * 4, 2), 256, 0, stream>>>(y2f, g2, be2,
                nullptr, Sb[1 - cur], l);
    }
    (void)in_sizes; (void)n_in; (void)out_size; (void)ws_size;
}

// Round 11
// 860.909 us; speedup vs baseline: 3.0688x; 1.0428x over previous
//
#include <hip/hip_runtime.h>
#include <cstddef>
#include <cstdint>

#define EMB 256
#define NN  256
#define BB  32
#define FFD 512
#define LL  5
#define MTOT (BB*NN)          // 8192 rows

typedef unsigned short u16;
typedef _Float16 f16;
typedef f16   f16x8 __attribute__((ext_vector_type(8)));
typedef float f32x4 __attribute__((ext_vector_type(4)));

static const size_t MB = 1048576ull;
static const size_t PLX = 2097152;     // 8192x256 plane (elements)
static const size_t PLH = 4194304;     // 8192x512 plane
static const size_t FRAG = 4194304;    // 8 MB fragment buffer per side (u16)
static const size_t WSEG = 589824;     // hi-plane u16 per (layer,side)
#define OQ 0
#define OS 65536
#define OA 131072
#define OV 196608
#define OC 262144
#define O1 327680
#define O2 458752

__device__ __forceinline__ float f16_f(u16 u) {
    union { u16 u; f16 f; } c; c.u = u;
    return (float)c.f;
}
__device__ __forceinline__ u16 f16_u(f16 h) {
    union { f16 f; u16 u; } c; c.f = h;
    return c.u;
}
// fp16 hi/lo split: hi = RNE(x), lo = RNE(x - hi).
__device__ __forceinline__ void split2h(float x, u16& hi, u16& lo) {
    f16 h = (f16)x;
    f16 l = (f16)(x - (float)h);
    hi = f16_u(h); lo = f16_u(l);
}

__device__ __forceinline__ void gll16(const void* g, void* l) {
    __builtin_amdgcn_global_load_lds(
        (const __attribute__((address_space(1))) unsigned int*)g,
        (__attribute__((address_space(3))) unsigned int*)l,
        16, 0, 0);
}

// ---------------------------------------------------------------------------
// MFMA GEMM core, fp16 2-term split, templated on BN (N-tile width).
// BN=128: 4 waves as 2x2 (acc[4][4], 48KB LDS) — HW-verified.
// BN=64 : 4 waves row-stacked (acc[2][4], 40KB LDS) — wc=0 degenerate case,
//         doubles grid for small-N GEMMs (occupancy 1/CU -> 4/CU).
// M-tile is 128 in both. Swizzle: source-side XOR chunk + same XOR on read.
// ---------------------------------------------------------------------------
template<int BN, typename PF>
__device__ __forceinline__ void mfma_core2(f32x4 (&acc)[BN/32][4], int nsp,
                                           int K, int m0, int n0,
                                           u16* AsH, u16* AsL, u16* BsH, PF pf)
{
    constexpr int MI = BN / 32;           // 4 (BN=128) or 2 (BN=64)
    const int tid  = threadIdx.x;
    const int lane = tid & 63;
    const int w    = tid >> 6;
    const int wr   = (BN == 128) ? (w >> 1) : w;
    const int wc   = (BN == 128) ? (w & 1) : 0;
    const int l15  = lane & 15, lg = lane >> 4;

    for (int p = 0; p < nsp; ++p) {
        const u16 *Ah, *Al, *Bh;
        pf(p, Ah, Al, Bh);
        const int nkt = K >> 6;
        for (int kt = 0; kt < nkt; ++kt) {
            __syncthreads();
            // stage A (128 rows x 64 k, 1024 16B-slots, both planes)
            #pragma unroll
            for (int c = 0; c < 4; ++c) {
                int slot = w * 256 + c * 64 + lane;
                int row  = slot >> 3;
                int cc   = slot & 7;
                int kc   = cc ^ (row & 7);
                const size_t ga = (size_t)(m0 + row) * K + (kt << 6) + kc * 8;
                const int lo = slot * 8;
                gll16(Ah + ga, AsH + lo);
                gll16(Al + ga, AsL + lo);
            }
            // stage B (BN rows x 64 k, BN*8 slots, hi plane)
            #pragma unroll
            for (int c = 0; c < BN / 32; ++c) {
                int slot = w * (BN * 2) + c * 64 + lane;
                int row  = slot >> 3;
                int cc   = slot & 7;
                int kc   = cc ^ (row & 7);
                const size_t gb = (size_t)(n0 + row) * K + (kt << 6) + kc * 8;
                gll16(Bh + gb, BsH + slot * 8);
            }
            __syncthreads();
            #pragma unroll
            for (int ks = 0; ks < 2; ++ks) {
                f16x8 ah[MI], al[MI], bh[4];
                #pragma unroll
                for (int i = 0; i < MI; ++i) {
                    int arow = wr * (MI * 16) + i * 16 + l15;
                    int aoff = ((arow << 3) + ((ks * 4 + lg) ^ (arow & 7))) * 8;
                    ah[i] = *(const f16x8*)(AsH + aoff);
                    al[i] = *(const f16x8*)(AsL + aoff);
                }
                #pragma unroll
                for (int i = 0; i < 4; ++i) {
                    int brow = wc * 64 + i * 16 + l15;
                    int boff = ((brow << 3) + ((ks * 4 + lg) ^ (brow & 7))) * 8;
                    bh[i] = *(const f16x8*)(BsH + boff);
                }
                #pragma unroll
                for (int mi = 0; mi < MI; ++mi)
                    #pragma unroll
                    for (int ni = 0; ni < 4; ++ni) {
                        acc[mi][ni] = __builtin_amdgcn_mfma_f32_16x16x32_f16(
                            ah[mi], bh[ni], acc[mi][ni], 0, 0, 0);
                        acc[mi][ni] = __builtin_amdgcn_mfma_f32_16x16x32_f16(
                            al[mi], bh[ni], acc[mi][ni], 0, 0, 0);
                    }
            }
        }
    }
}

// ---------------------------------------------------------------------------
// Fused QKV -> fragment-packed outputs (BN=128 core).
// ---------------------------------------------------------------------------
__global__ __launch_bounds__(256)
void qkv_k(const u16* __restrict__ Ssp, const u16* __restrict__ wt,
           u16* __restrict__ Qf, u16* __restrict__ Kf, u16* __restrict__ Vf,
           int l)
{
    const int s   = blockIdx.z;
    const int seg = blockIdx.y >> 1;
    const int n0  = (blockIdx.y & 1) * 128;
    const int m0  = blockIdx.x * 128;

    const u16* Xsh = Ssp + (size_t)s * (2 * PLX);
    const u16* Xsl = Xsh + PLX;
    const u16* Xoh = Ssp + (size_t)(1 - s) * (2 * PLX);
    const u16* Xol = Xoh + PLX;
    const u16* Wh  = wt + (size_t)(l * 2 + s) * WSEG;
    const int  nsp = (seg == 1) ? 2 : 1;

    __shared__ u16 AsH[8192], AsL[8192], BsH[8192];

    f32x4 acc[4][4];
    #pragma unroll
    for (int i = 0; i < 4; ++i)
        #pragma unroll
        for (int j = 0; j < 4; ++j) acc[i][j] = (f32x4){0.f, 0.f, 0.f, 0.f};

    auto pf = [&](int p, const u16*& Ah, const u16*& Al, const u16*& Bh) {
        if (seg == 0)      { Ah = Xsh; Al = Xsl; Bh = Wh + OQ; }
        else if (seg == 2) { Ah = Xoh; Al = Xol; Bh = Wh + OV; }
        else if (p == 0)   { Ah = Xsh; Al = Xsl; Bh = Wh + OS; }
        else               { Ah = Xoh; Al = Xol; Bh = Wh + OA; }
    };
    mfma_core2<128>(acc, nsp, 256, m0, n0, AsH, AsL, BsH, pf);

    const int lane = threadIdx.x & 63, w = threadIdx.x >> 6;
    const int wr = w >> 1, wc = w & 1, l15 = lane & 15, lg = lane >> 4;

    u16* Of = ((seg == 0) ? Qf : (seg == 1) ? Kf : Vf) + (size_t)s * FRAG;

    #pragma unroll
    for (int mi = 0; mi < 4; ++mi)
        #pragma unroll
        for (int ni = 0; ni < 4; ++ni) {
            const int col = n0 + wc * 64 + ni * 16 + l15;
            #pragma unroll
            for (int r = 0; r < 4; ++r) {
                const int row = m0 + wr * 64 + mi * 16 + lg * 4 + r;
                const int bloc = row >> 8;
                const int h = col >> 4;
                if (seg == 0) {
                    const int T = (row >> 4) & 15, rq = row & 15;
                    const int half = (col >> 3) & 1, e = col & 7;
                    const size_t base = (((size_t)bloc * 16 + T) * 16 + h) * 512
                                      + half * 128 + rq * 8 + e;
                    Of[base] = f16_u((f16)acc[mi][ni][r]);     // hi only
                } else if (seg == 1) {
                    const int g = (row >> 5) & 7, jj = row & 31;
                    const int t = (jj >> 2) & 1;
                    const int lk = ((jj >> 3) << 2) | (jj & 3);
                    const int half = (col >> 3) & 1, e = col & 7;
                    const size_t base = (((size_t)bloc * 8 + g) * 16 + h) * 1024
                                      + t * 512 + half * 128 + lk * 8 + e;
                    u16 hi, lo; split2h(acc[mi][ni][r], hi, lo);
                    Of[base] = hi;
                    Of[base + 256] = lo;
                } else {
                    const int g = (row >> 5) & 7, jj = row & 31;
                    const int lgv = jj >> 3, e = jj & 7;
                    const int lv = col & 15;
                    const size_t base = (((size_t)bloc * 8 + g) * 16 + h) * 1024
                                      + (lgv * 16 + lv) * 8 + e;
                    Of[base] = f16_u((f16)acc[mi][ni][r]);     // hi only
                }
            }
        }
}

// ---------------------------------------------------------------------------
// Generic 2-term GEMM with epilogue, templated on BN.
// RESID: 0 none, 1 fp32, 2 split fp16.
// ---------------------------------------------------------------------------
template<int BN, int RESID, int RELU, int OUTF32, int OUTF16>
__global__ __launch_bounds__(256)
void gemm3(const u16* __restrict__ Asp, size_t AMK, int K,
           const u16* __restrict__ wt, int boff,
           const float* __restrict__ bias, int Nd,
           const u16* __restrict__ Rsp, const float* __restrict__ Rf,
           float* __restrict__ Of, u16* __restrict__ Ob, size_t OMN, int l)
{
    constexpr int MI = BN / 32;
    const int s  = blockIdx.z;
    const int n0 = blockIdx.y * BN;
    const int m0 = blockIdx.x * 128;

    const u16* Ah0 = Asp + (size_t)s * (2 * AMK);
    const u16* Al0 = Ah0 + AMK;
    const u16* Bh0 = wt + (size_t)(l * 2 + s) * WSEG + boff;

    __shared__ u16 AsH[8192], AsL[8192], BsH[BN * 64];

    f32x4 acc[MI][4];
    #pragma unroll
    for (int i = 0; i < MI; ++i)
        #pragma unroll
        for (int j = 0; j < 4; ++j) acc[i][j] = (f32x4){0.f, 0.f, 0.f, 0.f};

    auto pf = [&](int p, const u16*& Ah, const u16*& Al, const u16*& Bh) {
        Ah = Ah0; Al = Al0; Bh = Bh0;
    };
    mfma_core2<BN>(acc, 1, K, m0, n0, AsH, AsL, BsH, pf);

    const float* bs = bias + (size_t)(l * 2 + s) * Nd;
    const int lane = threadIdx.x & 63, w = threadIdx.x >> 6;
    const int wr = (BN == 128) ? (w >> 1) : w;
    const int wc = (BN == 128) ? (w & 1) : 0;
    const int l15 = lane & 15, lg = lane >> 4;

    #pragma unroll
    for (int mi = 0; mi < MI; ++mi)
        #pragma unroll
        for (int ni = 0; ni < 4; ++ni) {
            const int col = n0 + wc * 64 + ni * 16 + l15;
            const float bv = bs[col];
            #pragma unroll
            for (int r = 0; r < 4; ++r) {
                const int row = m0 + wr * (MI * 16) + mi * 16 + lg * 4 + r;
                const size_t idx = (size_t)row * Nd + col;
                float v = acc[mi][ni][r] + bv;
                if constexpr (RESID == 1) {
                    v += Rf[(size_t)s * PLX + idx];
                } else if constexpr (RESID == 2) {
                    const u16* Rh = Rsp + (size_t)s * (2 * PLX);
                    v += f16_f(Rh[idx]) + f16_f(Rh[PLX + idx]);
                }
                if constexpr (RELU) v = fmaxf(v, 0.f);
                if constexpr (OUTF32) Of[(size_t)s * PLX + idx] = v;
                if constexpr (OUTF16) {
                    u16 hi, lo; split2h(v, hi, lo);
                    u16* Oh = Ob + (size_t)s * (2 * OMN);
                    Oh[idx] = hi;
                    Oh[OMN + idx] = lo;
                }
            }
        }
}

// ---------------------------------------------------------------------------
// MFMA flash attention v5 (fp16) — unchanged from round 10 (validated).
// ---------------------------------------------------------------------------
__global__ __launch_bounds__(512)
void attn_k(const u16* __restrict__ Qf, const u16* __restrict__ Kf,
            const u16* __restrict__ Vf, const float* __restrict__ cost,
            u16* __restrict__ AOs)
{
    const int id = blockIdx.x;
    const int bs = id & 63;
    const int ib = id >> 6;
    const int b = bs >> 1, s = bs & 1;
    const int i0 = ib * 32;

    const int tid = threadIdx.x;
    const int lane = tid & 63;
    const int wv = tid >> 6;
    const int l15 = lane & 15, lg = lane >> 4;
    const int h0 = wv * 2;

    const u16* Qfs = Qf + (size_t)s * FRAG;
    const u16* Kfs = Kf + (size_t)s * FRAG;
    const u16* Vfs = Vf + (size_t)s * FRAG;
    const float* cb = cost + (size_t)b * NN * NN;

    __shared__ float Cs[2][32][36];

    f16x8 qb1[2][2];
    #pragma unroll
    for (int hh = 0; hh < 2; ++hh)
        #pragma unroll
        for (int it = 0; it < 2; ++it) {
            const int T = (i0 >> 4) + it;
            const size_t base = (((size_t)b * 16 + T) * 16 + (h0 + hh)) * 512
                              + (lg & 1) * 128 + l15 * 8;
            qb1[hh][it] = *(const f16x8*)(Qfs + base);
        }

    float m_s[2][2], l_s[2][2];
    f32x4 occ[2][2];
    #pragma unroll
    for (int hh = 0; hh < 2; ++hh)
        #pragma unroll
        for (int it = 0; it < 2; ++it) {
            m_s[hh][it] = -1e30f;
            l_s[hh][it] = 0.f;
            occ[hh][it] = (f32x4){0.f, 0.f, 0.f, 0.f};
        }

    auto stageCost = [&](int g, int buf) {
        if (tid < 256) {
            if (s == 0) {
                const int i = tid >> 3, j4 = (tid & 7) * 4;
                float4 cv = *(const float4*)(cb + (size_t)(i0 + i) * NN + g * 32 + j4);
                Cs[buf][i][j4+0] = cv.x; Cs[buf][i][j4+1] = cv.y;
                Cs[buf][i][j4+2] = cv.z; Cs[buf][i][j4+3] = cv.w;
            } else {
                const int j = tid >> 3, i4 = (tid & 7) * 4;
                float4 cv = *(const float4*)(cb + (size_t)(g * 32 + j) * NN + i0 + i4);
                Cs[buf][i4+0][j] = cv.x; Cs[buf][i4+1][j] = cv.y;
                Cs[buf][i4+2][j] = cv.z; Cs[buf][i4+3][j] = cv.w;
            }
        }
    };

    auto loadKV = [&](int g, f16x8 (&kA)[2][2], f16x8 (&vv)[2]) {
        #pragma unroll
        for (int hh = 0; hh < 2; ++hh) {
            const size_t kb = (((size_t)b * 8 + g) * 16 + (h0 + hh)) * 1024;
            kA[hh][0] = *(const f16x8*)(Kfs + kb + lane * 8);
            kA[hh][1] = *(const f16x8*)(Kfs + kb + 512 + lane * 8);
            vv[hh]    = *(const f16x8*)(Vfs + kb + lane * 8);
        }
    };

    f16x8 kA0[2][2], vv0[2], kA1[2][2], vv1[2];
    stageCost(0, 0);
    loadKV(0, kA0, vv0);
    __syncthreads();

    auto iter = [&](int g, int cur,
                    f16x8 (&kAc)[2][2], f16x8 (&vvc)[2],
                    f16x8 (&kAn)[2][2], f16x8 (&vvn)[2]) {
        if (g < 7) {
            stageCost(g + 1, cur ^ 1);
            loadKV(g + 1, kAn, vvn);
        }
        float cst[2][8];
        #pragma unroll
        for (int it = 0; it < 2; ++it)
            #pragma unroll
            for (int t = 0; t < 2; ++t) {
                float4 cv = *(const float4*)&Cs[cur][it * 16 + l15][8 * lg + 4 * t];
                cst[it][t*4+0] = cv.x; cst[it][t*4+1] = cv.y;
                cst[it][t*4+2] = cv.z; cst[it][t*4+3] = cv.w;
            }
        #pragma unroll
        for (int hh = 0; hh < 2; ++hh) {
            #pragma unroll
            for (int it = 0; it < 2; ++it) {
                f32x4 st0 = (f32x4){0.f,0.f,0.f,0.f};
                f32x4 st1 = (f32x4){0.f,0.f,0.f,0.f};
                st0 = __builtin_amdgcn_mfma_f32_16x16x32_f16(kAc[hh][0], qb1[hh][it], st0, 0,0,0);
                st1 = __builtin_amdgcn_mfma_f32_16x16x32_f16(kAc[hh][1], qb1[hh][it], st1, 0,0,0);

                float sv[8];
                #pragma unroll
                for (int r = 0; r < 4; ++r) {
                    sv[r]     = st0[r] * 0.25f + cst[it][r];
                    sv[4 + r] = st1[r] * 0.25f + cst[it][4 + r];
                }
                float tm = sv[0];
                #pragma unroll
                for (int e = 1; e < 8; ++e) tm = fmaxf(tm, sv[e]);
                tm = fmaxf(tm, __shfl_xor(tm, 16));
                tm = fmaxf(tm, __shfl_xor(tm, 32));

                const float mo = m_s[hh][it];
                const float mn = fmaxf(mo, tm);
                const float sc = __expf(mo - mn);
                float p[8], ts = 0.f;
                #pragma unroll
                for (int e = 0; e < 8; ++e) { p[e] = __expf(sv[e] - mn); ts += p[e]; }
                ts += __shfl_xor(ts, 16);
                ts += __shfl_xor(ts, 32);
                l_s[hh][it] = l_s[hh][it] * sc + ts;
                m_s[hh][it] = mn;

                f32x4 o = occ[hh][it];
                o[0] *= sc; o[1] *= sc; o[2] *= sc; o[3] *= sc;
                f16x8 pb;
                #pragma unroll
                for (int e = 0; e < 8; ++e) pb[e] = (f16)p[e];
                o = __builtin_amdgcn_mfma_f32_16x16x32_f16(vvc[hh], pb, o, 0,0,0);
                occ[hh][it] = o;
            }
        }
        __syncthreads();
    };

    for (int gp = 0; gp < 8; gp += 2) {
        iter(gp,     0, kA0, vv0, kA1, vv1);
        iter(gp + 1, 1, kA1, vv1, kA0, vv0);
    }

    u16* AOh = AOs + (size_t)s * (2 * PLX);
    u16* AOl = AOh + PLX;
    #pragma unroll
    for (int hh = 0; hh < 2; ++hh)
        #pragma unroll
        for (int it = 0; it < 2; ++it) {
            const float inv = 1.f / l_s[hh][it];
            const size_t base = (size_t)(b * NN + i0 + it * 16 + l15) * EMB
                              + (h0 + hh) * 16 + lg * 4;
            ushort4 vh4, vl4;
            u16 h_, l_;
            split2h(occ[hh][it][0] * inv, h_, l_); vh4.x = h_; vl4.x = l_;
            split2h(occ[hh][it][1] * inv, h_, l_); vh4.y = h_; vl4.y = l_;
            split2h(occ[hh][it][2] * inv, h_, l_); vh4.z = h_; vl4.z = l_;
            split2h(occ[hh][it][3] * inv, h_, l_); vh4.w = h_; vl4.w = l_;
            *(ushort4*)(AOh + base) = vh4;
            *(ushort4*)(AOl + base) = vl4;
        }
}

// ---------------------------------------------------------------------------
// InstanceNorm over node axis; writes split fp16 planes (+ optional fp32).
// ---------------------------------------------------------------------------
template<int WF32>
__global__ __launch_bounds__(256)
void inorm_k(const float* __restrict__ Xb,
             const float* __restrict__ gb, const float* __restrict__ bb,
             float* __restrict__ Yf, u16* __restrict__ Ysp, int l)
{
    const int bx = blockIdx.x;
    const int b = bx >> 2, cg = bx & 3;
    const int s = blockIdx.y;
    const float* X = Xb + (size_t)s * PLX + (size_t)b * NN * EMB;
    const int tid = threadIdx.x;
    const int cl = tid & 63, q = tid >> 6;
    const int c = cg * 64 + cl;

    float sum = 0.f, ss = 0.f;
    for (int n = q * 64; n < q * 64 + 64; ++n) {
        float x = X[(size_t)n * EMB + c];
        sum += x; ss += x * x;
    }
    __shared__ float Ssum[4][64], Sss[4][64], Sa[64], Sb2[64];
    Ssum[q][cl] = sum; Sss[q][cl] = ss;
    __syncthreads();
    if (q == 0) {
        float s4 = Ssum[0][cl] + Ssum[1][cl] + Ssum[2][cl] + Ssum[3][cl];
        float q4 = Sss[0][cl] + Sss[1][cl] + Sss[2][cl] + Sss[3][cl];
        float mean = s4 * (1.f / NN);
        float var  = q4 * (1.f / NN) - mean * mean;
        float inv  = rsqrtf(var + 1e-5f);
        float gv = gb[(size_t)(l * 2 + s) * EMB + c];
        float bv = bb[(size_t)(l * 2 + s) * EMB + c];
        float a = gv * inv;
        Sa[cl]  = a;
        Sb2[cl] = bv - mean * a;
    }
    __syncthreads();
    const float a = Sa[cl], b2 = Sb2[cl];
    u16* Yh = Ysp + (size_t)s * (2 * PLX) + (size_t)b * NN * EMB;
    u16* Yl = Yh + PLX;
    float* Yo = WF32 ? (Yf + (size_t)s * PLX + (size_t)b * NN * EMB) : nullptr;
    for (int n = q * 64; n < q * 64 + 64; ++n) {
        const size_t idx = (size_t)n * EMB + c;
        float y = X[idx] * a + b2;
        if constexpr (WF32) Yo[idx] = y;
        u16 hi, lo; split2h(y, hi, lo);
        Yh[idx] = hi; Yl[idx] = lo;
    }
}

// ---------------------------------------------------------------------------
// Embedding -> split fp16 planes
// ---------------------------------------------------------------------------
__global__ __launch_bounds__(256)
void conv0_k(const float* __restrict__ rowe, const float* __restrict__ cole,
             u16* __restrict__ S0)
{
    const int side = blockIdx.y;
    const float* src = side ? cole : rowe;
    const size_t o = ((size_t)blockIdx.x * 256 + threadIdx.x) * 4;
    float4 v = *(const float4*)(src + o);
    u16 h0,l0,h1,l1,h2,l2,h3,l3;
    split2h(v.x, h0, l0); split2h(v.y, h1, l1);
    split2h(v.z, h2, l2); split2h(v.w, h3, l3);
    u16* Sh = S0 + (size_t)side * (2 * PLX);
    u16* Sl = Sh + PLX;
    ushort4 vh; vh.x=h0; vh.y=h1; vh.z=h2; vh.w=h3;
    ushort4 vl; vl.x=l0; vl.y=l1; vl.z=l2; vl.w=l3;
    *(ushort4*)(Sh + o) = vh;
    *(ushort4*)(Sl + o) = vl;
}

// ---------------------------------------------------------------------------
// ALL-layer weight transpose: W[k][n] -> Wt_hi[n][k] (fp16), one dispatch.
// blockIdx.y = l*2 + s  (10 values).
// ---------------------------------------------------------------------------
__global__ __launch_bounds__(256)
void wconv_k(const float* __restrict__ Wq, const float* __restrict__ Ws,
             const float* __restrict__ Wa, const float* __restrict__ Wv,
             const float* __restrict__ Wc, const float* __restrict__ W1,
             const float* __restrict__ W2, u16* __restrict__ wt)
{
    const int t = blockIdx.x;
    const int ls = blockIdx.y;          // l*2+s
    const float* src; int Kd, Nd, tr, tc; size_t dsto;
    if (t < 80) {
        int m = t >> 4, tt = t & 15; tr = tt >> 2; tc = tt & 3; Kd = 256; Nd = 256;
        const float* w0;
        switch (m) {
            case 0: w0 = Wq; dsto = OQ; break;
            case 1: w0 = Ws; dsto = OS; break;
            case 2: w0 = Wa; dsto = OA; break;
            case 3: w0 = Wv; dsto = OV; break;
            default: w0 = Wc; dsto = OC; break;
        }
        src = w0 + (size_t)ls * 65536;
    } else if (t < 112) {
        int tt = t - 80; tr = tt >> 3; tc = tt & 7; Kd = 256; Nd = 512;
        src = W1 + (size_t)ls * 131072; dsto = O1;
    } else {
        int tt = t - 112; tr = tt >> 2; tc = tt & 3; Kd = 512; Nd = 256;
        src = W2 + (size_t)ls * 131072; dsto = O2;
    }
    const int k0 = tr * 64, n0 = tc * 64;
    __shared__ float T[64][65];
    const int tid = threadIdx.x;
    {
        const int j4 = tid & 15, i0 = tid >> 4;
        #pragma unroll
        for (int ii = 0; ii < 4; ++ii) {
            int i = ii * 16 + i0;
            float4 v = *(const float4*)(src + (size_t)(k0 + i) * Nd + n0 + j4 * 4);
            T[i][j4*4+0] = v.x; T[i][j4*4+1] = v.y;
            T[i][j4*4+2] = v.z; T[i][j4*4+3] = v.w;
        }
    }
    __syncthreads();
    u16* Whi = wt + (size_t)ls * WSEG + dsto;
    {
        const int k4 = tid & 15, j0 = tid >> 4;
        #pragma unroll
        for (int jj = 0; jj < 4; ++jj) {
            int j = jj * 16 + j0;
            int n = n0 + j;
            ushort4 vh;
            vh.x = f16_u((f16)T[k4*4+0][j]);
            vh.y = f16_u((f16)T[k4*4+1][j]);
            vh.z = f16_u((f16)T[k4*4+2][j]);
            vh.w = f16_u((f16)T[k4*4+3][j]);
            *(ushort4*)(Whi + (size_t)n * Kd + k0 + k4 * 4) = vh;
        }
    }
}

// ---------------------------------------------------------------------------
// Workspace arena (128 MB, liveness-audited):
//  0-16 Sb0 | 16-32 Sb1 | 32-48 Qf->o1sp | 48-64 Kf->y1f->y2f
// 64-80 Vf->o1f | 80-92 wt (all layers, fp16 hi) | 96-112 AO -> 96-128 h
// ---------------------------------------------------------------------------
extern "C" void kernel_launch(void* const* d_in, const int* in_sizes, int n_in,
                              void* d_out, int out_size, void* d_ws, size_t ws_size,
                              hipStream_t stream)
{
    const float* row_emb = (const float*)d_in[0];
    const float* col_emb = (const float*)d_in[1];
    const float* cost    = (const float*)d_in[2];
    const float* Wq  = (const float*)d_in[3];
    const float* Ws  = (const float*)d_in[4];
    const float* Wa  = (const float*)d_in[5];
    const float* Wv  = (const float*)d_in[6];
    const float* Wc  = (const float*)d_in[7];
    const float* bc  = (const float*)d_in[8];
    const float* g1  = (const float*)d_in[9];
    const float* be1 = (const float*)d_in[10];
    const float* W1  = (const float*)d_in[11];
    const float* bf1 = (const float*)d_in[12];
    const float* W2  = (const float*)d_in[13];
    const float* bf2 = (const float*)d_in[14];
    const float* g2  = (const float*)d_in[15];
    const float* be2 = (const float*)d_in[16];

    char* W = (char*)d_ws;
    u16*   Sb[2]  = { (u16*)(W + 0 * MB), (u16*)(W + 16 * MB) };
    u16*   Qf     = (u16*)(W + 32 * MB);
    u16*   Kf     = (u16*)(W + 48 * MB);
    u16*   Vf     = (u16*)(W + 64 * MB);
    u16*   wt     = (u16*)(W + 80 * MB);
    u16*   AOsp   = (u16*)(W + 96 * MB);
    u16*   o1sp   = (u16*)(W + 32 * MB);     // alias Qf (dead after attn)
    float* y1f    = (float*)(W + 48 * MB);   // alias Kf (dead after attn)
    float* o1f    = (float*)(W + 64 * MB);   // alias Vf (dead after attn)
    u16*   hsp    = (u16*)(W + 96 * MB);     // alias AO (dead after Wc gemm)
    float* y2f    = (float*)(W + 48 * MB);   // alias y1 (dead after inorm1)

    conv0_k<<<dim3(2048, 2), 256, 0, stream>>>(row_emb, col_emb, Sb[0]);
    wconv_k<<<dim3(144, 10), 256, 0, stream>>>(Wq, Ws, Wa, Wv, Wc, W1, W2, wt);

    for (int l = 0; l < LL; ++l) {
        const int cur = l & 1;

        qkv_k<<<dim3(MTOT / 128, 6, 2), 256, 0, stream>>>(Sb[cur], wt, Qf, Kf, Vf, l);

        attn_k<<<dim3(512), 512, 0, stream>>>(Qf, Kf, Vf, cost, AOsp);

        // y1 = AO@Wc + bc + x(split)  -> y1f     [BN=64, grid 512]
        gemm3<64, 2, 0, 1, 0><<<dim3(MTOT / 128, 4, 2), 256, 0, stream>>>(
            AOsp, PLX, 256, wt, OC, bc, 256, Sb[cur], nullptr, y1f, nullptr, 0, l);

        // o1 = inorm(y1) -> o1f (fp32) + o1sp (planes)
        inorm_k<1><<<dim3(BB * 4, 2), 256, 0, stream>>>(y1f, g1, be1, o1f, o1sp, l);

        // h = relu(o1@W1 + bf1) -> hsp planes    [BN=64, grid 1024]
        gemm3<64, 0, 1, 0, 1><<<dim3(MTOT / 128, 8, 2), 256, 0, stream>>>(
            o1sp, PLX, 256, wt, O1, bf1, 512, nullptr, nullptr, nullptr, hsp, PLH, l);

        // y2 = h@W2 + bf2 + o1 -> y2f            [BN=64, grid 512]
        gemm3<64, 1, 0, 1, 0><<<dim3(MTOT / 128, 4, 2), 256, 0, stream>>>(
            hsp, PLH, 512, wt, O2, bf2, 256, nullptr, o1f, y2f, nullptr, 0, l);

        // out = inorm(y2) -> Sb[1-cur] planes (+ d_out fp32 on last layer)
        if (l == LL - 1)
            inorm_k<1><<<dim3(BB * 4, 2), 256, 0, stream>>>(y2f, g2, be2,
                (float*)d_out, Sb[1 - cur], l);
        else
            inorm_k<0><<<dim3(BB * 4, 2), 256, 0, stream>>>(y2f, g2, be2,
                nullptr, Sb[1 - cur], l);
    }
    (void)in_sizes; (void)n_in; (void)out_size; (void)ws_size;
}